// Round 1
// baseline (3614.511 us; speedup 1.0000x reference)
//
#include <hip/hip_runtime.h>
#include <cstdint>
#include <cstddef>

// ---------------- static problem config ----------------
#define NN      10000   // nodes
#define NE      120000  // edges
#define NG      32      // graphs
#define FNODE   64
#define FEDGE   16
#define HID     128
#define NHEADS  4
#define NL      3
#define NR      4
#define IDDIM   32
#define RELDIM  8
#define FFNH    256
#define HEADH   128
#define NCLS    10

// ---------------- helpers ----------------
__device__ __forceinline__ unsigned fenc(float f) {
  unsigned u = __float_as_uint(f);
  return (u & 0x80000000u) ? ~u : (u | 0x80000000u);
}
__device__ __forceinline__ float fdec(unsigned k) {
  return __uint_as_float((k & 0x80000000u) ? (k ^ 0x80000000u) : ~k);
}
__device__ __forceinline__ float silu_f(float x) { return x / (1.f + expf(-x)); }

// encoded(-inf) = ~bits(-inf) = 0x007FFFFF
#define ENC_NEG_INF 0x007FFFFFu

// ---------------- generic fp32 GEMM: C[M,Nc] = A[M,K] @ B[K,Nc] (+bias) ----------------
// BM=BN=64, BK=16, 256 threads, 4x4 per thread. K%16==0, Nc%64==0 assumed.
__global__ __launch_bounds__(256) void sgemm_bias(
    const float* __restrict__ A, const float* __restrict__ B,
    const float* __restrict__ bias, float* __restrict__ C,
    int M, int K, int Nc) {
  __shared__ float As[16][68];  // +4 pad: 2-way bank alias only (free on CDNA4)
  __shared__ float Bs[16][64];
  const int tid = threadIdx.x;
  const int bm = blockIdx.y * 64;
  const int bn = blockIdx.x * 64;
  const int tx = tid & 15, ty = tid >> 4;
  float acc[4][4] = {};
  for (int k0 = 0; k0 < K; k0 += 16) {
#pragma unroll
    for (int i = 0; i < 4; ++i) {
      int idx = tid + i * 256;      // 0..1023
      int r = idx >> 4;             // row in tile 0..63
      int c = idx & 15;             // k   in tile 0..15
      int gr = bm + r;
      As[c][r] = (gr < M) ? A[(size_t)gr * K + k0 + c] : 0.f;
    }
#pragma unroll
    for (int i = 0; i < 4; ++i) {
      int idx = tid + i * 256;
      int kr = idx >> 6;            // 0..15
      int c = idx & 63;
      Bs[kr][c] = B[(size_t)(k0 + kr) * Nc + bn + c];
    }
    __syncthreads();
#pragma unroll
    for (int kk = 0; kk < 16; ++kk) {
      float a[4], b[4];
#pragma unroll
      for (int i = 0; i < 4; ++i) a[i] = As[kk][ty * 4 + i];
#pragma unroll
      for (int j = 0; j < 4; ++j) b[j] = Bs[kk][tx * 4 + j];
#pragma unroll
      for (int i = 0; i < 4; ++i)
#pragma unroll
        for (int j = 0; j < 4; ++j) acc[i][j] = fmaf(a[i], b[j], acc[i][j]);
    }
    __syncthreads();
  }
#pragma unroll
  for (int i = 0; i < 4; ++i) {
    int gr = bm + ty * 4 + i;
    if (gr >= M) continue;
#pragma unroll
    for (int j = 0; j < 4; ++j) {
      int gc = bn + tx * 4 + j;
      float v = acc[i][j];
      if (bias) v += bias[gc];
      C[(size_t)gr * Nc + gc] = v;
    }
  }
}

// ---------------- input projection: h = silu(concat(x, id_emb[tok]) @ inW + inb) ----------------
__global__ __launch_bounds__(128) void input_proj(
    const float* __restrict__ x, const float* __restrict__ id_emb,
    const int* __restrict__ id_token, const float* __restrict__ inW,
    const float* __restrict__ inb, float* __restrict__ h) {
  int n = blockIdx.x, j = threadIdx.x;
  __shared__ float s[FNODE + IDDIM];
  if (j < FNODE) s[j] = x[(size_t)n * FNODE + j];
  else if (j < FNODE + IDDIM) s[j] = id_emb[(size_t)id_token[n] * IDDIM + (j - FNODE)];
  __syncthreads();
  float acc = inb[j];
#pragma unroll
  for (int k = 0; k < FNODE + IDDIM; ++k) acc = fmaf(s[k], inW[k * HID + j], acc);
  h[(size_t)n * HID + j] = silu_f(acc);
}

// ---------------- per-layer prep: gates=softmax(rel_gate[l]); msg_bias; erel[r] = rel_emb@We[16:24] ----------------
__global__ __launch_bounds__(512) void layer_prep(
    const float* __restrict__ rel_gate, const float* __restrict__ gat_bias,
    const float* __restrict__ rel_emb, const float* __restrict__ We, int l,
    float* __restrict__ gates, float* __restrict__ msg_bias, float* __restrict__ erel) {
  int j = threadIdx.x;
  float g[NR]; float mx = -1e30f;
  for (int r = 0; r < NR; ++r) { g[r] = rel_gate[l * NR + r]; mx = fmaxf(mx, g[r]); }
  float s = 0.f;
  for (int r = 0; r < NR; ++r) { g[r] = expf(g[r] - mx); s += g[r]; }
  for (int r = 0; r < NR; ++r) g[r] /= s;
  if (j < NR) gates[j] = g[j];
  if (j < HID) {
    float b = 0.f;
    for (int r = 0; r < NR; ++r) b = fmaf(g[r], gat_bias[((size_t)(l * NR + r)) * HID + j], b);
    msg_bias[j] = b;
  }
  for (int r = 0; r < NR; ++r) {
    const float* Wer = We + ((size_t)(l * NR + r)) * 24 * 512;
    const float* re  = rel_emb + (l * NR + r) * RELDIM;
    float acc = 0.f;
#pragma unroll
    for (int q = 0; q < RELDIM; ++q) acc = fmaf(re[q], Wer[(FEDGE + q) * 512 + j], acc);
    erel[r * 512 + j] = acc;
  }
}

// ---------------- fills ----------------
__global__ void fill_md(unsigned* __restrict__ menc, float* __restrict__ denom) {
  int i = blockIdx.x * 256 + threadIdx.x;
  if (i < NN * NHEADS) { menc[i] = ENC_NEG_INF; denom[i] = 0.f; }
}
__global__ void fill_zero(float* __restrict__ p, int n) {
  int i = blockIdx.x * 256 + threadIdx.x;
  if (i < n) p[i] = 0.f;
}

// ---------------- edge pass 1: score + segment max ----------------
__global__ __launch_bounds__(128) void edge_score(
    const int* __restrict__ etype, const int* __restrict__ eidx,
    const float* __restrict__ eattr, const float* __restrict__ xl,
    const float* __restrict__ xr, const float* __restrict__ We_r,
    const float* __restrict__ erel_r, const float* __restrict__ att_r,
    int r, float* __restrict__ score, unsigned* __restrict__ menc) {
  int e = blockIdx.x;
  if (etype[e] != r) return;
  int s = eidx[e], t = eidx[NE + e];
  int d = threadIdx.x;
  __shared__ float ea[FEDGE];
  __shared__ float red[2][NHEADS];
  if (d < FEDGE) ea[d] = eattr[(size_t)e * FEDGE + d];
  __syncthreads();
  const float* xls = xl + (size_t)s * 512;
  const float* xrt = xr + (size_t)t * 512;
  float vs[NHEADS];
#pragma unroll
  for (int hh = 0; hh < NHEADS; ++hh) {
    int idx = hh * HID + d;
    float ev = erel_r[idx];
#pragma unroll
    for (int k = 0; k < FEDGE; ++k) ev = fmaf(ea[k], We_r[k * 512 + idx], ev);
    float z = xls[idx] + xrt[idx] + ev;
    z = (z > 0.f) ? z : 0.2f * z;       // leaky_relu 0.2
    float v = z * att_r[hh * HID + d];
#pragma unroll
    for (int off = 32; off > 0; off >>= 1) v += __shfl_down(v, off, 64);
    vs[hh] = v;
  }
  if ((d & 63) == 0) {
#pragma unroll
    for (int hh = 0; hh < NHEADS; ++hh) red[d >> 6][hh] = vs[hh];
  }
  __syncthreads();
  if (d == 0) {
#pragma unroll
    for (int hh = 0; hh < NHEADS; ++hh) {
      float tot = red[0][hh] + red[1][hh];
      score[(size_t)e * NHEADS + hh] = tot;
      atomicMax(&menc[t * NHEADS + hh], fenc(tot));
    }
  }
}

// ---------------- edge pass 2: exp + segment sum ----------------
__global__ void edge_expsum(
    const int* __restrict__ etype, const int* __restrict__ eidx,
    const float* __restrict__ score, const unsigned* __restrict__ menc,
    float* __restrict__ ex, float* __restrict__ denom, int r) {
  int i = blockIdx.x * 256 + threadIdx.x;
  if (i >= NE * NHEADS) return;
  int e = i >> 2, hh = i & 3;
  if (etype[e] != r) return;
  int t = eidx[NE + e];
  float m = fdec(menc[t * NHEADS + hh]);
  float v = expf(score[i] - m);
  ex[i] = v;
  atomicAdd(&denom[t * NHEADS + hh], v);
}

// ---------------- edge pass 3: weighted aggregation (head-mean folded in) ----------------
__global__ __launch_bounds__(128) void edge_agg(
    const int* __restrict__ etype, const int* __restrict__ eidx,
    const float* __restrict__ ex, const float* __restrict__ denom,
    const float* __restrict__ xl, const float* __restrict__ gates,
    float* __restrict__ hmsg, int r) {
  int e = blockIdx.x;
  if (etype[e] != r) return;
  int s = eidx[e], t = eidx[NE + e];
  int d = threadIdx.x;
  float gr = gates[r] * 0.25f;  // head mean folded into segment sum
  float alpha[NHEADS];
#pragma unroll
  for (int hh = 0; hh < NHEADS; ++hh)
    alpha[hh] = ex[(size_t)e * NHEADS + hh] / fmaxf(denom[t * NHEADS + hh], 1e-16f);
  const float* xls = xl + (size_t)s * 512;
  float v = 0.f;
#pragma unroll
  for (int hh = 0; hh < NHEADS; ++hh) v = fmaf(alpha[hh], xls[hh * HID + d], v);
  atomicAdd(&hmsg[(size_t)t * HID + d], gr * v);
}

// ---------------- LayerNorm over 128 dims: h = LN(h + add (+bvec)) * g + b ----------------
__global__ __launch_bounds__(64) void ln128(
    float* __restrict__ h, const float* __restrict__ add, const float* __restrict__ bvec,
    const float* __restrict__ g, const float* __restrict__ b) {
  int n = blockIdx.x, lane = threadIdx.x;
  size_t base = (size_t)n * HID;
  float x0 = h[base + lane] + add[base + lane];
  float x1 = h[base + 64 + lane] + add[base + 64 + lane];
  if (bvec) { x0 += bvec[lane]; x1 += bvec[64 + lane]; }
  float s = x0 + x1;
#pragma unroll
  for (int m = 32; m > 0; m >>= 1) s += __shfl_xor(s, m, 64);
  float mu = s * (1.f / 128.f);
  float d0 = x0 - mu, d1 = x1 - mu;
  float q = d0 * d0 + d1 * d1;
#pragma unroll
  for (int m = 32; m > 0; m >>= 1) q += __shfl_xor(q, m, 64);
  float inv = 1.f / sqrtf(q * (1.f / 128.f) + 1e-5f);
  h[base + lane]      = d0 * inv * g[lane] + b[lane];
  h[base + 64 + lane] = d1 * inv * g[64 + lane] + b[64 + lane];
}

// ---------------- KAN input expansion: u[n] = [silu(v) | B-spline bases(v)] ----------------
// grid points t_j = (j-3)*0.4 - 1, GRID_SIZE=5, ORDER=3, 8 final bases per scalar
__global__ void expand_u(const float* __restrict__ v, float* __restrict__ u, int In, int rows) {
  int i = blockIdx.x * 256 + threadIdx.x;
  if (i >= rows * In) return;
  int n = i / In, c = i % In;
  float x = v[(size_t)n * In + c];
  size_t base = (size_t)n * In * 9;
  u[base + c] = silu_f(x);
  float bb[11];
#pragma unroll
  for (int j = 0; j < 11; ++j) {
    float t0 = (j - 3) * 0.4f - 1.f;
    float t1 = (j - 2) * 0.4f - 1.f;
    bb[j] = (x >= t0 && x < t1) ? 1.f : 0.f;
  }
#pragma unroll
  for (int p = 1; p <= 3; ++p) {
    float inv = 1.f / (0.4f * p);
#pragma unroll
    for (int j = 0; j < 11 - 3; ++j) {   // only need first 11-p, extra iters harmless but wrong—guard below
      if (j < 11 - p) {
        float tj   = (j - 3) * 0.4f - 1.f;
        float tjp1 = (j + p - 2) * 0.4f - 1.f;  // t(j+p+1)
        bb[j] = ((x - tj) * bb[j] + (tjp1 - x) * bb[j + 1]) * inv;
      }
    }
  }
  // note: loops above must cover j up to 11-p-1; p=1 needs j<10 — handled separately below
  float* ub = u + base + In + (size_t)c * 8;
#pragma unroll
  for (int gq = 0; gq < 8; ++gq) ub[gq] = bb[gq];
}

// Correct full-width Cox–de Boor (the kernel above truncates p=1 at j<8; replace logic):
// We re-implement properly here and use THIS kernel instead.
__global__ void expand_u2(const float* __restrict__ v, float* __restrict__ u, int In, int rows) {
  int i = blockIdx.x * 256 + threadIdx.x;
  if (i >= rows * In) return;
  int n = i / In, c = i % In;
  float x = v[(size_t)n * In + c];
  size_t base = (size_t)n * In * 9;
  u[base + c] = silu_f(x);
  float bb[11];
#pragma unroll
  for (int j = 0; j < 11; ++j) {
    float t0 = (j - 3) * 0.4f - 1.f;
    float t1 = (j - 2) * 0.4f - 1.f;
    bb[j] = (x >= t0 && x < t1) ? 1.f : 0.f;
  }
  {
    const float inv = 1.f / 0.4f;
#pragma unroll
    for (int j = 0; j < 10; ++j) {
      float tj = (j - 3) * 0.4f - 1.f, tjp1 = (j - 1) * 0.4f - 1.f;
      bb[j] = ((x - tj) * bb[j] + (tjp1 - x) * bb[j + 1]) * inv;
    }
  }
  {
    const float inv = 1.f / 0.8f;
#pragma unroll
    for (int j = 0; j < 9; ++j) {
      float tj = (j - 3) * 0.4f - 1.f, tjp1 = (j)*0.4f - 1.f;
      bb[j] = ((x - tj) * bb[j] + (tjp1 - x) * bb[j + 1]) * inv;
    }
  }
  {
    const float inv = 1.f / 1.2000001f;  // 0.4f*3 in fp32
#pragma unroll
    for (int j = 0; j < 8; ++j) {
      float tj = (j - 3) * 0.4f - 1.f, tjp1 = (j + 1) * 0.4f - 1.f;
      bb[j] = ((x - tj) * bb[j] + (tjp1 - x) * bb[j + 1]) * inv;
    }
  }
  float* ub = u + base + In + (size_t)c * 8;
#pragma unroll
  for (int gq = 0; gq < 8; ++gq) ub[gq] = bb[gq];
}

// ---------------- build expanded KAN weight: B[k, o], k in [0, In*9) ----------------
__global__ void build_kan_w(const float* __restrict__ base_w, const float* __restrict__ spline_w,
                            const float* __restrict__ scaler, float* __restrict__ B,
                            int In, int Out) {
  int i = blockIdx.x * 256 + threadIdx.x;
  if (i >= In * 9 * Out) return;
  int k = i / Out, o = i % Out;
  float v;
  if (k < In) v = base_w[(size_t)o * In + k];
  else {
    int q = k - In, ii = q >> 3, gq = q & 7;
    v = spline_w[((size_t)o * In + ii) * 8 + gq] * scaler[(size_t)o * In + ii];
  }
  B[i] = v;
}

// ---------------- readout ----------------
__global__ void pool_init(float* __restrict__ mean, unsigned* __restrict__ maxenc, float* __restrict__ cnt) {
  int i = blockIdx.x * 256 + threadIdx.x;
  if (i < NG * HID) { mean[i] = 0.f; maxenc[i] = ENC_NEG_INF; }
  if (i < NG) cnt[i] = 0.f;
}
__global__ __launch_bounds__(128) void pool_accum(
    const float* __restrict__ h, const int* __restrict__ batch,
    float* __restrict__ mean, unsigned* __restrict__ maxenc, float* __restrict__ cnt) {
  int n = blockIdx.x, d = threadIdx.x;
  int g = batch[n];
  float v = h[(size_t)n * HID + d];
  atomicAdd(&mean[g * HID + d], v);
  atomicMax(&maxenc[g * HID + d], fenc(v));
  if (d == 0) atomicAdd(&cnt[g], 1.f);
}
__global__ __launch_bounds__(256) void pool_final_ln(
    const float* __restrict__ mean, const unsigned* __restrict__ maxenc,
    const float* __restrict__ cnt, const float* __restrict__ rog,
    const float* __restrict__ rob, float* __restrict__ gvec) {
  int g = blockIdx.x, j = threadIdx.x;
  __shared__ float rb[256];
  float x;
  if (j < HID) x = mean[g * HID + j] / fmaxf(cnt[g], 1.f);
  else {
    float mv = fdec(maxenc[g * HID + (j - HID)]);
    x = (mv > -1e38f) ? mv : 0.f;  // where(isfinite, ., 0)
  }
  rb[j] = x; __syncthreads();
  for (int st = 128; st > 0; st >>= 1) { if (j < st) rb[j] += rb[j + st]; __syncthreads(); }
  float mu = rb[0] * (1.f / 256.f); __syncthreads();
  float d = x - mu;
  rb[j] = d * d; __syncthreads();
  for (int st = 128; st > 0; st >>= 1) { if (j < st) rb[j] += rb[j + st]; __syncthreads(); }
  float var = rb[0] * (1.f / 256.f);
  float inv = 1.f / sqrtf(var + 1e-5f);
  gvec[(size_t)g * 256 + j] = d * inv * rog[j] + rob[j];
}

// ---------------- small KAN head (reads raw weights, no prebuilt B) ----------------
__global__ void kan_head(const float* __restrict__ u, const float* __restrict__ base_w,
                         const float* __restrict__ spline_w, const float* __restrict__ scaler,
                         float* __restrict__ out, int In, int Out) {
  int o = blockIdx.x * 64 + threadIdx.x;
  int g = blockIdx.y;
  if (o >= Out) return;
  const float* ug = u + (size_t)g * In * 9;
  float acc = 0.f;
  for (int i = 0; i < In; ++i) acc = fmaf(ug[i], base_w[(size_t)o * In + i], acc);
  for (int i = 0; i < In; ++i) {
    const float* sp = spline_w + ((size_t)o * In + i) * 8;
    const float* ub = ug + In + (size_t)i * 8;
    float a2 = 0.f;
#pragma unroll
    for (int gq = 0; gq < 8; ++gq) a2 = fmaf(ub[gq], sp[gq], a2);
    acc = fmaf(scaler[(size_t)o * In + i], a2, acc);
  }
  out[(size_t)g * Out + o] = acc;
}

// ---------------- launch ----------------
extern "C" void kernel_launch(void* const* d_in, const int* in_sizes, int n_in,
                              void* d_out, int out_size, void* d_ws, size_t ws_size,
                              hipStream_t stream) {
  const float* x         = (const float*)d_in[0];
  const float* edge_attr = (const float*)d_in[1];
  const int*   id_token  = (const int*)  d_in[2];
  const int*   edge_index= (const int*)  d_in[3];
  const int*   edge_type = (const int*)  d_in[4];
  const int*   batch     = (const int*)  d_in[5];
  const float* id_emb    = (const float*)d_in[6];
  const float* inW       = (const float*)d_in[7];
  const float* inb       = (const float*)d_in[8];
  const float* Wl        = (const float*)d_in[9];
  const float* bl        = (const float*)d_in[10];
  const float* Wr        = (const float*)d_in[11];
  const float* br        = (const float*)d_in[12];
  const float* We        = (const float*)d_in[13];
  const float* att       = (const float*)d_in[14];
  const float* gat_bias  = (const float*)d_in[15];
  const float* rel_gate  = (const float*)d_in[16];
  const float* rel_emb   = (const float*)d_in[17];
  const float* ln1g      = (const float*)d_in[18];
  const float* ln1b      = (const float*)d_in[19];
  const float* ln2g      = (const float*)d_in[20];
  const float* ln2b      = (const float*)d_in[21];
  const float* ffn1_base = (const float*)d_in[22];
  const float* ffn1_spl  = (const float*)d_in[23];
  const float* ffn1_sc   = (const float*)d_in[24];
  const float* ffn2_base = (const float*)d_in[25];
  const float* ffn2_spl  = (const float*)d_in[26];
  const float* ffn2_sc   = (const float*)d_in[27];
  const float* rog       = (const float*)d_in[28];
  const float* rob       = (const float*)d_in[29];
  const float* h1_base   = (const float*)d_in[30];
  const float* h1_spl    = (const float*)d_in[31];
  const float* h1_sc     = (const float*)d_in[32];
  const float* h2_base   = (const float*)d_in[33];
  const float* h2_spl    = (const float*)d_in[34];
  const float* h2_sc     = (const float*)d_in[35];
  (void)in_sizes; (void)n_in; (void)out_size; (void)ws_size;

  // ---- workspace carve (256B aligned) ----
  char* wsp = (char*)d_ws;
  size_t off = 0;
  auto carve = [&](size_t bytes) { char* p = wsp + off; off = (off + bytes + 255) & ~(size_t)255; return p; };
  float*    h     = (float*)   carve((size_t)NN * HID * 4);
  float*    hmsg  = (float*)   carve((size_t)NN * HID * 4);     // also h_ffn
  float*    t1    = (float*)   carve((size_t)NN * FFNH * 4);    // ffn intermediate
  unsigned* menc  = (unsigned*)carve((size_t)NN * NHEADS * 4);
  float*    denom = (float*)   carve((size_t)NN * NHEADS * 4);
  float*    gates = (float*)   carve(NR * 4);
  float*    msgb  = (float*)   carve(HID * 4);
  float*    erel  = (float*)   carve(NR * 512 * 4);
  float*    Bw1   = (float*)   carve((size_t)HID * 9 * FFNH * 4);   // [1152,256]
  float*    Bw2   = (float*)   carve((size_t)FFNH * 9 * HID * 4);   // [2304,128]
  float*    pm    = (float*)   carve((size_t)NG * HID * 4);
  unsigned* pmax  = (unsigned*)carve((size_t)NG * HID * 4);
  float*    cnt   = (float*)   carve(NG * 4);
  float*    gvec  = (float*)   carve((size_t)NG * 256 * 4);
  float*    uhead = (float*)   carve((size_t)NG * 256 * 9 * 4);
  float*    thead = (float*)   carve((size_t)NG * HEADH * 4);
  // union arena: message phase {xl, xr, score, ex} vs FFN phase {u}
  char*  arena = carve((size_t)NN * FFNH * 9 * 4);  // 92.16 MB (u2 is largest)
  float* xl    = (float*)arena;
  float* xr    = xl + (size_t)NN * 512;
  float* score = xr + (size_t)NN * 512;
  float* exbuf = score + (size_t)NE * NHEADS;
  float* ubuf  = (float*)arena;

  // ---- input projection ----
  input_proj<<<NN, 128, 0, stream>>>(x, id_emb, id_token, inW, inb, h);

  for (int l = 0; l < NL; ++l) {
    layer_prep<<<1, 512, 0, stream>>>(rel_gate, gat_bias, rel_emb, We, l, gates, msgb, erel);
    fill_zero<<<(NN * HID + 255) / 256, 256, 0, stream>>>(hmsg, NN * HID);
    for (int r = 0; r < NR; ++r) {
      const float* Wlr = Wl + ((size_t)(l * NR + r)) * HID * 512;
      const float* blr = bl + (size_t)(l * NR + r) * 512;
      const float* Wrr = Wr + ((size_t)(l * NR + r)) * HID * 512;
      const float* brr = br + (size_t)(l * NR + r) * 512;
      const float* Wer = We + ((size_t)(l * NR + r)) * 24 * 512;
      const float* attr = att + (size_t)(l * NR + r) * 512;
      dim3 gg(512 / 64, (NN + 63) / 64);
      sgemm_bias<<<gg, 256, 0, stream>>>(h, Wlr, blr, xl, NN, HID, 512);
      sgemm_bias<<<gg, 256, 0, stream>>>(h, Wrr, brr, xr, NN, HID, 512);
      fill_md<<<(NN * NHEADS + 255) / 256, 256, 0, stream>>>(menc, denom);
      edge_score<<<NE, 128, 0, stream>>>(edge_type, edge_index, edge_attr, xl, xr,
                                         Wer, erel + r * 512, attr, r, score, menc);
      edge_expsum<<<(NE * NHEADS + 255) / 256, 256, 0, stream>>>(edge_type, edge_index,
                                                                 score, menc, exbuf, denom, r);
      edge_agg<<<NE, 128, 0, stream>>>(edge_type, edge_index, exbuf, denom, xl, gates, hmsg, r);
    }
    ln128<<<NN, 64, 0, stream>>>(h, hmsg, msgb, ln1g + l * HID, ln1b + l * HID);

    // ---- KAN FFN1: 128 -> 256 ----
    build_kan_w<<<((HID * 9 * FFNH) + 255) / 256, 256, 0, stream>>>(
        ffn1_base + (size_t)l * FFNH * HID, ffn1_spl + (size_t)l * FFNH * HID * 8,
        ffn1_sc + (size_t)l * FFNH * HID, Bw1, HID, FFNH);
    expand_u2<<<((NN * HID) + 255) / 256, 256, 0, stream>>>(h, ubuf, HID, NN);
    {
      dim3 g1(FFNH / 64, (NN + 63) / 64);
      sgemm_bias<<<g1, 256, 0, stream>>>(ubuf, Bw1, nullptr, t1, NN, HID * 9, FFNH);
    }
    // ---- KAN FFN2: 256 -> 128 ----
    build_kan_w<<<((FFNH * 9 * HID) + 255) / 256, 256, 0, stream>>>(
        ffn2_base + (size_t)l * HID * FFNH, ffn2_spl + (size_t)l * HID * FFNH * 8,
        ffn2_sc + (size_t)l * HID * FFNH, Bw2, FFNH, HID);
    expand_u2<<<((NN * FFNH) + 255) / 256, 256, 0, stream>>>(t1, ubuf, FFNH, NN);
    {
      dim3 g2(HID / 64, (NN + 63) / 64);
      sgemm_bias<<<g2, 256, 0, stream>>>(ubuf, Bw2, nullptr, hmsg, NN, FFNH * 9, HID);
    }
    ln128<<<NN, 64, 0, stream>>>(h, hmsg, nullptr, ln2g + l * HID, ln2b + l * HID);
  }

  // ---- readout ----
  pool_init<<<(NG * HID + 255) / 256, 256, 0, stream>>>(pm, pmax, cnt);
  pool_accum<<<NN, 128, 0, stream>>>(h, batch, pm, pmax, cnt);
  pool_final_ln<<<NG, 256, 0, stream>>>(pm, pmax, cnt, rog, rob, gvec);
  expand_u2<<<((NG * 256) + 255) / 256, 256, 0, stream>>>(gvec, uhead, 256, NG);
  kan_head<<<dim3(2, NG), 64, 0, stream>>>(uhead, h1_base, h1_spl, h1_sc, thead, 256, HEADH);
  expand_u2<<<((NG * HEADH) + 255) / 256, 256, 0, stream>>>(thead, uhead, HEADH, NG);
  kan_head<<<dim3(1, NG), 64, 0, stream>>>(uhead, h2_base, h2_spl, h2_sc, (float*)d_out, HEADH, NCLS);
}

// Round 3
// 3227.794 us; speedup vs baseline: 1.1198x; 1.1198x over previous
//
#include <hip/hip_runtime.h>
#include <cstdint>
#include <cstddef>

// ---------------- static problem config ----------------
#define NN      10000   // nodes
#define NE      120000  // edges
#define NG      32      // graphs
#define FNODE   64
#define FEDGE   16
#define HID     128
#define NHEADS  4
#define NL      3
#define NR      4
#define IDDIM   32
#define RELDIM  8
#define FFNH    256
#define HEADH   128
#define NCLS    10

typedef __attribute__((ext_vector_type(8))) short short8;
typedef __attribute__((ext_vector_type(4))) float floatx4;

// ---------------- helpers ----------------
__device__ __forceinline__ unsigned fenc(float f) {
  unsigned u = __float_as_uint(f);
  return (u & 0x80000000u) ? ~u : (u | 0x80000000u);
}
__device__ __forceinline__ float fdec(unsigned k) {
  return __uint_as_float((k & 0x80000000u) ? (k ^ 0x80000000u) : ~k);
}
__device__ __forceinline__ float silu_f(float x) { return x / (1.f + expf(-x)); }
__device__ __forceinline__ ushort f2bf(float f) {   // round-to-nearest-even bf16
  unsigned u = __float_as_uint(f);
  return (ushort)((u + 0x7FFFu + ((u >> 16) & 1u)) >> 16);
}
__device__ __forceinline__ float bf2f(ushort h) { return __uint_as_float((unsigned)h << 16); }

#define ENC_NEG_INF 0x007FFFFFu

// ---------------- split-bf16 MFMA GEMM: C[M,N] = A[M,K] @ BT[N,K]^T (+bias) ----------------
// A: fp32 [M,K]. BT: fp32 [N,K]. C: fp32 [M,N]. Split to hi/lo bf16 during LDS staging;
// D = Ah*Bh + Al*Bh + Ah*Bl (3xTF32-style, ~fp32 precision, drops lo*lo ~2^-18 rel).
// BM=128, BN=64, BK=64, 256 threads (4 waves). K%64==0, N%64==0. M guarded.
__global__ __launch_bounds__(256) void gemm_x2(
    const float* __restrict__ A, const float* __restrict__ BT,
    const float* __restrict__ bias, float* __restrict__ C,
    int M, int K, int N) {
  constexpr int LDA = 72;   // 64 + 8 pad (bf16 elems)
  __shared__ __align__(16) ushort Ah[128 * LDA];
  __shared__ __align__(16) ushort Al[128 * LDA];
  __shared__ __align__(16) ushort Bh[64 * LDA];
  __shared__ __align__(16) ushort Bl[64 * LDA];
  const int tid = threadIdx.x;
  const int lane = tid & 63, wave = tid >> 6;
  const int lrow = lane & 15, quad = lane >> 4;
  const int bm = blockIdx.y * 128, bn = blockIdx.x * 64;
  floatx4 acc[2][4] = {};
  for (int k0 = 0; k0 < K; k0 += 64) {
    // stage A: 128 rows x 64 cols fp32 (32 KB), float4 chunks, 8/thread
#pragma unroll
    for (int i = 0; i < 8; ++i) {
      int c = tid + i * 256;
      int row = c >> 4, col4 = c & 15;
      int gr = bm + row;
      float4 v = make_float4(0.f, 0.f, 0.f, 0.f);
      if (gr < M) v = *(const float4*)(A + (size_t)gr * K + k0 + col4 * 4);
      float vv[4] = {v.x, v.y, v.z, v.w};
      unsigned h01, h23, l01, l23;
      {
        ushort h0 = f2bf(vv[0]), h1 = f2bf(vv[1]), h2 = f2bf(vv[2]), h3 = f2bf(vv[3]);
        ushort l0 = f2bf(vv[0] - bf2f(h0)), l1 = f2bf(vv[1] - bf2f(h1));
        ushort l2 = f2bf(vv[2] - bf2f(h2)), l3 = f2bf(vv[3] - bf2f(h3));
        h01 = (unsigned)h0 | ((unsigned)h1 << 16); h23 = (unsigned)h2 | ((unsigned)h3 << 16);
        l01 = (unsigned)l0 | ((unsigned)l1 << 16); l23 = (unsigned)l2 | ((unsigned)l3 << 16);
      }
      *(uint2*)&Ah[row * LDA + col4 * 4] = make_uint2(h01, h23);
      *(uint2*)&Al[row * LDA + col4 * 4] = make_uint2(l01, l23);
    }
    // stage BT: 64 rows x 64 cols fp32 (16 KB), 4/thread
#pragma unroll
    for (int i = 0; i < 4; ++i) {
      int c = tid + i * 256;
      int row = c >> 4, col4 = c & 15;
      float4 v = *(const float4*)(BT + (size_t)(bn + row) * K + k0 + col4 * 4);
      float vv[4] = {v.x, v.y, v.z, v.w};
      unsigned h01, h23, l01, l23;
      {
        ushort h0 = f2bf(vv[0]), h1 = f2bf(vv[1]), h2 = f2bf(vv[2]), h3 = f2bf(vv[3]);
        ushort l0 = f2bf(vv[0] - bf2f(h0)), l1 = f2bf(vv[1] - bf2f(h1));
        ushort l2 = f2bf(vv[2] - bf2f(h2)), l3 = f2bf(vv[3] - bf2f(h3));
        h01 = (unsigned)h0 | ((unsigned)h1 << 16); h23 = (unsigned)h2 | ((unsigned)h3 << 16);
        l01 = (unsigned)l0 | ((unsigned)l1 << 16); l23 = (unsigned)l2 | ((unsigned)l3 << 16);
      }
      *(uint2*)&Bh[row * LDA + col4 * 4] = make_uint2(h01, h23);
      *(uint2*)&Bl[row * LDA + col4 * 4] = make_uint2(l01, l23);
    }
    __syncthreads();
#pragma unroll
    for (int kk = 0; kk < 64; kk += 32) {
      int kof = kk + quad * 8;
      const int ra0 = (wave * 32 + lrow) * LDA + kof;
      const int ra1 = (wave * 32 + 16 + lrow) * LDA + kof;
      short8 ah0 = *(const short8*)&Ah[ra0];
      short8 ah1 = *(const short8*)&Ah[ra1];
      short8 al0 = *(const short8*)&Al[ra0];
      short8 al1 = *(const short8*)&Al[ra1];
      short8 bh[4], blo[4];
#pragma unroll
      for (int nt = 0; nt < 4; ++nt) {
        int rb = (nt * 16 + lrow) * LDA + kof;
        bh[nt]  = *(const short8*)&Bh[rb];
        blo[nt] = *(const short8*)&Bl[rb];
      }
#pragma unroll
      for (int nt = 0; nt < 4; ++nt) {
        acc[0][nt] = __builtin_amdgcn_mfma_f32_16x16x32_bf16(ah0, bh[nt],  acc[0][nt], 0, 0, 0);
        acc[1][nt] = __builtin_amdgcn_mfma_f32_16x16x32_bf16(ah1, bh[nt],  acc[1][nt], 0, 0, 0);
        acc[0][nt] = __builtin_amdgcn_mfma_f32_16x16x32_bf16(al0, bh[nt],  acc[0][nt], 0, 0, 0);
        acc[1][nt] = __builtin_amdgcn_mfma_f32_16x16x32_bf16(al1, bh[nt],  acc[1][nt], 0, 0, 0);
        acc[0][nt] = __builtin_amdgcn_mfma_f32_16x16x32_bf16(ah0, blo[nt], acc[0][nt], 0, 0, 0);
        acc[1][nt] = __builtin_amdgcn_mfma_f32_16x16x32_bf16(ah1, blo[nt], acc[1][nt], 0, 0, 0);
      }
    }
    __syncthreads();
  }
  // epilogue: D layout col=lane&15, row=quad*4+reg (m89-verified)
#pragma unroll
  for (int mt = 0; mt < 2; ++mt) {
#pragma unroll
    for (int nt = 0; nt < 4; ++nt) {
#pragma unroll
      for (int reg = 0; reg < 4; ++reg) {
        int row = bm + wave * 32 + mt * 16 + quad * 4 + reg;
        int col = bn + nt * 16 + lrow;
        if (row < M) {
          float v = acc[mt][nt][reg];
          if (bias) v += bias[col];
          C[(size_t)row * N + col] = v;
        }
      }
    }
  }
}

// ---------------- weight transpose (fp32): W[G][128][512] -> WT [G][512][128] ----------------
__global__ void conv_wT(const float* __restrict__ W, float* __restrict__ WT, int total) {
  int i = blockIdx.x * 256 + threadIdx.x;
  if (i >= total) return;
  int g = i / (512 * 128), rem = i % (512 * 128);
  int n = rem >> 7, k = rem & 127;
  WT[i] = W[(size_t)g * 65536 + k * 512 + n];
}

// ---------------- input projection: h = silu(concat(x, id_emb[tok]) @ inW + inb) ----------------
__global__ __launch_bounds__(128) void input_proj(
    const float* __restrict__ x, const float* __restrict__ id_emb,
    const int* __restrict__ id_token, const float* __restrict__ inW,
    const float* __restrict__ inb, float* __restrict__ h) {
  int n = blockIdx.x, j = threadIdx.x;
  __shared__ float s[FNODE + IDDIM];
  if (j < FNODE) s[j] = x[(size_t)n * FNODE + j];
  else if (j < FNODE + IDDIM) s[j] = id_emb[(size_t)id_token[n] * IDDIM + (j - FNODE)];
  __syncthreads();
  float acc = inb[j];
#pragma unroll
  for (int k = 0; k < FNODE + IDDIM; ++k) acc = fmaf(s[k], inW[k * HID + j], acc);
  h[(size_t)n * HID + j] = silu_f(acc);
}

// ---------------- per-layer prep ----------------
__global__ __launch_bounds__(512) void layer_prep(
    const float* __restrict__ rel_gate, const float* __restrict__ gat_bias,
    const float* __restrict__ rel_emb, const float* __restrict__ We, int l,
    float* __restrict__ gates, float* __restrict__ msg_bias, float* __restrict__ erel) {
  int j = threadIdx.x;
  float g[NR]; float mx = -1e30f;
  for (int r = 0; r < NR; ++r) { g[r] = rel_gate[l * NR + r]; mx = fmaxf(mx, g[r]); }
  float s = 0.f;
  for (int r = 0; r < NR; ++r) { g[r] = expf(g[r] - mx); s += g[r]; }
  for (int r = 0; r < NR; ++r) g[r] /= s;
  if (j < NR) gates[j] = g[j];
  if (j < HID) {
    float b = 0.f;
    for (int r = 0; r < NR; ++r) b = fmaf(g[r], gat_bias[((size_t)(l * NR + r)) * HID + j], b);
    msg_bias[j] = b;
  }
  for (int r = 0; r < NR; ++r) {
    const float* Wer = We + ((size_t)(l * NR + r)) * 24 * 512;
    const float* re  = rel_emb + (l * NR + r) * RELDIM;
    float acc = 0.f;
#pragma unroll
    for (int q = 0; q < RELDIM; ++q) acc = fmaf(re[q], Wer[(FEDGE + q) * 512 + j], acc);
    erel[r * 512 + j] = acc;
  }
}

// ---------------- fills ----------------
__global__ void fill_md(unsigned* __restrict__ menc, float* __restrict__ denom) {
  int i = blockIdx.x * 256 + threadIdx.x;
  if (i < NN * NHEADS) { menc[i] = ENC_NEG_INF; denom[i] = 0.f; }
}
__global__ void fill_zero(float* __restrict__ p, int n) {
  int i = blockIdx.x * 256 + threadIdx.x;
  if (i < n) p[i] = 0.f;
}

// ---------------- edge pass 1: score + segment max ----------------
__global__ __launch_bounds__(128) void edge_score(
    const int* __restrict__ etype, const int* __restrict__ eidx,
    const float* __restrict__ eattr, const float* __restrict__ xl,
    const float* __restrict__ xr, const float* __restrict__ We_r,
    const float* __restrict__ erel_r, const float* __restrict__ att_r,
    int r, float* __restrict__ score, unsigned* __restrict__ menc) {
  int e = blockIdx.x;
  if (etype[e] != r) return;
  int s = eidx[e], t = eidx[NE + e];
  int d = threadIdx.x;
  __shared__ float ea[FEDGE];
  __shared__ float red[2][NHEADS];
  if (d < FEDGE) ea[d] = eattr[(size_t)e * FEDGE + d];
  __syncthreads();
  const float* xls = xl + (size_t)s * 512;
  const float* xrt = xr + (size_t)t * 512;
  float vs[NHEADS];
#pragma unroll
  for (int hh = 0; hh < NHEADS; ++hh) {
    int idx = hh * HID + d;
    float ev = erel_r[idx];
#pragma unroll
    for (int k = 0; k < FEDGE; ++k) ev = fmaf(ea[k], We_r[k * 512 + idx], ev);
    float z = xls[idx] + xrt[idx] + ev;
    z = (z > 0.f) ? z : 0.2f * z;       // leaky_relu 0.2
    float v = z * att_r[hh * HID + d];
#pragma unroll
    for (int off = 32; off > 0; off >>= 1) v += __shfl_down(v, off, 64);
    vs[hh] = v;
  }
  if ((d & 63) == 0) {
#pragma unroll
    for (int hh = 0; hh < NHEADS; ++hh) red[d >> 6][hh] = vs[hh];
  }
  __syncthreads();
  if (d == 0) {
#pragma unroll
    for (int hh = 0; hh < NHEADS; ++hh) {
      float tot = red[0][hh] + red[1][hh];
      score[(size_t)e * NHEADS + hh] = tot;
      atomicMax(&menc[t * NHEADS + hh], fenc(tot));
    }
  }
}

// ---------------- edge pass 2: exp + segment sum ----------------
__global__ void edge_expsum(
    const int* __restrict__ etype, const int* __restrict__ eidx,
    const float* __restrict__ score, const unsigned* __restrict__ menc,
    float* __restrict__ ex, float* __restrict__ denom, int r) {
  int i = blockIdx.x * 256 + threadIdx.x;
  if (i >= NE * NHEADS) return;
  int e = i >> 2, hh = i & 3;
  if (etype[e] != r) return;
  int t = eidx[NE + e];
  float m = fdec(menc[t * NHEADS + hh]);
  float v = expf(score[i] - m);
  ex[i] = v;
  atomicAdd(&denom[t * NHEADS + hh], v);
}

// ---------------- edge pass 3: weighted aggregation (head-mean folded in) ----------------
__global__ __launch_bounds__(128) void edge_agg(
    const int* __restrict__ etype, const int* __restrict__ eidx,
    const float* __restrict__ ex, const float* __restrict__ denom,
    const float* __restrict__ xl, const float* __restrict__ gates,
    float* __restrict__ hmsg, int r) {
  int e = blockIdx.x;
  if (etype[e] != r) return;
  int s = eidx[e], t = eidx[NE + e];
  int d = threadIdx.x;
  float gr = gates[r] * 0.25f;  // head mean folded into segment sum
  float alpha[NHEADS];
#pragma unroll
  for (int hh = 0; hh < NHEADS; ++hh)
    alpha[hh] = ex[(size_t)e * NHEADS + hh] / fmaxf(denom[t * NHEADS + hh], 1e-16f);
  const float* xls = xl + (size_t)s * 512;
  float v = 0.f;
#pragma unroll
  for (int hh = 0; hh < NHEADS; ++hh) v = fmaf(alpha[hh], xls[hh * HID + d], v);
  atomicAdd(&hmsg[(size_t)t * HID + d], gr * v);
}

// ---------------- LayerNorm over 128 dims: h = LN(h + add (+bvec)) * g + b ----------------
__global__ __launch_bounds__(64) void ln128(
    float* __restrict__ h, const float* __restrict__ add, const float* __restrict__ bvec,
    const float* __restrict__ g, const float* __restrict__ b) {
  int n = blockIdx.x, lane = threadIdx.x;
  size_t base = (size_t)n * HID;
  float x0 = h[base + lane] + add[base + lane];
  float x1 = h[base + 64 + lane] + add[base + 64 + lane];
  if (bvec) { x0 += bvec[lane]; x1 += bvec[64 + lane]; }
  float s = x0 + x1;
#pragma unroll
  for (int m = 32; m > 0; m >>= 1) s += __shfl_xor(s, m, 64);
  float mu = s * (1.f / 128.f);
  float d0 = x0 - mu, d1 = x1 - mu;
  float q = d0 * d0 + d1 * d1;
#pragma unroll
  for (int m = 32; m > 0; m >>= 1) q += __shfl_xor(q, m, 64);
  float inv = 1.f / sqrtf(q * (1.f / 128.f) + 1e-5f);
  h[base + lane]      = d0 * inv * g[lane] + b[lane];
  h[base + 64 + lane] = d1 * inv * g[64 + lane] + b[64 + lane];
}

// ---------------- KAN input expansion (fp32): u[n] = [silu(v) | bases(v)] ----------------
// grid t_j = (j-3)*0.4 - 1; GRID_SIZE=5, ORDER=3, 8 final cubic bases per scalar
__global__ void expand_f32(const float* __restrict__ v, float* __restrict__ u, int In, int rows) {
  int i = blockIdx.x * 256 + threadIdx.x;
  if (i >= rows * In) return;
  int n = i / In, c = i % In;
  float x = v[(size_t)n * In + c];
  size_t base = (size_t)n * In * 9;
  u[base + c] = silu_f(x);
  float bb[11];
#pragma unroll
  for (int j = 0; j < 11; ++j) {
    float t0 = (j - 3) * 0.4f - 1.f;
    float t1 = (j - 2) * 0.4f - 1.f;
    bb[j] = (x >= t0 && x < t1) ? 1.f : 0.f;
  }
  {
    const float inv = 1.f / 0.4f;
#pragma unroll
    for (int j = 0; j < 10; ++j) {
      float tj = (j - 3) * 0.4f - 1.f, tjp1 = (j - 1) * 0.4f - 1.f;
      bb[j] = ((x - tj) * bb[j] + (tjp1 - x) * bb[j + 1]) * inv;
    }
  }
  {
    const float inv = 1.f / 0.8f;
#pragma unroll
    for (int j = 0; j < 9; ++j) {
      float tj = (j - 3) * 0.4f - 1.f, tjp1 = (j) * 0.4f - 1.f;
      bb[j] = ((x - tj) * bb[j] + (tjp1 - x) * bb[j + 1]) * inv;
    }
  }
  {
    const float inv = 1.f / 1.2000001f;
#pragma unroll
    for (int j = 0; j < 8; ++j) {
      float tj = (j - 3) * 0.4f - 1.f, tjp1 = (j + 1) * 0.4f - 1.f;
      bb[j] = ((x - tj) * bb[j] + (tjp1 - x) * bb[j + 1]) * inv;
    }
  }
  float* ub = u + base + In + (size_t)c * 8;
#pragma unroll
  for (int gq = 0; gq < 8; ++gq) ub[gq] = bb[gq];
}

// ---------------- build expanded KAN weight, transposed fp32: BT[o, k], k in [0, In*9) ----------------
__global__ void build_kan_wT(const float* __restrict__ base_w, const float* __restrict__ spline_w,
                             const float* __restrict__ scaler, float* __restrict__ BT,
                             int In, int Out) {
  int i = blockIdx.x * 256 + threadIdx.x;
  if (i >= In * 9 * Out) return;
  int o = i / (In * 9), k = i % (In * 9);
  float v;
  if (k < In) v = base_w[(size_t)o * In + k];
  else {
    int q = k - In, ii = q >> 3, gq = q & 7;
    v = spline_w[((size_t)o * In + ii) * 8 + gq] * scaler[(size_t)o * In + ii];
  }
  BT[i] = v;
}

// ---------------- readout ----------------
__global__ void pool_init(float* __restrict__ mean, unsigned* __restrict__ maxenc, float* __restrict__ cnt) {
  int i = blockIdx.x * 256 + threadIdx.x;
  if (i < NG * HID) { mean[i] = 0.f; maxenc[i] = ENC_NEG_INF; }
  if (i < NG) cnt[i] = 0.f;
}
__global__ __launch_bounds__(128) void pool_accum(
    const float* __restrict__ h, const int* __restrict__ batch,
    float* __restrict__ mean, unsigned* __restrict__ maxenc, float* __restrict__ cnt) {
  int n = blockIdx.x, d = threadIdx.x;
  int g = batch[n];
  float v = h[(size_t)n * HID + d];
  atomicAdd(&mean[g * HID + d], v);
  atomicMax(&maxenc[g * HID + d], fenc(v));
  if (d == 0) atomicAdd(&cnt[g], 1.f);
}
__global__ __launch_bounds__(256) void pool_final_ln(
    const float* __restrict__ mean, const unsigned* __restrict__ maxenc,
    const float* __restrict__ cnt, const float* __restrict__ rog,
    const float* __restrict__ rob, float* __restrict__ gvec) {
  int g = blockIdx.x, j = threadIdx.x;
  __shared__ float rb[256];
  float x;
  if (j < HID) x = mean[g * HID + j] / fmaxf(cnt[g], 1.f);
  else {
    float mv = fdec(maxenc[g * HID + (j - HID)]);
    x = (mv > -1e38f) ? mv : 0.f;  // where(isfinite, ., 0)
  }
  rb[j] = x; __syncthreads();
  for (int st = 128; st > 0; st >>= 1) { if (j < st) rb[j] += rb[j + st]; __syncthreads(); }
  float mu = rb[0] * (1.f / 256.f); __syncthreads();
  float d = x - mu;
  rb[j] = d * d; __syncthreads();
  for (int st = 128; st > 0; st >>= 1) { if (j < st) rb[j] += rb[j + st]; __syncthreads(); }
  float var = rb[0] * (1.f / 256.f);
  float inv = 1.f / sqrtf(var + 1e-5f);
  gvec[(size_t)g * 256 + j] = d * inv * rog[j] + rob[j];
}

// ---------------- small KAN head (fp32, reads raw weights) ----------------
__global__ void kan_head(const float* __restrict__ u, const float* __restrict__ base_w,
                         const float* __restrict__ spline_w, const float* __restrict__ scaler,
                         float* __restrict__ out, int In, int Out) {
  int o = blockIdx.x * 64 + threadIdx.x;
  int g = blockIdx.y;
  if (o >= Out) return;
  const float* ug = u + (size_t)g * In * 9;
  float acc = 0.f;
  for (int i = 0; i < In; ++i) acc = fmaf(ug[i], base_w[(size_t)o * In + i], acc);
  for (int i = 0; i < In; ++i) {
    const float* sp = spline_w + ((size_t)o * In + i) * 8;
    const float* ub = ug + In + (size_t)i * 8;
    float a2 = 0.f;
#pragma unroll
    for (int gq = 0; gq < 8; ++gq) a2 = fmaf(ub[gq], sp[gq], a2);
    acc = fmaf(scaler[(size_t)o * In + i], a2, acc);
  }
  out[(size_t)g * Out + o] = acc;
}

// ---------------- launch ----------------
extern "C" void kernel_launch(void* const* d_in, const int* in_sizes, int n_in,
                              void* d_out, int out_size, void* d_ws, size_t ws_size,
                              hipStream_t stream) {
  const float* x         = (const float*)d_in[0];
  const float* edge_attr = (const float*)d_in[1];
  const int*   id_token  = (const int*)  d_in[2];
  const int*   edge_index= (const int*)  d_in[3];
  const int*   edge_type = (const int*)  d_in[4];
  const int*   batch     = (const int*)  d_in[5];
  const float* id_emb    = (const float*)d_in[6];
  const float* inW       = (const float*)d_in[7];
  const float* inb       = (const float*)d_in[8];
  const float* Wl        = (const float*)d_in[9];
  const float* bl        = (const float*)d_in[10];
  const float* Wr        = (const float*)d_in[11];
  const float* br        = (const float*)d_in[12];
  const float* We        = (const float*)d_in[13];
  const float* att       = (const float*)d_in[14];
  const float* gat_bias  = (const float*)d_in[15];
  const float* rel_gate  = (const float*)d_in[16];
  const float* rel_emb   = (const float*)d_in[17];
  const float* ln1g      = (const float*)d_in[18];
  const float* ln1b      = (const float*)d_in[19];
  const float* ln2g      = (const float*)d_in[20];
  const float* ln2b      = (const float*)d_in[21];
  const float* ffn1_base = (const float*)d_in[22];
  const float* ffn1_spl  = (const float*)d_in[23];
  const float* ffn1_sc   = (const float*)d_in[24];
  const float* ffn2_base = (const float*)d_in[25];
  const float* ffn2_spl  = (const float*)d_in[26];
  const float* ffn2_sc   = (const float*)d_in[27];
  const float* rog       = (const float*)d_in[28];
  const float* rob       = (const float*)d_in[29];
  const float* h1_base   = (const float*)d_in[30];
  const float* h1_spl    = (const float*)d_in[31];
  const float* h1_sc     = (const float*)d_in[32];
  const float* h2_base   = (const float*)d_in[33];
  const float* h2_spl    = (const float*)d_in[34];
  const float* h2_sc     = (const float*)d_in[35];
  (void)in_sizes; (void)n_in; (void)out_size; (void)ws_size;

  // ---- workspace carve (256B aligned) ----
  char* wsp = (char*)d_ws;
  size_t off = 0;
  auto carve = [&](size_t bytes) { char* p = wsp + off; off = (off + bytes + 255) & ~(size_t)255; return p; };
  float*    h     = (float*)   carve((size_t)NN * HID * 4);
  float*    hmsg  = (float*)   carve((size_t)NN * HID * 4);     // also h_ffn
  float*    t1    = (float*)   carve((size_t)NN * FFNH * 4);    // ffn intermediate
  unsigned* menc  = (unsigned*)carve((size_t)NN * NHEADS * 4);
  float*    denom = (float*)   carve((size_t)NN * NHEADS * 4);
  float*    gates = (float*)   carve(NR * 4);
  float*    msgb  = (float*)   carve(HID * 4);
  float*    erel  = (float*)   carve(NR * 512 * 4);
  float*    WlT   = (float*)   carve((size_t)NL * NR * 512 * HID * 4);
  float*    WrT   = (float*)   carve((size_t)NL * NR * 512 * HID * 4);
  float*    BwT1  = (float*)   carve((size_t)FFNH * HID * 9 * 4);   // [256][1152]
  float*    BwT2  = (float*)   carve((size_t)HID * FFNH * 9 * 4);   // [128][2304]
  float*    pm    = (float*)   carve((size_t)NG * HID * 4);
  unsigned* pmax  = (unsigned*)carve((size_t)NG * HID * 4);
  float*    cnt   = (float*)   carve(NG * 4);
  float*    gvec  = (float*)   carve((size_t)NG * 256 * 4);
  float*    uhead = (float*)   carve((size_t)NG * 256 * 9 * 4);
  float*    thead = (float*)   carve((size_t)NG * HEADH * 4);
  // union arena: message phase {xl, xr, score, ex} vs FFN phase {u fp32}
  size_t msg_bytes = (size_t)NN * 512 * 4 * 2 + (size_t)NE * NHEADS * 4 * 2;
  size_t ffn_bytes = (size_t)NN * FFNH * 9 * 4;
  char*  arena = carve(msg_bytes > ffn_bytes ? msg_bytes : ffn_bytes);
  float* xl    = (float*)arena;
  float* xr    = xl + (size_t)NN * 512;
  float* score = xr + (size_t)NN * 512;
  float* exbuf = score + (size_t)NE * NHEADS;
  float* ubuf  = (float*)arena;

  // ---- weight transpose (once per launch) ----
  {
    int total = NL * NR * 512 * HID;
    conv_wT<<<(total + 255) / 256, 256, 0, stream>>>(Wl, WlT, total);
    conv_wT<<<(total + 255) / 256, 256, 0, stream>>>(Wr, WrT, total);
  }

  // ---- input projection ----
  input_proj<<<NN, 128, 0, stream>>>(x, id_emb, id_token, inW, inb, h);

  const int MB = (NN + 127) / 128;  // 79 row-blocks
  for (int l = 0; l < NL; ++l) {
    layer_prep<<<1, 512, 0, stream>>>(rel_gate, gat_bias, rel_emb, We, l, gates, msgb, erel);
    fill_zero<<<(NN * HID + 255) / 256, 256, 0, stream>>>(hmsg, NN * HID);
    for (int r = 0; r < NR; ++r) {
      const float* WlTr = WlT + ((size_t)(l * NR + r)) * 512 * HID;
      const float* WrTr = WrT + ((size_t)(l * NR + r)) * 512 * HID;
      const float* blr = bl + (size_t)(l * NR + r) * 512;
      const float* brr = br + (size_t)(l * NR + r) * 512;
      const float* Wer = We + ((size_t)(l * NR + r)) * 24 * 512;
      const float* attr = att + (size_t)(l * NR + r) * 512;
      dim3 gg(512 / 64, MB);
      gemm_x2<<<gg, 256, 0, stream>>>(h, WlTr, blr, xl, NN, HID, 512);
      gemm_x2<<<gg, 256, 0, stream>>>(h, WrTr, brr, xr, NN, HID, 512);
      fill_md<<<(NN * NHEADS + 255) / 256, 256, 0, stream>>>(menc, denom);
      edge_score<<<NE, 128, 0, stream>>>(edge_type, edge_index, edge_attr, xl, xr,
                                         Wer, erel + r * 512, attr, r, score, menc);
      edge_expsum<<<(NE * NHEADS + 255) / 256, 256, 0, stream>>>(edge_type, edge_index,
                                                                 score, menc, exbuf, denom, r);
      edge_agg<<<NE, 128, 0, stream>>>(edge_type, edge_index, exbuf, denom, xl, gates, hmsg, r);
    }
    ln128<<<NN, 64, 0, stream>>>(h, hmsg, msgb, ln1g + l * HID, ln1b + l * HID);

    // ---- KAN FFN1: 128 -> 256 (K = 1152) ----
    build_kan_wT<<<((HID * 9 * FFNH) + 255) / 256, 256, 0, stream>>>(
        ffn1_base + (size_t)l * FFNH * HID, ffn1_spl + (size_t)l * FFNH * HID * 8,
        ffn1_sc + (size_t)l * FFNH * HID, BwT1, HID, FFNH);
    expand_f32<<<((NN * HID) + 255) / 256, 256, 0, stream>>>(h, ubuf, HID, NN);
    gemm_x2<<<dim3(FFNH / 64, MB), 256, 0, stream>>>(ubuf, BwT1, nullptr, t1, NN, HID * 9, FFNH);
    // ---- KAN FFN2: 256 -> 128 (K = 2304) ----
    build_kan_wT<<<((FFNH * 9 * HID) + 255) / 256, 256, 0, stream>>>(
        ffn2_base + (size_t)l * HID * FFNH, ffn2_spl + (size_t)l * HID * FFNH * 8,
        ffn2_sc + (size_t)l * HID * FFNH, BwT2, FFNH, HID);
    expand_f32<<<((NN * FFNH) + 255) / 256, 256, 0, stream>>>(t1, ubuf, FFNH, NN);
    gemm_x2<<<dim3(HID / 64, MB), 256, 0, stream>>>(ubuf, BwT2, nullptr, hmsg, NN, FFNH * 9, HID);
    ln128<<<NN, 64, 0, stream>>>(h, hmsg, nullptr, ln2g + l * HID, ln2b + l * HID);
  }

  // ---- readout ----
  pool_init<<<(NG * HID + 255) / 256, 256, 0, stream>>>(pm, pmax, cnt);
  pool_accum<<<NN, 128, 0, stream>>>(h, batch, pm, pmax, cnt);
  pool_final_ln<<<NG, 256, 0, stream>>>(pm, pmax, cnt, rog, rob, gvec);
  expand_f32<<<((NG * 256) + 255) / 256, 256, 0, stream>>>(gvec, uhead, 256, NG);
  kan_head<<<dim3(2, NG), 64, 0, stream>>>(uhead, h1_base, h1_spl, h1_sc, thead, 256, HEADH);
  expand_f32<<<((NG * HEADH) + 255) / 256, 256, 0, stream>>>(thead, uhead, HEADH, NG);
  kan_head<<<dim3(1, NG), 64, 0, stream>>>(uhead, h2_base, h2_spl, h2_sc, (float*)d_out, HEADH, NCLS);
}

// Round 4
// 2915.383 us; speedup vs baseline: 1.2398x; 1.1072x over previous
//
#include <hip/hip_runtime.h>
#include <cstdint>
#include <cstddef>

// ---------------- static problem config ----------------
#define NN      10000   // nodes
#define NE      120000  // edges
#define NG      32      // graphs
#define FNODE   64
#define FEDGE   16
#define HID     128
#define NHEADS  4
#define NL      3
#define NR      4
#define IDDIM   32
#define RELDIM  8
#define FFNH    256
#define HEADH   128
#define NCLS    10

typedef __attribute__((ext_vector_type(8))) short short8;
typedef __attribute__((ext_vector_type(4))) float floatx4;

// ---------------- helpers ----------------
__device__ __forceinline__ unsigned fenc(float f) {
  unsigned u = __float_as_uint(f);
  return (u & 0x80000000u) ? ~u : (u | 0x80000000u);
}
__device__ __forceinline__ float fdec(unsigned k) {
  return __uint_as_float((k & 0x80000000u) ? (k ^ 0x80000000u) : ~k);
}
__device__ __forceinline__ float silu_f(float x) { return x / (1.f + expf(-x)); }
__device__ __forceinline__ ushort f2bf(float f) {   // round-to-nearest-even bf16
  unsigned u = __float_as_uint(f);
  return (ushort)((u + 0x7FFFu + ((u >> 16) & 1u)) >> 16);
}
__device__ __forceinline__ float bf2f(ushort h) { return __uint_as_float((unsigned)h << 16); }

#define ENC_NEG_INF 0x007FFFFFu

// Cox–de Boor cubic bases on grid t_j = (j-3)*0.4 - 1 (GRID_SIZE=5, ORDER=3) -> 8 bases
__device__ __forceinline__ void kan_bases(float x, float* out8) {
  float bb[11];
#pragma unroll
  for (int j = 0; j < 11; ++j) {
    float t0 = (j - 3) * 0.4f - 1.f;
    float t1 = (j - 2) * 0.4f - 1.f;
    bb[j] = (x >= t0 && x < t1) ? 1.f : 0.f;
  }
  {
    const float inv = 1.f / 0.4f;
#pragma unroll
    for (int j = 0; j < 10; ++j) {
      float tj = (j - 3) * 0.4f - 1.f, tjp1 = (j - 1) * 0.4f - 1.f;
      bb[j] = ((x - tj) * bb[j] + (tjp1 - x) * bb[j + 1]) * inv;
    }
  }
  {
    const float inv = 1.f / 0.8f;
#pragma unroll
    for (int j = 0; j < 9; ++j) {
      float tj = (j - 3) * 0.4f - 1.f, tjp1 = (j) * 0.4f - 1.f;
      bb[j] = ((x - tj) * bb[j] + (tjp1 - x) * bb[j + 1]) * inv;
    }
  }
  {
    const float inv = 1.f / 1.2000001f;
#pragma unroll
    for (int j = 0; j < 8; ++j) {
      float tj = (j - 3) * 0.4f - 1.f, tjp1 = (j + 1) * 0.4f - 1.f;
      bb[j] = ((x - tj) * bb[j] + (tjp1 - x) * bb[j + 1]) * inv;
    }
  }
#pragma unroll
  for (int j = 0; j < 8; ++j) out8[j] = bb[j];
}

// ---------------- split-bf16 MFMA GEMM: C[M,N] = A[M,K] @ BT[N,K]^T (+bias) ----------------
// A: fp32 [M,K]. BT: fp32 [N,K]. C: fp32 [M,N]. Split hi/lo bf16 during staging;
// D = Ah*Bh + Al*Bh + Ah*Bl. BM=128, BN=64, BK=64, 256 threads. K%64==0, N%64==0.
__global__ __launch_bounds__(256) void gemm_x2(
    const float* __restrict__ A, const float* __restrict__ BT,
    const float* __restrict__ bias, float* __restrict__ C,
    int M, int K, int N) {
  constexpr int LDA = 72;
  __shared__ __align__(16) ushort Ah[128 * LDA];
  __shared__ __align__(16) ushort Al[128 * LDA];
  __shared__ __align__(16) ushort Bh[64 * LDA];
  __shared__ __align__(16) ushort Bl[64 * LDA];
  const int tid = threadIdx.x;
  const int lane = tid & 63, wave = tid >> 6;
  const int lrow = lane & 15, quad = lane >> 4;
  const int bm = blockIdx.y * 128, bn = blockIdx.x * 64;
  floatx4 acc[2][4] = {};
  for (int k0 = 0; k0 < K; k0 += 64) {
#pragma unroll
    for (int i = 0; i < 8; ++i) {
      int c = tid + i * 256;
      int row = c >> 4, col4 = c & 15;
      int gr = bm + row;
      float4 v = make_float4(0.f, 0.f, 0.f, 0.f);
      if (gr < M) v = *(const float4*)(A + (size_t)gr * K + k0 + col4 * 4);
      float vv[4] = {v.x, v.y, v.z, v.w};
      ushort h0 = f2bf(vv[0]), h1 = f2bf(vv[1]), h2 = f2bf(vv[2]), h3 = f2bf(vv[3]);
      ushort l0 = f2bf(vv[0] - bf2f(h0)), l1 = f2bf(vv[1] - bf2f(h1));
      ushort l2 = f2bf(vv[2] - bf2f(h2)), l3 = f2bf(vv[3] - bf2f(h3));
      *(uint2*)&Ah[row * LDA + col4 * 4] =
        make_uint2((unsigned)h0 | ((unsigned)h1 << 16), (unsigned)h2 | ((unsigned)h3 << 16));
      *(uint2*)&Al[row * LDA + col4 * 4] =
        make_uint2((unsigned)l0 | ((unsigned)l1 << 16), (unsigned)l2 | ((unsigned)l3 << 16));
    }
#pragma unroll
    for (int i = 0; i < 4; ++i) {
      int c = tid + i * 256;
      int row = c >> 4, col4 = c & 15;
      float4 v = *(const float4*)(BT + (size_t)(bn + row) * K + k0 + col4 * 4);
      float vv[4] = {v.x, v.y, v.z, v.w};
      ushort h0 = f2bf(vv[0]), h1 = f2bf(vv[1]), h2 = f2bf(vv[2]), h3 = f2bf(vv[3]);
      ushort l0 = f2bf(vv[0] - bf2f(h0)), l1 = f2bf(vv[1] - bf2f(h1));
      ushort l2 = f2bf(vv[2] - bf2f(h2)), l3 = f2bf(vv[3] - bf2f(h3));
      *(uint2*)&Bh[row * LDA + col4 * 4] =
        make_uint2((unsigned)h0 | ((unsigned)h1 << 16), (unsigned)h2 | ((unsigned)h3 << 16));
      *(uint2*)&Bl[row * LDA + col4 * 4] =
        make_uint2((unsigned)l0 | ((unsigned)l1 << 16), (unsigned)l2 | ((unsigned)l3 << 16));
    }
    __syncthreads();
#pragma unroll
    for (int kk = 0; kk < 64; kk += 32) {
      int kof = kk + quad * 8;
      const int ra0 = (wave * 32 + lrow) * LDA + kof;
      const int ra1 = (wave * 32 + 16 + lrow) * LDA + kof;
      short8 ah0 = *(const short8*)&Ah[ra0];
      short8 ah1 = *(const short8*)&Ah[ra1];
      short8 al0 = *(const short8*)&Al[ra0];
      short8 al1 = *(const short8*)&Al[ra1];
      short8 bh[4], blo[4];
#pragma unroll
      for (int nt = 0; nt < 4; ++nt) {
        int rb = (nt * 16 + lrow) * LDA + kof;
        bh[nt]  = *(const short8*)&Bh[rb];
        blo[nt] = *(const short8*)&Bl[rb];
      }
#pragma unroll
      for (int nt = 0; nt < 4; ++nt) {
        acc[0][nt] = __builtin_amdgcn_mfma_f32_16x16x32_bf16(ah0, bh[nt],  acc[0][nt], 0, 0, 0);
        acc[1][nt] = __builtin_amdgcn_mfma_f32_16x16x32_bf16(ah1, bh[nt],  acc[1][nt], 0, 0, 0);
        acc[0][nt] = __builtin_amdgcn_mfma_f32_16x16x32_bf16(al0, bh[nt],  acc[0][nt], 0, 0, 0);
        acc[1][nt] = __builtin_amdgcn_mfma_f32_16x16x32_bf16(al1, bh[nt],  acc[1][nt], 0, 0, 0);
        acc[0][nt] = __builtin_amdgcn_mfma_f32_16x16x32_bf16(ah0, blo[nt], acc[0][nt], 0, 0, 0);
        acc[1][nt] = __builtin_amdgcn_mfma_f32_16x16x32_bf16(ah1, blo[nt], acc[1][nt], 0, 0, 0);
      }
    }
    __syncthreads();
  }
#pragma unroll
  for (int mt = 0; mt < 2; ++mt) {
#pragma unroll
    for (int nt = 0; nt < 4; ++nt) {
#pragma unroll
      for (int reg = 0; reg < 4; ++reg) {
        int row = bm + wave * 32 + mt * 16 + quad * 4 + reg;
        int col = bn + nt * 16 + lrow;
        if (row < M) {
          float v = acc[mt][nt][reg];
          if (bias) v += bias[col];
          C[(size_t)row * N + col] = v;
        }
      }
    }
  }
}

// ---------------- fused KAN GEMM: C[M,N] = expand(A)[M,In*9] @ BT[N,In*9]^T ----------------
// A: fp32 [M,In] raw activations; expansion (silu | 8 cubic bases per col) computed during
// LDS staging. BT: fp32 [N, In*9] (k<In: base w; else spline, k=In+ii*8+gq). In%64==0.
// BM in {64,128}, BN=64, BK=64, 256 threads. Split-bf16 3-term MFMA.
template<int BM>
__global__ __launch_bounds__(256) void gemm_kan(
    const float* __restrict__ A, const float* __restrict__ BT,
    float* __restrict__ C, int M, int In, int N) {
  const int K = In * 9;
  constexpr int LDA = 72;
  __shared__ __align__(16) ushort Ah[BM * LDA];
  __shared__ __align__(16) ushort Al[BM * LDA];
  __shared__ __align__(16) ushort Bh[64 * LDA];
  __shared__ __align__(16) ushort Bl[64 * LDA];
  const int tid = threadIdx.x;
  const int lane = tid & 63, wave = tid >> 6;
  const int lrow = lane & 15, quad = lane >> 4;
  const int bm = blockIdx.y * BM, bn = blockIdx.x * 64;
  constexpr int MT = BM / 64;               // m-frags per wave
  floatx4 acc[MT][4] = {};
  for (int k0 = 0; k0 < K; k0 += 64) {
    // ---- stage A with on-the-fly expansion ----
    if (k0 < In) {
      // silu region: BM rows x 64 cols of A[:, k0..k0+63]
#pragma unroll
      for (int i = 0; i < BM / 16; ++i) {
        int c = tid + i * 256;
        int row = c >> 4, col4 = c & 15;
        int gr = bm + row;
        float4 v = make_float4(0.f, 0.f, 0.f, 0.f);
        if (gr < M) v = *(const float4*)(A + (size_t)gr * In + k0 + col4 * 4);
        float vv[4] = {silu_f(v.x), silu_f(v.y), silu_f(v.z), silu_f(v.w)};
        ushort h0 = f2bf(vv[0]), h1 = f2bf(vv[1]), h2 = f2bf(vv[2]), h3 = f2bf(vv[3]);
        ushort l0 = f2bf(vv[0] - bf2f(h0)), l1 = f2bf(vv[1] - bf2f(h1));
        ushort l2 = f2bf(vv[2] - bf2f(h2)), l3 = f2bf(vv[3] - bf2f(h3));
        *(uint2*)&Ah[row * LDA + col4 * 4] =
          make_uint2((unsigned)h0 | ((unsigned)h1 << 16), (unsigned)h2 | ((unsigned)h3 << 16));
        *(uint2*)&Al[row * LDA + col4 * 4] =
          make_uint2((unsigned)l0 | ((unsigned)l1 << 16), (unsigned)l2 | ((unsigned)l3 << 16));
      }
    } else {
      // spline region: tile covers input cols i0..i0+7, all 8 bases each
      int i0 = (k0 - In) >> 3;
      if (tid < BM * 2) {
        int row = tid >> 1, half = tid & 1;
        int gr = bm + row;
        float4 v = make_float4(0.f, 0.f, 0.f, 0.f);
        if (gr < M) v = *(const float4*)(A + (size_t)gr * In + i0 + half * 4);
        float vv[4] = {v.x, v.y, v.z, v.w};
#pragma unroll
        for (int jj = 0; jj < 4; ++jj) {
          float b8[8];
          kan_bases(vv[jj], b8);
          unsigned hu[4], lu[4];
#pragma unroll
          for (int q = 0; q < 4; ++q) {
            ushort ha = f2bf(b8[2 * q]), hb = f2bf(b8[2 * q + 1]);
            ushort la = f2bf(b8[2 * q] - bf2f(ha)), lb = f2bf(b8[2 * q + 1] - bf2f(hb));
            hu[q] = (unsigned)ha | ((unsigned)hb << 16);
            lu[q] = (unsigned)la | ((unsigned)lb << 16);
          }
          int cbase = (half * 4 + jj) * 8;
          *(uint4*)&Ah[row * LDA + cbase] = make_uint4(hu[0], hu[1], hu[2], hu[3]);
          *(uint4*)&Al[row * LDA + cbase] = make_uint4(lu[0], lu[1], lu[2], lu[3]);
        }
      }
    }
    // ---- stage BT: 64 rows x 64 cols fp32 ----
#pragma unroll
    for (int i = 0; i < 4; ++i) {
      int c = tid + i * 256;
      int row = c >> 4, col4 = c & 15;
      float4 v = *(const float4*)(BT + (size_t)(bn + row) * K + k0 + col4 * 4);
      float vv[4] = {v.x, v.y, v.z, v.w};
      ushort h0 = f2bf(vv[0]), h1 = f2bf(vv[1]), h2 = f2bf(vv[2]), h3 = f2bf(vv[3]);
      ushort l0 = f2bf(vv[0] - bf2f(h0)), l1 = f2bf(vv[1] - bf2f(h1));
      ushort l2 = f2bf(vv[2] - bf2f(h2)), l3 = f2bf(vv[3] - bf2f(h3));
      *(uint2*)&Bh[row * LDA + col4 * 4] =
        make_uint2((unsigned)h0 | ((unsigned)h1 << 16), (unsigned)h2 | ((unsigned)h3 << 16));
      *(uint2*)&Bl[row * LDA + col4 * 4] =
        make_uint2((unsigned)l0 | ((unsigned)l1 << 16), (unsigned)l2 | ((unsigned)l3 << 16));
    }
    __syncthreads();
#pragma unroll
    for (int kk = 0; kk < 64; kk += 32) {
      int kof = kk + quad * 8;
      short8 ah[MT], al[MT];
#pragma unroll
      for (int mt = 0; mt < MT; ++mt) {
        int ra = (wave * (BM / 4) + mt * 16 + lrow) * LDA + kof;
        ah[mt] = *(const short8*)&Ah[ra];
        al[mt] = *(const short8*)&Al[ra];
      }
      short8 bh[4], blo[4];
#pragma unroll
      for (int nt = 0; nt < 4; ++nt) {
        int rb = (nt * 16 + lrow) * LDA + kof;
        bh[nt]  = *(const short8*)&Bh[rb];
        blo[nt] = *(const short8*)&Bl[rb];
      }
#pragma unroll
      for (int nt = 0; nt < 4; ++nt) {
#pragma unroll
        for (int mt = 0; mt < MT; ++mt) {
          acc[mt][nt] = __builtin_amdgcn_mfma_f32_16x16x32_bf16(ah[mt], bh[nt],  acc[mt][nt], 0, 0, 0);
          acc[mt][nt] = __builtin_amdgcn_mfma_f32_16x16x32_bf16(al[mt], bh[nt],  acc[mt][nt], 0, 0, 0);
          acc[mt][nt] = __builtin_amdgcn_mfma_f32_16x16x32_bf16(ah[mt], blo[nt], acc[mt][nt], 0, 0, 0);
        }
      }
    }
    __syncthreads();
  }
#pragma unroll
  for (int mt = 0; mt < MT; ++mt) {
#pragma unroll
    for (int nt = 0; nt < 4; ++nt) {
#pragma unroll
      for (int reg = 0; reg < 4; ++reg) {
        int row = bm + wave * (BM / 4) + mt * 16 + quad * 4 + reg;
        int col = bn + nt * 16 + lrow;
        if (row < M) C[(size_t)row * N + col] = acc[mt][nt][reg];
      }
    }
  }
}

// ---------------- merged weight transpose: [Wl|Wr] -> WT [G][1024][128] + bias [G][1024] ----
__global__ void conv_wT2(const float* __restrict__ Wl, const float* __restrict__ Wr,
                         const float* __restrict__ bl, const float* __restrict__ br,
                         float* __restrict__ WT, float* __restrict__ bout, int total) {
  int i = blockIdx.x * 256 + threadIdx.x;
  if (i >= total) return;
  int g = i / (1024 * 128), rem = i % (1024 * 128);
  int n = rem >> 7, k = rem & 127;
  int nn = n & 511;
  const float* W = (n < 512) ? Wl : Wr;
  WT[i] = W[(size_t)g * 65536 + (size_t)k * 512 + nn];
  if (k == 0) bout[g * 1024 + n] = ((n < 512) ? bl : br)[g * 512 + nn];
}

// ---------------- input projection ----------------
__global__ __launch_bounds__(128) void input_proj(
    const float* __restrict__ x, const float* __restrict__ id_emb,
    const int* __restrict__ id_token, const float* __restrict__ inW,
    const float* __restrict__ inb, float* __restrict__ h) {
  int n = blockIdx.x, j = threadIdx.x;
  __shared__ float s[FNODE + IDDIM];
  if (j < FNODE) s[j] = x[(size_t)n * FNODE + j];
  else if (j < FNODE + IDDIM) s[j] = id_emb[(size_t)id_token[n] * IDDIM + (j - FNODE)];
  __syncthreads();
  float acc = inb[j];
#pragma unroll
  for (int k = 0; k < FNODE + IDDIM; ++k) acc = fmaf(s[k], inW[k * HID + j], acc);
  h[(size_t)n * HID + j] = silu_f(acc);
}

// ---------------- per-layer prep ----------------
__global__ __launch_bounds__(512) void layer_prep(
    const float* __restrict__ rel_gate, const float* __restrict__ gat_bias,
    const float* __restrict__ rel_emb, const float* __restrict__ We, int l,
    float* __restrict__ gates, float* __restrict__ msg_bias, float* __restrict__ erel) {
  int j = threadIdx.x;
  float g[NR]; float mx = -1e30f;
  for (int r = 0; r < NR; ++r) { g[r] = rel_gate[l * NR + r]; mx = fmaxf(mx, g[r]); }
  float s = 0.f;
  for (int r = 0; r < NR; ++r) { g[r] = expf(g[r] - mx); s += g[r]; }
  for (int r = 0; r < NR; ++r) g[r] /= s;
  if (j < NR) gates[j] = g[j];
  if (j < HID) {
    float b = 0.f;
    for (int r = 0; r < NR; ++r) b = fmaf(g[r], gat_bias[((size_t)(l * NR + r)) * HID + j], b);
    msg_bias[j] = b;
  }
  for (int r = 0; r < NR; ++r) {
    const float* Wer = We + ((size_t)(l * NR + r)) * 24 * 512;
    const float* re  = rel_emb + (l * NR + r) * RELDIM;
    float acc = 0.f;
#pragma unroll
    for (int q = 0; q < RELDIM; ++q) acc = fmaf(re[q], Wer[(FEDGE + q) * 512 + j], acc);
    erel[r * 512 + j] = acc;
  }
}

// ---------------- fills ----------------
__global__ void fill_md(unsigned* __restrict__ menc, float* __restrict__ denom) {
  int i = blockIdx.x * 256 + threadIdx.x;
  if (i < NN * NHEADS) { menc[i] = ENC_NEG_INF; denom[i] = 0.f; }
}
__global__ void fill_zero(float* __restrict__ p, int n) {
  int i = blockIdx.x * 256 + threadIdx.x;
  if (i < n) p[i] = 0.f;
}

// ---------------- edge pass 1: score + segment max (xlr stride 1024; xr = xlr+512) ------
__global__ __launch_bounds__(128) void edge_score(
    const int* __restrict__ etype, const int* __restrict__ eidx,
    const float* __restrict__ eattr, const float* __restrict__ xlr,
    const float* __restrict__ We_r, const float* __restrict__ erel_r,
    const float* __restrict__ att_r,
    int r, float* __restrict__ score, unsigned* __restrict__ menc) {
  int e = blockIdx.x;
  if (etype[e] != r) return;
  int s = eidx[e], t = eidx[NE + e];
  int d = threadIdx.x;
  __shared__ float ea[FEDGE];
  __shared__ float red[2][NHEADS];
  if (d < FEDGE) ea[d] = eattr[(size_t)e * FEDGE + d];
  __syncthreads();
  const float* xls = xlr + (size_t)s * 1024;
  const float* xrt = xlr + (size_t)t * 1024 + 512;
  float vs[NHEADS];
#pragma unroll
  for (int hh = 0; hh < NHEADS; ++hh) {
    int idx = hh * HID + d;
    float ev = erel_r[idx];
#pragma unroll
    for (int k = 0; k < FEDGE; ++k) ev = fmaf(ea[k], We_r[k * 512 + idx], ev);
    float z = xls[idx] + xrt[idx] + ev;
    z = (z > 0.f) ? z : 0.2f * z;       // leaky_relu 0.2
    float v = z * att_r[hh * HID + d];
#pragma unroll
    for (int off = 32; off > 0; off >>= 1) v += __shfl_down(v, off, 64);
    vs[hh] = v;
  }
  if ((d & 63) == 0) {
#pragma unroll
    for (int hh = 0; hh < NHEADS; ++hh) red[d >> 6][hh] = vs[hh];
  }
  __syncthreads();
  if (d == 0) {
#pragma unroll
    for (int hh = 0; hh < NHEADS; ++hh) {
      float tot = red[0][hh] + red[1][hh];
      score[(size_t)e * NHEADS + hh] = tot;
      atomicMax(&menc[t * NHEADS + hh], fenc(tot));
    }
  }
}

// ---------------- edge pass 2: exp + segment sum ----------------
__global__ void edge_expsum(
    const int* __restrict__ etype, const int* __restrict__ eidx,
    const float* __restrict__ score, const unsigned* __restrict__ menc,
    float* __restrict__ ex, float* __restrict__ denom, int r) {
  int i = blockIdx.x * 256 + threadIdx.x;
  if (i >= NE * NHEADS) return;
  int e = i >> 2, hh = i & 3;
  if (etype[e] != r) return;
  int t = eidx[NE + e];
  float m = fdec(menc[t * NHEADS + hh]);
  float v = expf(score[i] - m);
  ex[i] = v;
  atomicAdd(&denom[t * NHEADS + hh], v);
}

// ---------------- edge pass 3: weighted aggregation (head-mean folded in) ----------------
__global__ __launch_bounds__(128) void edge_agg(
    const int* __restrict__ etype, const int* __restrict__ eidx,
    const float* __restrict__ ex, const float* __restrict__ denom,
    const float* __restrict__ xlr, const float* __restrict__ gates,
    float* __restrict__ hmsg, int r) {
  int e = blockIdx.x;
  if (etype[e] != r) return;
  int s = eidx[e], t = eidx[NE + e];
  int d = threadIdx.x;
  float gr = gates[r] * 0.25f;  // head mean folded into segment sum
  float alpha[NHEADS];
#pragma unroll
  for (int hh = 0; hh < NHEADS; ++hh)
    alpha[hh] = ex[(size_t)e * NHEADS + hh] / fmaxf(denom[t * NHEADS + hh], 1e-16f);
  const float* xls = xlr + (size_t)s * 1024;
  float v = 0.f;
#pragma unroll
  for (int hh = 0; hh < NHEADS; ++hh) v = fmaf(alpha[hh], xls[hh * HID + d], v);
  atomicAdd(&hmsg[(size_t)t * HID + d], gr * v);
}

// ---------------- LayerNorm over 128 dims ----------------
__global__ __launch_bounds__(64) void ln128(
    float* __restrict__ h, const float* __restrict__ add, const float* __restrict__ bvec,
    const float* __restrict__ g, const float* __restrict__ b) {
  int n = blockIdx.x, lane = threadIdx.x;
  size_t base = (size_t)n * HID;
  float x0 = h[base + lane] + add[base + lane];
  float x1 = h[base + 64 + lane] + add[base + 64 + lane];
  if (bvec) { x0 += bvec[lane]; x1 += bvec[64 + lane]; }
  float s = x0 + x1;
#pragma unroll
  for (int m = 32; m > 0; m >>= 1) s += __shfl_xor(s, m, 64);
  float mu = s * (1.f / 128.f);
  float d0 = x0 - mu, d1 = x1 - mu;
  float q = d0 * d0 + d1 * d1;
#pragma unroll
  for (int m = 32; m > 0; m >>= 1) q += __shfl_xor(q, m, 64);
  float inv = 1.f / sqrtf(q * (1.f / 128.f) + 1e-5f);
  h[base + lane]      = d0 * inv * g[lane] + b[lane];
  h[base + 64 + lane] = d1 * inv * g[64 + lane] + b[64 + lane];
}

// ---------------- KAN expansion (fp32) — used only for the tiny readout head ----------------
__global__ void expand_f32(const float* __restrict__ v, float* __restrict__ u, int In, int rows) {
  int i = blockIdx.x * 256 + threadIdx.x;
  if (i >= rows * In) return;
  int n = i / In, c = i % In;
  float x = v[(size_t)n * In + c];
  size_t base = (size_t)n * In * 9;
  u[base + c] = silu_f(x);
  float b8[8];
  kan_bases(x, b8);
  float* ub = u + base + In + (size_t)c * 8;
#pragma unroll
  for (int gq = 0; gq < 8; ++gq) ub[gq] = b8[gq];
}

// ---------------- build expanded KAN weight, transposed fp32: BT[o, k] ----------------
__global__ void build_kan_wT(const float* __restrict__ base_w, const float* __restrict__ spline_w,
                             const float* __restrict__ scaler, float* __restrict__ BT,
                             int In, int Out) {
  int i = blockIdx.x * 256 + threadIdx.x;
  if (i >= In * 9 * Out) return;
  int o = i / (In * 9), k = i % (In * 9);
  float v;
  if (k < In) v = base_w[(size_t)o * In + k];
  else {
    int q = k - In, ii = q >> 3, gq = q & 7;
    v = spline_w[((size_t)o * In + ii) * 8 + gq] * scaler[(size_t)o * In + ii];
  }
  BT[i] = v;
}

// ---------------- readout ----------------
__global__ void pool_init(float* __restrict__ mean, unsigned* __restrict__ maxenc, float* __restrict__ cnt) {
  int i = blockIdx.x * 256 + threadIdx.x;
  if (i < NG * HID) { mean[i] = 0.f; maxenc[i] = ENC_NEG_INF; }
  if (i < NG) cnt[i] = 0.f;
}
__global__ __launch_bounds__(128) void pool_accum(
    const float* __restrict__ h, const int* __restrict__ batch,
    float* __restrict__ mean, unsigned* __restrict__ maxenc, float* __restrict__ cnt) {
  int n = blockIdx.x, d = threadIdx.x;
  int g = batch[n];
  float v = h[(size_t)n * HID + d];
  atomicAdd(&mean[g * HID + d], v);
  atomicMax(&maxenc[g * HID + d], fenc(v));
  if (d == 0) atomicAdd(&cnt[g], 1.f);
}
__global__ __launch_bounds__(256) void pool_final_ln(
    const float* __restrict__ mean, const unsigned* __restrict__ maxenc,
    const float* __restrict__ cnt, const float* __restrict__ rog,
    const float* __restrict__ rob, float* __restrict__ gvec) {
  int g = blockIdx.x, j = threadIdx.x;
  __shared__ float rb[256];
  float x;
  if (j < HID) x = mean[g * HID + j] / fmaxf(cnt[g], 1.f);
  else {
    float mv = fdec(maxenc[g * HID + (j - HID)]);
    x = (mv > -1e38f) ? mv : 0.f;  // where(isfinite, ., 0)
  }
  rb[j] = x; __syncthreads();
  for (int st = 128; st > 0; st >>= 1) { if (j < st) rb[j] += rb[j + st]; __syncthreads(); }
  float mu = rb[0] * (1.f / 256.f); __syncthreads();
  float d = x - mu;
  rb[j] = d * d; __syncthreads();
  for (int st = 128; st > 0; st >>= 1) { if (j < st) rb[j] += rb[j + st]; __syncthreads(); }
  float var = rb[0] * (1.f / 256.f);
  float inv = 1.f / sqrtf(var + 1e-5f);
  gvec[(size_t)g * 256 + j] = d * inv * rog[j] + rob[j];
}

// ---------------- small KAN head (fp32, raw weights) ----------------
__global__ void kan_head(const float* __restrict__ u, const float* __restrict__ base_w,
                         const float* __restrict__ spline_w, const float* __restrict__ scaler,
                         float* __restrict__ out, int In, int Out) {
  int o = blockIdx.x * 64 + threadIdx.x;
  int g = blockIdx.y;
  if (o >= Out) return;
  const float* ug = u + (size_t)g * In * 9;
  float acc = 0.f;
  for (int i = 0; i < In; ++i) acc = fmaf(ug[i], base_w[(size_t)o * In + i], acc);
  for (int i = 0; i < In; ++i) {
    const float* sp = spline_w + ((size_t)o * In + i) * 8;
    const float* ub = ug + In + (size_t)i * 8;
    float a2 = 0.f;
#pragma unroll
    for (int gq = 0; gq < 8; ++gq) a2 = fmaf(ub[gq], sp[gq], a2);
    acc = fmaf(scaler[(size_t)o * In + i], a2, acc);
  }
  out[(size_t)g * Out + o] = acc;
}

// ---------------- launch ----------------
extern "C" void kernel_launch(void* const* d_in, const int* in_sizes, int n_in,
                              void* d_out, int out_size, void* d_ws, size_t ws_size,
                              hipStream_t stream) {
  const float* x         = (const float*)d_in[0];
  const float* edge_attr = (const float*)d_in[1];
  const int*   id_token  = (const int*)  d_in[2];
  const int*   edge_index= (const int*)  d_in[3];
  const int*   edge_type = (const int*)  d_in[4];
  const int*   batch     = (const int*)  d_in[5];
  const float* id_emb    = (const float*)d_in[6];
  const float* inW       = (const float*)d_in[7];
  const float* inb       = (const float*)d_in[8];
  const float* Wl        = (const float*)d_in[9];
  const float* bl        = (const float*)d_in[10];
  const float* Wr        = (const float*)d_in[11];
  const float* br        = (const float*)d_in[12];
  const float* We        = (const float*)d_in[13];
  const float* att       = (const float*)d_in[14];
  const float* gat_bias  = (const float*)d_in[15];
  const float* rel_gate  = (const float*)d_in[16];
  const float* rel_emb   = (const float*)d_in[17];
  const float* ln1g      = (const float*)d_in[18];
  const float* ln1b      = (const float*)d_in[19];
  const float* ln2g      = (const float*)d_in[20];
  const float* ln2b      = (const float*)d_in[21];
  const float* ffn1_base = (const float*)d_in[22];
  const float* ffn1_spl  = (const float*)d_in[23];
  const float* ffn1_sc   = (const float*)d_in[24];
  const float* ffn2_base = (const float*)d_in[25];
  const float* ffn2_spl  = (const float*)d_in[26];
  const float* ffn2_sc   = (const float*)d_in[27];
  const float* rog       = (const float*)d_in[28];
  const float* rob       = (const float*)d_in[29];
  const float* h1_base   = (const float*)d_in[30];
  const float* h1_spl    = (const float*)d_in[31];
  const float* h1_sc     = (const float*)d_in[32];
  const float* h2_base   = (const float*)d_in[33];
  const float* h2_spl    = (const float*)d_in[34];
  const float* h2_sc     = (const float*)d_in[35];
  (void)in_sizes; (void)n_in; (void)out_size; (void)ws_size;

  // ---- workspace carve (256B aligned) ----
  char* wsp = (char*)d_ws;
  size_t off = 0;
  auto carve = [&](size_t bytes) { char* p = wsp + off; off = (off + bytes + 255) & ~(size_t)255; return p; };
  float*    h     = (float*)   carve((size_t)NN * HID * 4);
  float*    hmsg  = (float*)   carve((size_t)NN * HID * 4);
  float*    t1    = (float*)   carve((size_t)NN * FFNH * 4);
  unsigned* menc  = (unsigned*)carve((size_t)NN * NHEADS * 4);
  float*    denom = (float*)   carve((size_t)NN * NHEADS * 4);
  float*    gates = (float*)   carve(NR * 4);
  float*    msgb  = (float*)   carve(HID * 4);
  float*    erel  = (float*)   carve(NR * 512 * 4);
  float*    WlrT  = (float*)   carve((size_t)NL * NR * 1024 * HID * 4);  // merged [1024][128]
  float*    blr   = (float*)   carve((size_t)NL * NR * 1024 * 4);
  float*    BwT1  = (float*)   carve((size_t)FFNH * HID * 9 * 4);   // [256][1152]
  float*    BwT2  = (float*)   carve((size_t)HID * FFNH * 9 * 4);   // [128][2304]
  float*    pm    = (float*)   carve((size_t)NG * HID * 4);
  unsigned* pmax  = (unsigned*)carve((size_t)NG * HID * 4);
  float*    cnt   = (float*)   carve(NG * 4);
  float*    gvec  = (float*)   carve((size_t)NG * 256 * 4);
  float*    uhead = (float*)   carve((size_t)NG * 256 * 9 * 4);
  float*    thead = (float*)   carve((size_t)NG * HEADH * 4);
  float*    xlr   = (float*)   carve((size_t)NN * 1024 * 4);        // 41 MB
  float*    score = (float*)   carve((size_t)NE * NHEADS * 4);
  float*    exbuf = (float*)   carve((size_t)NE * NHEADS * 4);

  // ---- weight transpose (once per launch) ----
  {
    int total = NL * NR * 1024 * 128;
    conv_wT2<<<(total + 255) / 256, 256, 0, stream>>>(Wl, Wr, bl, br, WlrT, blr, total);
  }

  // ---- input projection ----
  input_proj<<<NN, 128, 0, stream>>>(x, id_emb, id_token, inW, inb, h);

  const int MB128 = (NN + 127) / 128;  // 79
  const int MB64  = (NN + 63) / 64;    // 157
  for (int l = 0; l < NL; ++l) {
    layer_prep<<<1, 512, 0, stream>>>(rel_gate, gat_bias, rel_emb, We, l, gates, msgb, erel);
    fill_zero<<<(NN * HID + 255) / 256, 256, 0, stream>>>(hmsg, NN * HID);
    for (int r = 0; r < NR; ++r) {
      const float* WlrTr = WlrT + ((size_t)(l * NR + r)) * 1024 * HID;
      const float* blrr  = blr + (size_t)(l * NR + r) * 1024;
      const float* Wer   = We + ((size_t)(l * NR + r)) * 24 * 512;
      const float* attr  = att + (size_t)(l * NR + r) * 512;
      gemm_x2<<<dim3(1024 / 64, MB128), 256, 0, stream>>>(h, WlrTr, blrr, xlr, NN, HID, 1024);
      fill_md<<<(NN * NHEADS + 255) / 256, 256, 0, stream>>>(menc, denom);
      edge_score<<<NE, 128, 0, stream>>>(edge_type, edge_index, edge_attr, xlr,
                                         Wer, erel + r * 512, attr, r, score, menc);
      edge_expsum<<<(NE * NHEADS + 255) / 256, 256, 0, stream>>>(edge_type, edge_index,
                                                                 score, menc, exbuf, denom, r);
      edge_agg<<<NE, 128, 0, stream>>>(edge_type, edge_index, exbuf, denom, xlr, gates, hmsg, r);
    }
    ln128<<<NN, 64, 0, stream>>>(h, hmsg, msgb, ln1g + l * HID, ln1b + l * HID);

    // ---- KAN FFN1: 128 -> 256 (K = 1152), fused expansion ----
    build_kan_wT<<<((HID * 9 * FFNH) + 255) / 256, 256, 0, stream>>>(
        ffn1_base + (size_t)l * FFNH * HID, ffn1_spl + (size_t)l * FFNH * HID * 8,
        ffn1_sc + (size_t)l * FFNH * HID, BwT1, HID, FFNH);
    gemm_kan<128><<<dim3(FFNH / 64, MB128), 256, 0, stream>>>(h, BwT1, t1, NN, HID, FFNH);
    // ---- KAN FFN2: 256 -> 128 (K = 2304), fused expansion ----
    build_kan_wT<<<((FFNH * 9 * HID) + 255) / 256, 256, 0, stream>>>(
        ffn2_base + (size_t)l * HID * FFNH, ffn2_spl + (size_t)l * HID * FFNH * 8,
        ffn2_sc + (size_t)l * HID * FFNH, BwT2, FFNH, HID);
    gemm_kan<64><<<dim3(HID / 64, MB64), 256, 0, stream>>>(t1, BwT2, hmsg, NN, FFNH, HID);
    ln128<<<NN, 64, 0, stream>>>(h, hmsg, nullptr, ln2g + l * HID, ln2b + l * HID);
  }

  // ---- readout ----
  pool_init<<<(NG * HID + 255) / 256, 256, 0, stream>>>(pm, pmax, cnt);
  pool_accum<<<NN, 128, 0, stream>>>(h, batch, pm, pmax, cnt);
  pool_final_ln<<<NG, 256, 0, stream>>>(pm, pmax, cnt, rog, rob, gvec);
  expand_f32<<<((NG * 256) + 255) / 256, 256, 0, stream>>>(gvec, uhead, 256, NG);
  kan_head<<<dim3(2, NG), 64, 0, stream>>>(uhead, h1_base, h1_spl, h1_sc, thead, 256, HEADH);
  expand_f32<<<((NG * HEADH) + 255) / 256, 256, 0, stream>>>(thead, uhead, HEADH, NG);
  kan_head<<<dim3(1, NG), 64, 0, stream>>>(uhead, h2_base, h2_spl, h2_sc, (float*)d_out, HEADH, NCLS);
}

// Round 5
// 2749.126 us; speedup vs baseline: 1.3148x; 1.0605x over previous
//
#include <hip/hip_runtime.h>
#include <cstdint>
#include <cstddef>

// ---------------- static problem config ----------------
#define NN      10000   // nodes
#define NE      120000  // edges
#define NG      32      // graphs
#define FNODE   64
#define FEDGE   16
#define HID     128
#define NHEADS  4
#define NL      3
#define NR      4
#define IDDIM   32
#define RELDIM  8
#define FFNH    256
#define HEADH   128
#define NCLS    10

typedef __attribute__((ext_vector_type(8))) short short8;
typedef __attribute__((ext_vector_type(4))) float floatx4;

// ---------------- helpers ----------------
__device__ __forceinline__ unsigned fenc(float f) {
  unsigned u = __float_as_uint(f);
  return (u & 0x80000000u) ? ~u : (u | 0x80000000u);
}
__device__ __forceinline__ float fdec(unsigned k) {
  return __uint_as_float((k & 0x80000000u) ? (k ^ 0x80000000u) : ~k);
}
__device__ __forceinline__ float silu_f(float x) { return x / (1.f + expf(-x)); }
__device__ __forceinline__ ushort f2bf(float f) {   // round-to-nearest-even bf16
  unsigned u = __float_as_uint(f);
  return (ushort)((u + 0x7FFFu + ((u >> 16) & 1u)) >> 16);
}
__device__ __forceinline__ float bf2f(ushort h) { return __uint_as_float((unsigned)h << 16); }

#define ENC_NEG_INF 0x007FFFFFu

// Cox–de Boor cubic bases on grid t_j = (j-3)*0.4 - 1 (GRID_SIZE=5, ORDER=3) -> 8 bases
__device__ __forceinline__ void kan_bases(float x, float* out8) {
  float bb[11];
#pragma unroll
  for (int j = 0; j < 11; ++j) {
    float t0 = (j - 3) * 0.4f - 1.f;
    float t1 = (j - 2) * 0.4f - 1.f;
    bb[j] = (x >= t0 && x < t1) ? 1.f : 0.f;
  }
  {
    const float inv = 1.f / 0.4f;
#pragma unroll
    for (int j = 0; j < 10; ++j) {
      float tj = (j - 3) * 0.4f - 1.f, tjp1 = (j - 1) * 0.4f - 1.f;
      bb[j] = ((x - tj) * bb[j] + (tjp1 - x) * bb[j + 1]) * inv;
    }
  }
  {
    const float inv = 1.f / 0.8f;
#pragma unroll
    for (int j = 0; j < 9; ++j) {
      float tj = (j - 3) * 0.4f - 1.f, tjp1 = (j) * 0.4f - 1.f;
      bb[j] = ((x - tj) * bb[j] + (tjp1 - x) * bb[j + 1]) * inv;
    }
  }
  {
    const float inv = 1.f / 1.2000001f;
#pragma unroll
    for (int j = 0; j < 8; ++j) {
      float tj = (j - 3) * 0.4f - 1.f, tjp1 = (j + 1) * 0.4f - 1.f;
      bb[j] = ((x - tj) * bb[j] + (tjp1 - x) * bb[j + 1]) * inv;
    }
  }
#pragma unroll
  for (int j = 0; j < 8; ++j) out8[j] = bb[j];
}

// ---------------- 3-term MFMA GEMM, all operands pre-split bf16 hi/lo ----------------
// C[M,N] = A @ B^T (+bias), D = Ah*Bh + Al*Bh + Ah*Bl. A*: bf16 [M,K], B*: bf16 [N,K].
// BM=128, BN=64, BK=64, 256 threads. K%64==0, N%64==0, M guarded.
__global__ __launch_bounds__(256) void gemm_bf3(
    const ushort* __restrict__ Ahg, const ushort* __restrict__ Alg,
    const ushort* __restrict__ Bhg, const ushort* __restrict__ Blg,
    const float* __restrict__ bias, float* __restrict__ C,
    int M, int K, int N) {
  constexpr int LDA = 72;
  __shared__ __align__(16) ushort Ah[128 * LDA];
  __shared__ __align__(16) ushort Al[128 * LDA];
  __shared__ __align__(16) ushort Bh[64 * LDA];
  __shared__ __align__(16) ushort Bl[64 * LDA];
  const int tid = threadIdx.x;
  const int lane = tid & 63, wave = tid >> 6;
  const int lrow = lane & 15, quad = lane >> 4;
  const int bm = blockIdx.y * 128, bn = blockIdx.x * 64;
  floatx4 acc[2][4] = {};
  for (int k0 = 0; k0 < K; k0 += 64) {
    // stage A hi/lo: 128 rows x 64 cols bf16, 16B chunks, 4 per array per thread
#pragma unroll
    for (int i = 0; i < 4; ++i) {
      int c = tid + i * 256;
      int row = c >> 3, col8 = c & 7;
      int gr = bm + row;
      uint4 vh = make_uint4(0, 0, 0, 0), vl = make_uint4(0, 0, 0, 0);
      if (gr < M) {
        vh = *(const uint4*)(Ahg + (size_t)gr * K + k0 + col8 * 8);
        vl = *(const uint4*)(Alg + (size_t)gr * K + k0 + col8 * 8);
      }
      *(uint4*)&Ah[row * LDA + col8 * 8] = vh;
      *(uint4*)&Al[row * LDA + col8 * 8] = vl;
    }
    // stage B hi/lo: 64 rows x 64 cols, 2 per array per thread
#pragma unroll
    for (int i = 0; i < 2; ++i) {
      int c = tid + i * 256;
      int row = c >> 3, col8 = c & 7;
      *(uint4*)&Bh[row * LDA + col8 * 8] = *(const uint4*)(Bhg + (size_t)(bn + row) * K + k0 + col8 * 8);
      *(uint4*)&Bl[row * LDA + col8 * 8] = *(const uint4*)(Blg + (size_t)(bn + row) * K + k0 + col8 * 8);
    }
    __syncthreads();
#pragma unroll
    for (int kk = 0; kk < 64; kk += 32) {
      int kof = kk + quad * 8;
      const int ra0 = (wave * 32 + lrow) * LDA + kof;
      const int ra1 = (wave * 32 + 16 + lrow) * LDA + kof;
      short8 ah0 = *(const short8*)&Ah[ra0];
      short8 ah1 = *(const short8*)&Ah[ra1];
      short8 al0 = *(const short8*)&Al[ra0];
      short8 al1 = *(const short8*)&Al[ra1];
      short8 bh[4], blo[4];
#pragma unroll
      for (int nt = 0; nt < 4; ++nt) {
        int rb = (nt * 16 + lrow) * LDA + kof;
        bh[nt]  = *(const short8*)&Bh[rb];
        blo[nt] = *(const short8*)&Bl[rb];
      }
#pragma unroll
      for (int nt = 0; nt < 4; ++nt) {
        acc[0][nt] = __builtin_amdgcn_mfma_f32_16x16x32_bf16(ah0, bh[nt],  acc[0][nt], 0, 0, 0);
        acc[1][nt] = __builtin_amdgcn_mfma_f32_16x16x32_bf16(ah1, bh[nt],  acc[1][nt], 0, 0, 0);
        acc[0][nt] = __builtin_amdgcn_mfma_f32_16x16x32_bf16(al0, bh[nt],  acc[0][nt], 0, 0, 0);
        acc[1][nt] = __builtin_amdgcn_mfma_f32_16x16x32_bf16(al1, bh[nt],  acc[1][nt], 0, 0, 0);
        acc[0][nt] = __builtin_amdgcn_mfma_f32_16x16x32_bf16(ah0, blo[nt], acc[0][nt], 0, 0, 0);
        acc[1][nt] = __builtin_amdgcn_mfma_f32_16x16x32_bf16(ah1, blo[nt], acc[1][nt], 0, 0, 0);
      }
    }
    __syncthreads();
  }
#pragma unroll
  for (int mt = 0; mt < 2; ++mt) {
#pragma unroll
    for (int nt = 0; nt < 4; ++nt) {
#pragma unroll
      for (int reg = 0; reg < 4; ++reg) {
        int row = bm + wave * 32 + mt * 16 + quad * 4 + reg;
        int col = bn + nt * 16 + lrow;
        if (row < M) {
          float v = acc[mt][nt][reg];
          if (bias) v += bias[col];
          C[(size_t)row * N + col] = v;
        }
      }
    }
  }
}

// ---------------- fused KAN GEMM: C[M,N] = expand(A)[M,In*9] @ BT[N,In*9]^T ----------------
// A: fp32 [M,In] raw; expansion (silu | 8 cubic bases) + hi/lo split during A staging.
// B pre-split bf16 hi/lo [N, In*9]. BM in {64,128}, BN=64, BK=64, 256 threads.
template<int BM>
__global__ __launch_bounds__(256) void gemm_kan(
    const float* __restrict__ A, const ushort* __restrict__ Bhg, const ushort* __restrict__ Blg,
    float* __restrict__ C, int M, int In, int N) {
  const int K = In * 9;
  constexpr int LDA = 72;
  __shared__ __align__(16) ushort Ah[BM * LDA];
  __shared__ __align__(16) ushort Al[BM * LDA];
  __shared__ __align__(16) ushort Bh[64 * LDA];
  __shared__ __align__(16) ushort Bl[64 * LDA];
  const int tid = threadIdx.x;
  const int lane = tid & 63, wave = tid >> 6;
  const int lrow = lane & 15, quad = lane >> 4;
  const int bm = blockIdx.y * BM, bn = blockIdx.x * 64;
  constexpr int MT = BM / 64;
  floatx4 acc[MT][4] = {};
  for (int k0 = 0; k0 < K; k0 += 64) {
    // ---- stage A with on-the-fly expansion + split ----
    if (k0 < In) {
#pragma unroll
      for (int i = 0; i < BM / 16; ++i) {
        int c = tid + i * 256;
        int row = c >> 4, col4 = c & 15;
        int gr = bm + row;
        float4 v = make_float4(0.f, 0.f, 0.f, 0.f);
        if (gr < M) v = *(const float4*)(A + (size_t)gr * In + k0 + col4 * 4);
        float vv[4] = {silu_f(v.x), silu_f(v.y), silu_f(v.z), silu_f(v.w)};
        ushort h0 = f2bf(vv[0]), h1 = f2bf(vv[1]), h2 = f2bf(vv[2]), h3 = f2bf(vv[3]);
        ushort l0 = f2bf(vv[0] - bf2f(h0)), l1 = f2bf(vv[1] - bf2f(h1));
        ushort l2 = f2bf(vv[2] - bf2f(h2)), l3 = f2bf(vv[3] - bf2f(h3));
        *(uint2*)&Ah[row * LDA + col4 * 4] =
          make_uint2((unsigned)h0 | ((unsigned)h1 << 16), (unsigned)h2 | ((unsigned)h3 << 16));
        *(uint2*)&Al[row * LDA + col4 * 4] =
          make_uint2((unsigned)l0 | ((unsigned)l1 << 16), (unsigned)l2 | ((unsigned)l3 << 16));
      }
    } else {
      int i0 = (k0 - In) >> 3;
      if (tid < BM * 2) {
        int row = tid >> 1, half = tid & 1;
        int gr = bm + row;
        float4 v = make_float4(0.f, 0.f, 0.f, 0.f);
        if (gr < M) v = *(const float4*)(A + (size_t)gr * In + i0 + half * 4);
        float vv[4] = {v.x, v.y, v.z, v.w};
#pragma unroll
        for (int jj = 0; jj < 4; ++jj) {
          float b8[8];
          kan_bases(vv[jj], b8);
          unsigned hu[4], lu[4];
#pragma unroll
          for (int q = 0; q < 4; ++q) {
            ushort ha = f2bf(b8[2 * q]), hb = f2bf(b8[2 * q + 1]);
            ushort la = f2bf(b8[2 * q] - bf2f(ha)), lb = f2bf(b8[2 * q + 1] - bf2f(hb));
            hu[q] = (unsigned)ha | ((unsigned)hb << 16);
            lu[q] = (unsigned)la | ((unsigned)lb << 16);
          }
          int cbase = (half * 4 + jj) * 8;
          *(uint4*)&Ah[row * LDA + cbase] = make_uint4(hu[0], hu[1], hu[2], hu[3]);
          *(uint4*)&Al[row * LDA + cbase] = make_uint4(lu[0], lu[1], lu[2], lu[3]);
        }
      }
    }
    // ---- stage B hi/lo: direct copies ----
#pragma unroll
    for (int i = 0; i < 2; ++i) {
      int c = tid + i * 256;
      int row = c >> 3, col8 = c & 7;
      *(uint4*)&Bh[row * LDA + col8 * 8] = *(const uint4*)(Bhg + (size_t)(bn + row) * K + k0 + col8 * 8);
      *(uint4*)&Bl[row * LDA + col8 * 8] = *(const uint4*)(Blg + (size_t)(bn + row) * K + k0 + col8 * 8);
    }
    __syncthreads();
#pragma unroll
    for (int kk = 0; kk < 64; kk += 32) {
      int kof = kk + quad * 8;
      short8 ah[MT], al[MT];
#pragma unroll
      for (int mt = 0; mt < MT; ++mt) {
        int ra = (wave * (BM / 4) + mt * 16 + lrow) * LDA + kof;
        ah[mt] = *(const short8*)&Ah[ra];
        al[mt] = *(const short8*)&Al[ra];
      }
      short8 bh[4], blo[4];
#pragma unroll
      for (int nt = 0; nt < 4; ++nt) {
        int rb = (nt * 16 + lrow) * LDA + kof;
        bh[nt]  = *(const short8*)&Bh[rb];
        blo[nt] = *(const short8*)&Bl[rb];
      }
#pragma unroll
      for (int nt = 0; nt < 4; ++nt) {
#pragma unroll
        for (int mt = 0; mt < MT; ++mt) {
          acc[mt][nt] = __builtin_amdgcn_mfma_f32_16x16x32_bf16(ah[mt], bh[nt],  acc[mt][nt], 0, 0, 0);
          acc[mt][nt] = __builtin_amdgcn_mfma_f32_16x16x32_bf16(al[mt], bh[nt],  acc[mt][nt], 0, 0, 0);
          acc[mt][nt] = __builtin_amdgcn_mfma_f32_16x16x32_bf16(ah[mt], blo[nt], acc[mt][nt], 0, 0, 0);
        }
      }
    }
    __syncthreads();
  }
#pragma unroll
  for (int mt = 0; mt < MT; ++mt) {
#pragma unroll
    for (int nt = 0; nt < 4; ++nt) {
#pragma unroll
      for (int reg = 0; reg < 4; ++reg) {
        int row = bm + wave * (BM / 4) + mt * 16 + quad * 4 + reg;
        int col = bn + nt * 16 + lrow;
        if (row < M) C[(size_t)row * N + col] = acc[mt][nt][reg];
      }
    }
  }
}

// ---------------- merged weight transpose+split: [Wl|Wr] -> hi/lo bf16 [G][1024][128] ----
__global__ void conv_wT2(const float* __restrict__ Wl, const float* __restrict__ Wr,
                         const float* __restrict__ bl, const float* __restrict__ br,
                         ushort* __restrict__ WTh, ushort* __restrict__ WTl,
                         float* __restrict__ bout, int total) {
  int i = blockIdx.x * 256 + threadIdx.x;
  if (i >= total) return;
  int g = i / (1024 * 128), rem = i % (1024 * 128);
  int n = rem >> 7, k = rem & 127;
  int nn = n & 511;
  const float* W = (n < 512) ? Wl : Wr;
  float v = W[(size_t)g * 65536 + (size_t)k * 512 + nn];
  ushort hi = f2bf(v);
  WTh[i] = hi;
  WTl[i] = f2bf(v - bf2f(hi));
  if (k == 0) bout[g * 1024 + n] = ((n < 512) ? bl : br)[g * 512 + nn];
}

// ---------------- build expanded KAN weight, transposed + split: BT[o, k] ----------------
__global__ void build_kan_wT(const float* __restrict__ base_w, const float* __restrict__ spline_w,
                             const float* __restrict__ scaler,
                             ushort* __restrict__ BTh, ushort* __restrict__ BTl,
                             int In, int Out) {
  int i = blockIdx.x * 256 + threadIdx.x;
  if (i >= In * 9 * Out) return;
  int o = i / (In * 9), k = i % (In * 9);
  float v;
  if (k < In) v = base_w[(size_t)o * In + k];
  else {
    int q = k - In, ii = q >> 3, gq = q & 7;
    v = spline_w[((size_t)o * In + ii) * 8 + gq] * scaler[(size_t)o * In + ii];
  }
  ushort hi = f2bf(v);
  BTh[i] = hi;
  BTl[i] = f2bf(v - bf2f(hi));
}

// ---------------- input projection (writes fp32 h + hi/lo bf16) ----------------
__global__ __launch_bounds__(128) void input_proj(
    const float* __restrict__ x, const float* __restrict__ id_emb,
    const int* __restrict__ id_token, const float* __restrict__ inW,
    const float* __restrict__ inb, float* __restrict__ h,
    ushort* __restrict__ hh, ushort* __restrict__ hl) {
  int n = blockIdx.x, j = threadIdx.x;
  __shared__ float s[FNODE + IDDIM];
  if (j < FNODE) s[j] = x[(size_t)n * FNODE + j];
  else if (j < FNODE + IDDIM) s[j] = id_emb[(size_t)id_token[n] * IDDIM + (j - FNODE)];
  __syncthreads();
  float acc = inb[j];
#pragma unroll
  for (int k = 0; k < FNODE + IDDIM; ++k) acc = fmaf(s[k], inW[k * HID + j], acc);
  float v = silu_f(acc);
  h[(size_t)n * HID + j] = v;
  ushort hi = f2bf(v);
  hh[(size_t)n * HID + j] = hi;
  hl[(size_t)n * HID + j] = f2bf(v - bf2f(hi));
}

// ---------------- per-layer prep ----------------
__global__ __launch_bounds__(512) void layer_prep(
    const float* __restrict__ rel_gate, const float* __restrict__ gat_bias,
    const float* __restrict__ rel_emb, const float* __restrict__ We, int l,
    float* __restrict__ gates, float* __restrict__ msg_bias, float* __restrict__ erel) {
  int j = threadIdx.x;
  float g[NR]; float mx = -1e30f;
  for (int r = 0; r < NR; ++r) { g[r] = rel_gate[l * NR + r]; mx = fmaxf(mx, g[r]); }
  float s = 0.f;
  for (int r = 0; r < NR; ++r) { g[r] = expf(g[r] - mx); s += g[r]; }
  for (int r = 0; r < NR; ++r) g[r] /= s;
  if (j < NR) gates[j] = g[j];
  if (j < HID) {
    float b = 0.f;
    for (int r = 0; r < NR; ++r) b = fmaf(g[r], gat_bias[((size_t)(l * NR + r)) * HID + j], b);
    msg_bias[j] = b;
  }
  for (int r = 0; r < NR; ++r) {
    const float* Wer = We + ((size_t)(l * NR + r)) * 24 * 512;
    const float* re  = rel_emb + (l * NR + r) * RELDIM;
    float acc = 0.f;
#pragma unroll
    for (int q = 0; q < RELDIM; ++q) acc = fmaf(re[q], Wer[(FEDGE + q) * 512 + j], acc);
    erel[r * 512 + j] = acc;
  }
}

// ---------------- fills ----------------
__global__ void fill_md(unsigned* __restrict__ menc, float* __restrict__ denom) {
  int i = blockIdx.x * 256 + threadIdx.x;
  if (i < NN * NHEADS) { menc[i] = ENC_NEG_INF; denom[i] = 0.f; }
}
__global__ void fill_zero(float* __restrict__ p, int n) {
  int i = blockIdx.x * 256 + threadIdx.x;
  if (i < n) p[i] = 0.f;
}

// ---------------- edge pass 1: score + segment max (xlr stride 1024; xr = xlr+512) ------
__global__ __launch_bounds__(128) void edge_score(
    const int* __restrict__ etype, const int* __restrict__ eidx,
    const float* __restrict__ eattr, const float* __restrict__ xlr,
    const float* __restrict__ We_r, const float* __restrict__ erel_r,
    const float* __restrict__ att_r,
    int r, float* __restrict__ score, unsigned* __restrict__ menc) {
  int e = blockIdx.x;
  if (etype[e] != r) return;
  int s = eidx[e], t = eidx[NE + e];
  int d = threadIdx.x;
  __shared__ float ea[FEDGE];
  __shared__ float red[2][NHEADS];
  if (d < FEDGE) ea[d] = eattr[(size_t)e * FEDGE + d];
  __syncthreads();
  const float* xls = xlr + (size_t)s * 1024;
  const float* xrt = xlr + (size_t)t * 1024 + 512;
  float vs[NHEADS];
#pragma unroll
  for (int hh = 0; hh < NHEADS; ++hh) {
    int idx = hh * HID + d;
    float ev = erel_r[idx];
#pragma unroll
    for (int k = 0; k < FEDGE; ++k) ev = fmaf(ea[k], We_r[k * 512 + idx], ev);
    float z = xls[idx] + xrt[idx] + ev;
    z = (z > 0.f) ? z : 0.2f * z;       // leaky_relu 0.2
    float v = z * att_r[hh * HID + d];
#pragma unroll
    for (int off = 32; off > 0; off >>= 1) v += __shfl_down(v, off, 64);
    vs[hh] = v;
  }
  if ((d & 63) == 0) {
#pragma unroll
    for (int hh = 0; hh < NHEADS; ++hh) red[d >> 6][hh] = vs[hh];
  }
  __syncthreads();
  if (d == 0) {
#pragma unroll
    for (int hh = 0; hh < NHEADS; ++hh) {
      float tot = red[0][hh] + red[1][hh];
      score[(size_t)e * NHEADS + hh] = tot;
      atomicMax(&menc[t * NHEADS + hh], fenc(tot));
    }
  }
}

// ---------------- edge pass 2: exp + segment sum ----------------
__global__ void edge_expsum(
    const int* __restrict__ etype, const int* __restrict__ eidx,
    const float* __restrict__ score, const unsigned* __restrict__ menc,
    float* __restrict__ ex, float* __restrict__ denom, int r) {
  int i = blockIdx.x * 256 + threadIdx.x;
  if (i >= NE * NHEADS) return;
  int e = i >> 2, hh = i & 3;
  if (etype[e] != r) return;
  int t = eidx[NE + e];
  float m = fdec(menc[t * NHEADS + hh]);
  float v = expf(score[i] - m);
  ex[i] = v;
  atomicAdd(&denom[t * NHEADS + hh], v);
}

// ---------------- edge pass 3: weighted aggregation (head-mean folded in) ----------------
__global__ __launch_bounds__(128) void edge_agg(
    const int* __restrict__ etype, const int* __restrict__ eidx,
    const float* __restrict__ ex, const float* __restrict__ denom,
    const float* __restrict__ xlr, const float* __restrict__ gates,
    float* __restrict__ hmsg, int r) {
  int e = blockIdx.x;
  if (etype[e] != r) return;
  int s = eidx[e], t = eidx[NE + e];
  int d = threadIdx.x;
  float gr = gates[r] * 0.25f;  // head mean folded into segment sum
  float alpha[NHEADS];
#pragma unroll
  for (int hh = 0; hh < NHEADS; ++hh)
    alpha[hh] = ex[(size_t)e * NHEADS + hh] / fmaxf(denom[t * NHEADS + hh], 1e-16f);
  const float* xls = xlr + (size_t)s * 1024;
  float v = 0.f;
#pragma unroll
  for (int hh = 0; hh < NHEADS; ++hh) v = fmaf(alpha[hh], xls[hh * HID + d], v);
  atomicAdd(&hmsg[(size_t)t * HID + d], gr * v);
}

// ---------------- LayerNorm over 128 dims (optionally emits hi/lo bf16) ----------------
__global__ __launch_bounds__(64) void ln128(
    float* __restrict__ h, const float* __restrict__ add, const float* __restrict__ bvec,
    const float* __restrict__ g, const float* __restrict__ b,
    ushort* __restrict__ hh, ushort* __restrict__ hl) {
  int n = blockIdx.x, lane = threadIdx.x;
  size_t base = (size_t)n * HID;
  float x0 = h[base + lane] + add[base + lane];
  float x1 = h[base + 64 + lane] + add[base + 64 + lane];
  if (bvec) { x0 += bvec[lane]; x1 += bvec[64 + lane]; }
  float s = x0 + x1;
#pragma unroll
  for (int m = 32; m > 0; m >>= 1) s += __shfl_xor(s, m, 64);
  float mu = s * (1.f / 128.f);
  float d0 = x0 - mu, d1 = x1 - mu;
  float q = d0 * d0 + d1 * d1;
#pragma unroll
  for (int m = 32; m > 0; m >>= 1) q += __shfl_xor(q, m, 64);
  float inv = 1.f / sqrtf(q * (1.f / 128.f) + 1e-5f);
  float o0 = d0 * inv * g[lane] + b[lane];
  float o1 = d1 * inv * g[64 + lane] + b[64 + lane];
  h[base + lane]      = o0;
  h[base + 64 + lane] = o1;
  if (hh) {
    ushort i0 = f2bf(o0), i1 = f2bf(o1);
    hh[base + lane] = i0;        hh[base + 64 + lane] = i1;
    hl[base + lane] = f2bf(o0 - bf2f(i0));
    hl[base + 64 + lane] = f2bf(o1 - bf2f(i1));
  }
}

// ---------------- KAN expansion (fp32) — tiny readout head only ----------------
__global__ void expand_f32(const float* __restrict__ v, float* __restrict__ u, int In, int rows) {
  int i = blockIdx.x * 256 + threadIdx.x;
  if (i >= rows * In) return;
  int n = i / In, c = i % In;
  float x = v[(size_t)n * In + c];
  size_t base = (size_t)n * In * 9;
  u[base + c] = silu_f(x);
  float b8[8];
  kan_bases(x, b8);
  float* ub = u + base + In + (size_t)c * 8;
#pragma unroll
  for (int gq = 0; gq < 8; ++gq) ub[gq] = b8[gq];
}

// ---------------- readout ----------------
__global__ void pool_init(float* __restrict__ mean, unsigned* __restrict__ maxenc, float* __restrict__ cnt) {
  int i = blockIdx.x * 256 + threadIdx.x;
  if (i < NG * HID) { mean[i] = 0.f; maxenc[i] = ENC_NEG_INF; }
  if (i < NG) cnt[i] = 0.f;
}
__global__ __launch_bounds__(128) void pool_accum(
    const float* __restrict__ h, const int* __restrict__ batch,
    float* __restrict__ mean, unsigned* __restrict__ maxenc, float* __restrict__ cnt) {
  int n = blockIdx.x, d = threadIdx.x;
  int g = batch[n];
  float v = h[(size_t)n * HID + d];
  atomicAdd(&mean[g * HID + d], v);
  atomicMax(&maxenc[g * HID + d], fenc(v));
  if (d == 0) atomicAdd(&cnt[g], 1.f);
}
__global__ __launch_bounds__(256) void pool_final_ln(
    const float* __restrict__ mean, const unsigned* __restrict__ maxenc,
    const float* __restrict__ cnt, const float* __restrict__ rog,
    const float* __restrict__ rob, float* __restrict__ gvec) {
  int g = blockIdx.x, j = threadIdx.x;
  __shared__ float rb[256];
  float x;
  if (j < HID) x = mean[g * HID + j] / fmaxf(cnt[g], 1.f);
  else {
    float mv = fdec(maxenc[g * HID + (j - HID)]);
    x = (mv > -1e38f) ? mv : 0.f;  // where(isfinite, ., 0)
  }
  rb[j] = x; __syncthreads();
  for (int st = 128; st > 0; st >>= 1) { if (j < st) rb[j] += rb[j + st]; __syncthreads(); }
  float mu = rb[0] * (1.f / 256.f); __syncthreads();
  float d = x - mu;
  rb[j] = d * d; __syncthreads();
  for (int st = 128; st > 0; st >>= 1) { if (j < st) rb[j] += rb[j + st]; __syncthreads(); }
  float var = rb[0] * (1.f / 256.f);
  float inv = 1.f / sqrtf(var + 1e-5f);
  gvec[(size_t)g * 256 + j] = d * inv * rog[j] + rob[j];
}

// ---------------- small KAN head (fp32, raw weights) ----------------
__global__ void kan_head(const float* __restrict__ u, const float* __restrict__ base_w,
                         const float* __restrict__ spline_w, const float* __restrict__ scaler,
                         float* __restrict__ out, int In, int Out) {
  int o = blockIdx.x * 64 + threadIdx.x;
  int g = blockIdx.y;
  if (o >= Out) return;
  const float* ug = u + (size_t)g * In * 9;
  float acc = 0.f;
  for (int i = 0; i < In; ++i) acc = fmaf(ug[i], base_w[(size_t)o * In + i], acc);
  for (int i = 0; i < In; ++i) {
    const float* sp = spline_w + ((size_t)o * In + i) * 8;
    const float* ub = ug + In + (size_t)i * 8;
    float a2 = 0.f;
#pragma unroll
    for (int gq = 0; gq < 8; ++gq) a2 = fmaf(ub[gq], sp[gq], a2);
    acc = fmaf(scaler[(size_t)o * In + i], a2, acc);
  }
  out[(size_t)g * Out + o] = acc;
}

// ---------------- launch ----------------
extern "C" void kernel_launch(void* const* d_in, const int* in_sizes, int n_in,
                              void* d_out, int out_size, void* d_ws, size_t ws_size,
                              hipStream_t stream) {
  const float* x         = (const float*)d_in[0];
  const float* edge_attr = (const float*)d_in[1];
  const int*   id_token  = (const int*)  d_in[2];
  const int*   edge_index= (const int*)  d_in[3];
  const int*   edge_type = (const int*)  d_in[4];
  const int*   batch     = (const int*)  d_in[5];
  const float* id_emb    = (const float*)d_in[6];
  const float* inW       = (const float*)d_in[7];
  const float* inb       = (const float*)d_in[8];
  const float* Wl        = (const float*)d_in[9];
  const float* bl        = (const float*)d_in[10];
  const float* Wr        = (const float*)d_in[11];
  const float* br        = (const float*)d_in[12];
  const float* We        = (const float*)d_in[13];
  const float* att       = (const float*)d_in[14];
  const float* gat_bias  = (const float*)d_in[15];
  const float* rel_gate  = (const float*)d_in[16];
  const float* rel_emb   = (const float*)d_in[17];
  const float* ln1g      = (const float*)d_in[18];
  const float* ln1b      = (const float*)d_in[19];
  const float* ln2g      = (const float*)d_in[20];
  const float* ln2b      = (const float*)d_in[21];
  const float* ffn1_base = (const float*)d_in[22];
  const float* ffn1_spl  = (const float*)d_in[23];
  const float* ffn1_sc   = (const float*)d_in[24];
  const float* ffn2_base = (const float*)d_in[25];
  const float* ffn2_spl  = (const float*)d_in[26];
  const float* ffn2_sc   = (const float*)d_in[27];
  const float* rog       = (const float*)d_in[28];
  const float* rob       = (const float*)d_in[29];
  const float* h1_base   = (const float*)d_in[30];
  const float* h1_spl    = (const float*)d_in[31];
  const float* h1_sc     = (const float*)d_in[32];
  const float* h2_base   = (const float*)d_in[33];
  const float* h2_spl    = (const float*)d_in[34];
  const float* h2_sc     = (const float*)d_in[35];
  (void)in_sizes; (void)n_in; (void)out_size; (void)ws_size;

  // ---- workspace carve (256B aligned) ----
  char* wsp = (char*)d_ws;
  size_t off = 0;
  auto carve = [&](size_t bytes) { char* p = wsp + off; off = (off + bytes + 255) & ~(size_t)255; return p; };
  float*    h     = (float*)   carve((size_t)NN * HID * 4);
  ushort*   h_hi  = (ushort*)  carve((size_t)NN * HID * 2);
  ushort*   h_lo  = (ushort*)  carve((size_t)NN * HID * 2);
  float*    hmsg  = (float*)   carve((size_t)NN * HID * 4);
  float*    t1    = (float*)   carve((size_t)NN * FFNH * 4);
  unsigned* menc  = (unsigned*)carve((size_t)NN * NHEADS * 4);
  float*    denom = (float*)   carve((size_t)NN * NHEADS * 4);
  float*    gates = (float*)   carve(NR * 4);
  float*    msgb  = (float*)   carve(HID * 4);
  float*    erel  = (float*)   carve(NR * 512 * 4);
  ushort*   WTh   = (ushort*)  carve((size_t)NL * NR * 1024 * HID * 2);
  ushort*   WTl   = (ushort*)  carve((size_t)NL * NR * 1024 * HID * 2);
  float*    blr   = (float*)   carve((size_t)NL * NR * 1024 * 4);
  ushort*   B1h   = (ushort*)  carve((size_t)FFNH * HID * 9 * 2);   // [256][1152]
  ushort*   B1l   = (ushort*)  carve((size_t)FFNH * HID * 9 * 2);
  ushort*   B2h   = (ushort*)  carve((size_t)HID * FFNH * 9 * 2);   // [128][2304]
  ushort*   B2l   = (ushort*)  carve((size_t)HID * FFNH * 9 * 2);
  float*    pm    = (float*)   carve((size_t)NG * HID * 4);
  unsigned* pmax  = (unsigned*)carve((size_t)NG * HID * 4);
  float*    cnt   = (float*)   carve(NG * 4);
  float*    gvec  = (float*)   carve((size_t)NG * 256 * 4);
  float*    uhead = (float*)   carve((size_t)NG * 256 * 9 * 4);
  float*    thead = (float*)   carve((size_t)NG * HEADH * 4);
  float*    xlr   = (float*)   carve((size_t)NN * 1024 * 4);        // 41 MB
  float*    score = (float*)   carve((size_t)NE * NHEADS * 4);
  float*    exbuf = (float*)   carve((size_t)NE * NHEADS * 4);

  // ---- weight transpose + split (once per launch) ----
  {
    int total = NL * NR * 1024 * 128;
    conv_wT2<<<(total + 255) / 256, 256, 0, stream>>>(Wl, Wr, bl, br, WTh, WTl, blr, total);
  }

  // ---- input projection ----
  input_proj<<<NN, 128, 0, stream>>>(x, id_emb, id_token, inW, inb, h, h_hi, h_lo);

  const int MB128 = (NN + 127) / 128;  // 79
  const int MB64  = (NN + 63) / 64;    // 157
  for (int l = 0; l < NL; ++l) {
    layer_prep<<<1, 512, 0, stream>>>(rel_gate, gat_bias, rel_emb, We, l, gates, msgb, erel);
    fill_zero<<<(NN * HID + 255) / 256, 256, 0, stream>>>(hmsg, NN * HID);
    for (int r = 0; r < NR; ++r) {
      const ushort* WThr = WTh + ((size_t)(l * NR + r)) * 1024 * HID;
      const ushort* WTlr = WTl + ((size_t)(l * NR + r)) * 1024 * HID;
      const float* blrr  = blr + (size_t)(l * NR + r) * 1024;
      const float* Wer   = We + ((size_t)(l * NR + r)) * 24 * 512;
      const float* attr  = att + (size_t)(l * NR + r) * 512;
      gemm_bf3<<<dim3(1024 / 64, MB128), 256, 0, stream>>>(h_hi, h_lo, WThr, WTlr, blrr, xlr, NN, HID, 1024);
      fill_md<<<(NN * NHEADS + 255) / 256, 256, 0, stream>>>(menc, denom);
      edge_score<<<NE, 128, 0, stream>>>(edge_type, edge_index, edge_attr, xlr,
                                         Wer, erel + r * 512, attr, r, score, menc);
      edge_expsum<<<(NE * NHEADS + 255) / 256, 256, 0, stream>>>(edge_type, edge_index,
                                                                 score, menc, exbuf, denom, r);
      edge_agg<<<NE, 128, 0, stream>>>(edge_type, edge_index, exbuf, denom, xlr, gates, hmsg, r);
    }
    ln128<<<NN, 64, 0, stream>>>(h, hmsg, msgb, ln1g + l * HID, ln1b + l * HID, nullptr, nullptr);

    // ---- KAN FFN1: 128 -> 256 (K = 1152), fused expansion ----
    build_kan_wT<<<((HID * 9 * FFNH) + 255) / 256, 256, 0, stream>>>(
        ffn1_base + (size_t)l * FFNH * HID, ffn1_spl + (size_t)l * FFNH * HID * 8,
        ffn1_sc + (size_t)l * FFNH * HID, B1h, B1l, HID, FFNH);
    gemm_kan<128><<<dim3(FFNH / 64, MB128), 256, 0, stream>>>(h, B1h, B1l, t1, NN, HID, FFNH);
    // ---- KAN FFN2: 256 -> 128 (K = 2304), fused expansion ----
    build_kan_wT<<<((FFNH * 9 * HID) + 255) / 256, 256, 0, stream>>>(
        ffn2_base + (size_t)l * HID * FFNH, ffn2_spl + (size_t)l * HID * FFNH * 8,
        ffn2_sc + (size_t)l * HID * FFNH, B2h, B2l, FFNH, HID);
    gemm_kan<64><<<dim3(HID / 64, MB64), 256, 0, stream>>>(t1, B2h, B2l, hmsg, NN, FFNH, HID);
    // ln2 refreshes h_hi/h_lo for next layer's projections
    ln128<<<NN, 64, 0, stream>>>(h, hmsg, nullptr, ln2g + l * HID, ln2b + l * HID, h_hi, h_lo);
  }

  // ---- readout ----
  pool_init<<<(NG * HID + 255) / 256, 256, 0, stream>>>(pm, pmax, cnt);
  pool_accum<<<NN, 128, 0, stream>>>(h, batch, pm, pmax, cnt);
  pool_final_ln<<<NG, 256, 0, stream>>>(pm, pmax, cnt, rog, rob, gvec);
  expand_f32<<<((NG * 256) + 255) / 256, 256, 0, stream>>>(gvec, uhead, 256, NG);
  kan_head<<<dim3(2, NG), 64, 0, stream>>>(uhead, h1_base, h1_spl, h1_sc, thead, 256, HEADH);
  expand_f32<<<((NG * HEADH) + 255) / 256, 256, 0, stream>>>(thead, uhead, HEADH, NG);
  kan_head<<<dim3(1, NG), 64, 0, stream>>>(uhead, h2_base, h2_spl, h2_sc, (float*)d_out, HEADH, NCLS);
}

// Round 6
// 2245.183 us; speedup vs baseline: 1.6099x; 1.2245x over previous
//
#include <hip/hip_runtime.h>
#include <cstdint>
#include <cstddef>

// ---------------- static problem config ----------------
#define NN      10000   // nodes
#define NE      120000  // edges
#define NG      32      // graphs
#define FNODE   64
#define FEDGE   16
#define HID     128
#define NHEADS  4
#define NL      3
#define NR      4
#define IDDIM   32
#define RELDIM  8
#define FFNH    256
#define HEADH   128
#define NCLS    10

typedef __attribute__((ext_vector_type(8))) short short8;
typedef __attribute__((ext_vector_type(4))) float floatx4;

// ---------------- helpers ----------------
__device__ __forceinline__ unsigned fenc(float f) {
  unsigned u = __float_as_uint(f);
  return (u & 0x80000000u) ? ~u : (u | 0x80000000u);
}
__device__ __forceinline__ float fdec(unsigned k) {
  return __uint_as_float((k & 0x80000000u) ? (k ^ 0x80000000u) : ~k);
}
__device__ __forceinline__ float silu_f(float x) { return x / (1.f + expf(-x)); }
__device__ __forceinline__ ushort f2bf(float f) {   // round-to-nearest-even bf16
  unsigned u = __float_as_uint(f);
  return (ushort)((u + 0x7FFFu + ((u >> 16) & 1u)) >> 16);
}
__device__ __forceinline__ float bf2f(ushort h) { return __uint_as_float((unsigned)h << 16); }

#define ENC_NEG_INF 0x007FFFFFu

// Cox–de Boor cubic bases on grid t_j = (j-3)*0.4 - 1 (GRID_SIZE=5, ORDER=3) -> 8 bases
__device__ __forceinline__ void kan_bases(float x, float* out8) {
  float bb[11];
#pragma unroll
  for (int j = 0; j < 11; ++j) {
    float t0 = (j - 3) * 0.4f - 1.f;
    float t1 = (j - 2) * 0.4f - 1.f;
    bb[j] = (x >= t0 && x < t1) ? 1.f : 0.f;
  }
  {
    const float inv = 1.f / 0.4f;
#pragma unroll
    for (int j = 0; j < 10; ++j) {
      float tj = (j - 3) * 0.4f - 1.f, tjp1 = (j - 1) * 0.4f - 1.f;
      bb[j] = ((x - tj) * bb[j] + (tjp1 - x) * bb[j + 1]) * inv;
    }
  }
  {
    const float inv = 1.f / 0.8f;
#pragma unroll
    for (int j = 0; j < 9; ++j) {
      float tj = (j - 3) * 0.4f - 1.f, tjp1 = (j) * 0.4f - 1.f;
      bb[j] = ((x - tj) * bb[j] + (tjp1 - x) * bb[j + 1]) * inv;
    }
  }
  {
    const float inv = 1.f / 1.2000001f;
#pragma unroll
    for (int j = 0; j < 8; ++j) {
      float tj = (j - 3) * 0.4f - 1.f, tjp1 = (j + 1) * 0.4f - 1.f;
      bb[j] = ((x - tj) * bb[j] + (tjp1 - x) * bb[j + 1]) * inv;
    }
  }
#pragma unroll
  for (int j = 0; j < 8; ++j) out8[j] = bb[j];
}

// ---------------- 3-term MFMA GEMM, operands pre-split bf16 hi/lo ----------------
__global__ __launch_bounds__(256) void gemm_bf3(
    const ushort* __restrict__ Ahg, const ushort* __restrict__ Alg,
    const ushort* __restrict__ Bhg, const ushort* __restrict__ Blg,
    const float* __restrict__ bias, float* __restrict__ C,
    int M, int K, int N) {
  constexpr int LDA = 72;
  __shared__ __align__(16) ushort Ah[128 * LDA];
  __shared__ __align__(16) ushort Al[128 * LDA];
  __shared__ __align__(16) ushort Bh[64 * LDA];
  __shared__ __align__(16) ushort Bl[64 * LDA];
  const int tid = threadIdx.x;
  const int lane = tid & 63, wave = tid >> 6;
  const int lrow = lane & 15, quad = lane >> 4;
  const int bm = blockIdx.y * 128, bn = blockIdx.x * 64;
  floatx4 acc[2][4] = {};
  for (int k0 = 0; k0 < K; k0 += 64) {
#pragma unroll
    for (int i = 0; i < 4; ++i) {
      int c = tid + i * 256;
      int row = c >> 3, col8 = c & 7;
      int gr = bm + row;
      uint4 vh = make_uint4(0, 0, 0, 0), vl = make_uint4(0, 0, 0, 0);
      if (gr < M) {
        vh = *(const uint4*)(Ahg + (size_t)gr * K + k0 + col8 * 8);
        vl = *(const uint4*)(Alg + (size_t)gr * K + k0 + col8 * 8);
      }
      *(uint4*)&Ah[row * LDA + col8 * 8] = vh;
      *(uint4*)&Al[row * LDA + col8 * 8] = vl;
    }
#pragma unroll
    for (int i = 0; i < 2; ++i) {
      int c = tid + i * 256;
      int row = c >> 3, col8 = c & 7;
      *(uint4*)&Bh[row * LDA + col8 * 8] = *(const uint4*)(Bhg + (size_t)(bn + row) * K + k0 + col8 * 8);
      *(uint4*)&Bl[row * LDA + col8 * 8] = *(const uint4*)(Blg + (size_t)(bn + row) * K + k0 + col8 * 8);
    }
    __syncthreads();
#pragma unroll
    for (int kk = 0; kk < 64; kk += 32) {
      int kof = kk + quad * 8;
      const int ra0 = (wave * 32 + lrow) * LDA + kof;
      const int ra1 = (wave * 32 + 16 + lrow) * LDA + kof;
      short8 ah0 = *(const short8*)&Ah[ra0];
      short8 ah1 = *(const short8*)&Ah[ra1];
      short8 al0 = *(const short8*)&Al[ra0];
      short8 al1 = *(const short8*)&Al[ra1];
      short8 bh[4], blo[4];
#pragma unroll
      for (int nt = 0; nt < 4; ++nt) {
        int rb = (nt * 16 + lrow) * LDA + kof;
        bh[nt]  = *(const short8*)&Bh[rb];
        blo[nt] = *(const short8*)&Bl[rb];
      }
#pragma unroll
      for (int nt = 0; nt < 4; ++nt) {
        acc[0][nt] = __builtin_amdgcn_mfma_f32_16x16x32_bf16(ah0, bh[nt],  acc[0][nt], 0, 0, 0);
        acc[1][nt] = __builtin_amdgcn_mfma_f32_16x16x32_bf16(ah1, bh[nt],  acc[1][nt], 0, 0, 0);
        acc[0][nt] = __builtin_amdgcn_mfma_f32_16x16x32_bf16(al0, bh[nt],  acc[0][nt], 0, 0, 0);
        acc[1][nt] = __builtin_amdgcn_mfma_f32_16x16x32_bf16(al1, bh[nt],  acc[1][nt], 0, 0, 0);
        acc[0][nt] = __builtin_amdgcn_mfma_f32_16x16x32_bf16(ah0, blo[nt], acc[0][nt], 0, 0, 0);
        acc[1][nt] = __builtin_amdgcn_mfma_f32_16x16x32_bf16(ah1, blo[nt], acc[1][nt], 0, 0, 0);
      }
    }
    __syncthreads();
  }
#pragma unroll
  for (int mt = 0; mt < 2; ++mt) {
#pragma unroll
    for (int nt = 0; nt < 4; ++nt) {
#pragma unroll
      for (int reg = 0; reg < 4; ++reg) {
        int row = bm + wave * 32 + mt * 16 + quad * 4 + reg;
        int col = bn + nt * 16 + lrow;
        if (row < M) {
          float v = acc[mt][nt][reg];
          if (bias) v += bias[col];
          C[(size_t)row * N + col] = v;
        }
      }
    }
  }
}

// ---------------- fused KAN GEMM w/ split-K: C += expand(A) @ BT^T ----------------
// A: fp32 [M,In]; expansion computed during staging. B pre-split bf16 hi/lo [N, In*9].
// Grid.z = SPLIT; each split handles a K-tile chunk; epilogue atomicAdd (C pre-zeroed).
template<int BM, int SPLIT>
__global__ __launch_bounds__(256) void gemm_kan(
    const float* __restrict__ A, const ushort* __restrict__ Bhg, const ushort* __restrict__ Blg,
    float* __restrict__ C, int M, int In, int N) {
  const int K = In * 9;
  const int ntiles = K >> 6;
  const int per = (ntiles + SPLIT - 1) / SPLIT;
  const int kt0 = blockIdx.z * per;
  const int kt1 = (kt0 + per < ntiles) ? (kt0 + per) : ntiles;
  constexpr int LDA = 72;
  __shared__ __align__(16) ushort Ah[BM * LDA];
  __shared__ __align__(16) ushort Al[BM * LDA];
  __shared__ __align__(16) ushort Bh[64 * LDA];
  __shared__ __align__(16) ushort Bl[64 * LDA];
  const int tid = threadIdx.x;
  const int lane = tid & 63, wave = tid >> 6;
  const int lrow = lane & 15, quad = lane >> 4;
  const int bm = blockIdx.y * BM, bn = blockIdx.x * 64;
  constexpr int MT = BM / 64;
  floatx4 acc[MT][4] = {};
  for (int kt = kt0; kt < kt1; ++kt) {
    int k0 = kt << 6;
    if (k0 < In) {
#pragma unroll
      for (int i = 0; i < BM / 16; ++i) {
        int c = tid + i * 256;
        int row = c >> 4, col4 = c & 15;
        int gr = bm + row;
        float4 v = make_float4(0.f, 0.f, 0.f, 0.f);
        if (gr < M) v = *(const float4*)(A + (size_t)gr * In + k0 + col4 * 4);
        float vv[4] = {silu_f(v.x), silu_f(v.y), silu_f(v.z), silu_f(v.w)};
        ushort h0 = f2bf(vv[0]), h1 = f2bf(vv[1]), h2 = f2bf(vv[2]), h3 = f2bf(vv[3]);
        ushort l0 = f2bf(vv[0] - bf2f(h0)), l1 = f2bf(vv[1] - bf2f(h1));
        ushort l2 = f2bf(vv[2] - bf2f(h2)), l3 = f2bf(vv[3] - bf2f(h3));
        *(uint2*)&Ah[row * LDA + col4 * 4] =
          make_uint2((unsigned)h0 | ((unsigned)h1 << 16), (unsigned)h2 | ((unsigned)h3 << 16));
        *(uint2*)&Al[row * LDA + col4 * 4] =
          make_uint2((unsigned)l0 | ((unsigned)l1 << 16), (unsigned)l2 | ((unsigned)l3 << 16));
      }
    } else {
      int i0 = (k0 - In) >> 3;
      if (tid < BM * 2) {
        int row = tid >> 1, half = tid & 1;
        int gr = bm + row;
        float4 v = make_float4(0.f, 0.f, 0.f, 0.f);
        if (gr < M) v = *(const float4*)(A + (size_t)gr * In + i0 + half * 4);
        float vv[4] = {v.x, v.y, v.z, v.w};
#pragma unroll
        for (int jj = 0; jj < 4; ++jj) {
          float b8[8];
          kan_bases(vv[jj], b8);
          unsigned hu[4], lu[4];
#pragma unroll
          for (int q = 0; q < 4; ++q) {
            ushort ha = f2bf(b8[2 * q]), hb = f2bf(b8[2 * q + 1]);
            ushort la = f2bf(b8[2 * q] - bf2f(ha)), lb = f2bf(b8[2 * q + 1] - bf2f(hb));
            hu[q] = (unsigned)ha | ((unsigned)hb << 16);
            lu[q] = (unsigned)la | ((unsigned)lb << 16);
          }
          int cbase = (half * 4 + jj) * 8;
          *(uint4*)&Ah[row * LDA + cbase] = make_uint4(hu[0], hu[1], hu[2], hu[3]);
          *(uint4*)&Al[row * LDA + cbase] = make_uint4(lu[0], lu[1], lu[2], lu[3]);
        }
      }
    }
#pragma unroll
    for (int i = 0; i < 2; ++i) {
      int c = tid + i * 256;
      int row = c >> 3, col8 = c & 7;
      *(uint4*)&Bh[row * LDA + col8 * 8] = *(const uint4*)(Bhg + (size_t)(bn + row) * K + k0 + col8 * 8);
      *(uint4*)&Bl[row * LDA + col8 * 8] = *(const uint4*)(Blg + (size_t)(bn + row) * K + k0 + col8 * 8);
    }
    __syncthreads();
#pragma unroll
    for (int kk = 0; kk < 64; kk += 32) {
      int kof = kk + quad * 8;
      short8 ah[MT], al[MT];
#pragma unroll
      for (int mt = 0; mt < MT; ++mt) {
        int ra = (wave * (BM / 4) + mt * 16 + lrow) * LDA + kof;
        ah[mt] = *(const short8*)&Ah[ra];
        al[mt] = *(const short8*)&Al[ra];
      }
      short8 bh[4], blo[4];
#pragma unroll
      for (int nt = 0; nt < 4; ++nt) {
        int rb = (nt * 16 + lrow) * LDA + kof;
        bh[nt]  = *(const short8*)&Bh[rb];
        blo[nt] = *(const short8*)&Bl[rb];
      }
#pragma unroll
      for (int nt = 0; nt < 4; ++nt) {
#pragma unroll
        for (int mt = 0; mt < MT; ++mt) {
          acc[mt][nt] = __builtin_amdgcn_mfma_f32_16x16x32_bf16(ah[mt], bh[nt],  acc[mt][nt], 0, 0, 0);
          acc[mt][nt] = __builtin_amdgcn_mfma_f32_16x16x32_bf16(al[mt], bh[nt],  acc[mt][nt], 0, 0, 0);
          acc[mt][nt] = __builtin_amdgcn_mfma_f32_16x16x32_bf16(ah[mt], blo[nt], acc[mt][nt], 0, 0, 0);
        }
      }
    }
    __syncthreads();
  }
#pragma unroll
  for (int mt = 0; mt < MT; ++mt) {
#pragma unroll
    for (int nt = 0; nt < 4; ++nt) {
#pragma unroll
      for (int reg = 0; reg < 4; ++reg) {
        int row = bm + wave * (BM / 4) + mt * 16 + quad * 4 + reg;
        int col = bn + nt * 16 + lrow;
        if (row < M) atomicAdd(&C[(size_t)row * N + col], acc[mt][nt][reg]);
      }
    }
  }
}

// ---------------- merged weight transpose+split ----------------
__global__ void conv_wT2(const float* __restrict__ Wl, const float* __restrict__ Wr,
                         const float* __restrict__ bl, const float* __restrict__ br,
                         ushort* __restrict__ WTh, ushort* __restrict__ WTl,
                         float* __restrict__ bout, int total) {
  int i = blockIdx.x * 256 + threadIdx.x;
  if (i >= total) return;
  int g = i / (1024 * 128), rem = i % (1024 * 128);
  int n = rem >> 7, k = rem & 127;
  int nn = n & 511;
  const float* W = (n < 512) ? Wl : Wr;
  float v = W[(size_t)g * 65536 + (size_t)k * 512 + nn];
  ushort hi = f2bf(v);
  WTh[i] = hi;
  WTl[i] = f2bf(v - bf2f(hi));
  if (k == 0) bout[g * 1024 + n] = ((n < 512) ? bl : br)[g * 512 + nn];
}

// ---------------- build expanded KAN weight, transposed + split ----------------
__global__ void build_kan_wT(const float* __restrict__ base_w, const float* __restrict__ spline_w,
                             const float* __restrict__ scaler,
                             ushort* __restrict__ BTh, ushort* __restrict__ BTl,
                             int In, int Out) {
  int i = blockIdx.x * 256 + threadIdx.x;
  if (i >= In * 9 * Out) return;
  int o = i / (In * 9), k = i % (In * 9);
  float v;
  if (k < In) v = base_w[(size_t)o * In + k];
  else {
    int q = k - In, ii = q >> 3, gq = q & 7;
    v = spline_w[((size_t)o * In + ii) * 8 + gq] * scaler[(size_t)o * In + ii];
  }
  ushort hi = f2bf(v);
  BTh[i] = hi;
  BTl[i] = f2bf(v - bf2f(hi));
}

// ---------------- input projection (fp32 h + hi/lo bf16) ----------------
__global__ __launch_bounds__(128) void input_proj(
    const float* __restrict__ x, const float* __restrict__ id_emb,
    const int* __restrict__ id_token, const float* __restrict__ inW,
    const float* __restrict__ inb, float* __restrict__ h,
    ushort* __restrict__ hh, ushort* __restrict__ hl) {
  int n = blockIdx.x, j = threadIdx.x;
  __shared__ float s[FNODE + IDDIM];
  if (j < FNODE) s[j] = x[(size_t)n * FNODE + j];
  else if (j < FNODE + IDDIM) s[j] = id_emb[(size_t)id_token[n] * IDDIM + (j - FNODE)];
  __syncthreads();
  float acc = inb[j];
#pragma unroll
  for (int k = 0; k < FNODE + IDDIM; ++k) acc = fmaf(s[k], inW[k * HID + j], acc);
  float v = silu_f(acc);
  h[(size_t)n * HID + j] = v;
  ushort hi = f2bf(v);
  hh[(size_t)n * HID + j] = hi;
  hl[(size_t)n * HID + j] = f2bf(v - bf2f(hi));
}

// ---------------- per-layer prep ----------------
__global__ __launch_bounds__(512) void layer_prep(
    const float* __restrict__ rel_gate, const float* __restrict__ gat_bias,
    const float* __restrict__ rel_emb, const float* __restrict__ We, int l,
    float* __restrict__ gates, float* __restrict__ msg_bias, float* __restrict__ erel) {
  int j = threadIdx.x;
  float g[NR]; float mx = -1e30f;
  for (int r = 0; r < NR; ++r) { g[r] = rel_gate[l * NR + r]; mx = fmaxf(mx, g[r]); }
  float s = 0.f;
  for (int r = 0; r < NR; ++r) { g[r] = expf(g[r] - mx); s += g[r]; }
  for (int r = 0; r < NR; ++r) g[r] /= s;
  if (j < NR) gates[j] = g[j];
  if (j < HID) {
    float b = 0.f;
    for (int r = 0; r < NR; ++r) b = fmaf(g[r], gat_bias[((size_t)(l * NR + r)) * HID + j], b);
    msg_bias[j] = b;
  }
  for (int r = 0; r < NR; ++r) {
    const float* Wer = We + ((size_t)(l * NR + r)) * 24 * 512;
    const float* re  = rel_emb + (l * NR + r) * RELDIM;
    float acc = 0.f;
#pragma unroll
    for (int q = 0; q < RELDIM; ++q) acc = fmaf(re[q], Wer[(FEDGE + q) * 512 + j], acc);
    erel[r * 512 + j] = acc;
  }
}

// ---------------- fills ----------------
__global__ void fill_zero(float* __restrict__ p, int n) {
  int i = blockIdx.x * 256 + threadIdx.x;
  if (i < n) p[i] = 0.f;
}
__global__ void fill_zero_i(int* __restrict__ p, int n) {
  int i = blockIdx.x * 256 + threadIdx.x;
  if (i < n) p[i] = 0;
}

// ---------------- CSR build (by target) ----------------
__global__ void csr_count(const int* __restrict__ eidx, int* __restrict__ deg) {
  int e = blockIdx.x * 256 + threadIdx.x;
  if (e < NE) atomicAdd(&deg[eidx[NE + e]], 1);
}
__global__ __launch_bounds__(256) void csr_scan(const int* __restrict__ deg,
                                                int* __restrict__ in_off, int* __restrict__ cursor) {
  __shared__ int ps[256];
  int t = threadIdx.x;
  const int CH = (NN + 255) / 256;  // 40
  int base = t * CH;
  int sum = 0;
  for (int i = 0; i < CH; ++i) { int idx = base + i; if (idx < NN) sum += deg[idx]; }
  ps[t] = sum;
  __syncthreads();
  for (int o = 1; o < 256; o <<= 1) {
    int v = (t >= o) ? ps[t - o] : 0;
    __syncthreads();
    ps[t] += v;
    __syncthreads();
  }
  int run = (t == 0) ? 0 : ps[t - 1];
  for (int i = 0; i < CH; ++i) {
    int idx = base + i;
    if (idx < NN) { in_off[idx] = run; cursor[idx] = run; run += deg[idx]; }
  }
  if (t == 255) in_off[NN] = run;
}
__global__ void csr_scatter(const int* __restrict__ eidx, int* __restrict__ cursor,
                            int* __restrict__ in_edges) {
  int e = blockIdx.x * 256 + threadIdx.x;
  if (e < NE) {
    int pos = atomicAdd(&cursor[eidx[NE + e]], 1);
    in_edges[pos] = e;
  }
}

// ---------------- node-centric GAT pass: score+softmax+aggregate, one wave per node ----
// xlr [NN,1024]: xl = [0,512), xr = [512,1024). hmsg = beta*hmsg + gates[r]*0.25*agg.
__global__ __launch_bounds__(256) void gat_node(
    const int* __restrict__ in_off, const int* __restrict__ in_edges,
    const int* __restrict__ etype, const int* __restrict__ eidx,
    const float* __restrict__ eattr, const float* __restrict__ xlr,
    const float* __restrict__ We_r, const float* __restrict__ erel_r,
    const float* __restrict__ att_r, const float* __restrict__ gates,
    int r, float beta, float* __restrict__ hmsg) {
  __shared__ float WeL[16][512];
  __shared__ float attL[512];
  __shared__ float erelL[512];
  int tid = threadIdx.x;
  for (int i = tid; i < 16 * 512; i += 256) WeL[i >> 9][i & 511] = We_r[i];
  for (int i = tid; i < 512; i += 256) { attL[i] = att_r[i]; erelL[i] = erel_r[i]; }
  __syncthreads();
  float gr = gates[r] * 0.25f;
  int lane = tid & 63, wave = tid >> 6;
  int n = blockIdx.x * 4 + wave;
  if (n >= NN) return;
  float xr[8];
  const float* xrb = xlr + (size_t)n * 1024 + 512;
#pragma unroll
  for (int h = 0; h < 4; ++h) {
    xr[h * 2]     = xrb[h * 128 + lane];
    xr[h * 2 + 1] = xrb[h * 128 + 64 + lane];
  }
  float m[4] = {-1e30f, -1e30f, -1e30f, -1e30f};
  float lsum[4] = {0.f, 0.f, 0.f, 0.f};
  float acc[8] = {0.f, 0.f, 0.f, 0.f, 0.f, 0.f, 0.f, 0.f};
  int e0 = in_off[n], e1 = in_off[n + 1];
  for (int ii = e0; ii < e1; ++ii) {
    int e = in_edges[ii];
    if (etype[e] != r) continue;
    int s = eidx[e];
    const float* xls = xlr + (size_t)s * 1024;
    float ea[16];
#pragma unroll
    for (int k = 0; k < 16; ++k) ea[k] = eattr[(size_t)e * 16 + k];
    float xlv[8], p[4];
#pragma unroll
    for (int h = 0; h < 4; ++h) {
      float ph = 0.f;
#pragma unroll
      for (int half = 0; half < 2; ++half) {
        int idx = h * 128 + half * 64 + lane;
        float xv = xls[idx];
        xlv[h * 2 + half] = xv;
        float et = erelL[idx];
#pragma unroll
        for (int k = 0; k < 16; ++k) et = fmaf(ea[k], WeL[k][idx], et);
        float z = xv + xr[h * 2 + half] + et;
        z = (z > 0.f) ? z : 0.2f * z;  // leaky_relu 0.2
        ph = fmaf(z, attL[idx], ph);
      }
      p[h] = ph;
    }
#pragma unroll
    for (int h = 0; h < 4; ++h) {
#pragma unroll
      for (int o = 32; o > 0; o >>= 1) p[h] += __shfl_xor(p[h], o, 64);
    }
#pragma unroll
    for (int h = 0; h < 4; ++h) {
      float sh = p[h];
      float mn = fmaxf(m[h], sh);
      float sc = expf(m[h] - mn);
      float we = expf(sh - mn);
      m[h] = mn;
      lsum[h] = lsum[h] * sc + we;
      acc[h * 2]     = acc[h * 2] * sc + we * xlv[h * 2];
      acc[h * 2 + 1] = acc[h * 2 + 1] * sc + we * xlv[h * 2 + 1];
    }
  }
  float o0 = 0.f, o1 = 0.f;
#pragma unroll
  for (int h = 0; h < 4; ++h) {
    float inv = 1.f / fmaxf(lsum[h], 1e-16f);
    o0 += acc[h * 2] * inv;
    o1 += acc[h * 2 + 1] * inv;
  }
  size_t base = (size_t)n * HID;
  float old0 = 0.f, old1 = 0.f;
  if (beta != 0.f) { old0 = hmsg[base + lane]; old1 = hmsg[base + 64 + lane]; }
  hmsg[base + lane]      = old0 + gr * o0;
  hmsg[base + 64 + lane] = old1 + gr * o1;
}

// ---------------- LayerNorm over 128 dims (optionally emits hi/lo bf16) ----------------
__global__ __launch_bounds__(64) void ln128(
    float* __restrict__ h, const float* __restrict__ add, const float* __restrict__ bvec,
    const float* __restrict__ g, const float* __restrict__ b,
    ushort* __restrict__ hh, ushort* __restrict__ hl) {
  int n = blockIdx.x, lane = threadIdx.x;
  size_t base = (size_t)n * HID;
  float x0 = h[base + lane] + add[base + lane];
  float x1 = h[base + 64 + lane] + add[base + 64 + lane];
  if (bvec) { x0 += bvec[lane]; x1 += bvec[64 + lane]; }
  float s = x0 + x1;
#pragma unroll
  for (int m = 32; m > 0; m >>= 1) s += __shfl_xor(s, m, 64);
  float mu = s * (1.f / 128.f);
  float d0 = x0 - mu, d1 = x1 - mu;
  float q = d0 * d0 + d1 * d1;
#pragma unroll
  for (int m = 32; m > 0; m >>= 1) q += __shfl_xor(q, m, 64);
  float inv = 1.f / sqrtf(q * (1.f / 128.f) + 1e-5f);
  float o0 = d0 * inv * g[lane] + b[lane];
  float o1 = d1 * inv * g[64 + lane] + b[64 + lane];
  h[base + lane]      = o0;
  h[base + 64 + lane] = o1;
  if (hh) {
    ushort i0 = f2bf(o0), i1 = f2bf(o1);
    hh[base + lane] = i0;        hh[base + 64 + lane] = i1;
    hl[base + lane] = f2bf(o0 - bf2f(i0));
    hl[base + 64 + lane] = f2bf(o1 - bf2f(i1));
  }
}

// ---------------- KAN expansion (fp32) — tiny readout head only ----------------
__global__ void expand_f32(const float* __restrict__ v, float* __restrict__ u, int In, int rows) {
  int i = blockIdx.x * 256 + threadIdx.x;
  if (i >= rows * In) return;
  int n = i / In, c = i % In;
  float x = v[(size_t)n * In + c];
  size_t base = (size_t)n * In * 9;
  u[base + c] = silu_f(x);
  float b8[8];
  kan_bases(x, b8);
  float* ub = u + base + In + (size_t)c * 8;
#pragma unroll
  for (int gq = 0; gq < 8; ++gq) ub[gq] = b8[gq];
}

// ---------------- readout ----------------
__global__ void pool_init(float* __restrict__ mean, unsigned* __restrict__ maxenc, float* __restrict__ cnt) {
  int i = blockIdx.x * 256 + threadIdx.x;
  if (i < NG * HID) { mean[i] = 0.f; maxenc[i] = ENC_NEG_INF; }
  if (i < NG) cnt[i] = 0.f;
}
__global__ __launch_bounds__(128) void pool_accum(
    const float* __restrict__ h, const int* __restrict__ batch,
    float* __restrict__ mean, unsigned* __restrict__ maxenc, float* __restrict__ cnt) {
  int n = blockIdx.x, d = threadIdx.x;
  int g = batch[n];
  float v = h[(size_t)n * HID + d];
  atomicAdd(&mean[g * HID + d], v);
  atomicMax(&maxenc[g * HID + d], fenc(v));
  if (d == 0) atomicAdd(&cnt[g], 1.f);
}
__global__ __launch_bounds__(256) void pool_final_ln(
    const float* __restrict__ mean, const unsigned* __restrict__ maxenc,
    const float* __restrict__ cnt, const float* __restrict__ rog,
    const float* __restrict__ rob, float* __restrict__ gvec) {
  int g = blockIdx.x, j = threadIdx.x;
  __shared__ float rb[256];
  float x;
  if (j < HID) x = mean[g * HID + j] / fmaxf(cnt[g], 1.f);
  else {
    float mv = fdec(maxenc[g * HID + (j - HID)]);
    x = (mv > -1e38f) ? mv : 0.f;
  }
  rb[j] = x; __syncthreads();
  for (int st = 128; st > 0; st >>= 1) { if (j < st) rb[j] += rb[j + st]; __syncthreads(); }
  float mu = rb[0] * (1.f / 256.f); __syncthreads();
  float d = x - mu;
  rb[j] = d * d; __syncthreads();
  for (int st = 128; st > 0; st >>= 1) { if (j < st) rb[j] += rb[j + st]; __syncthreads(); }
  float var = rb[0] * (1.f / 256.f);
  float inv = 1.f / sqrtf(var + 1e-5f);
  gvec[(size_t)g * 256 + j] = d * inv * rog[j] + rob[j];
}

// ---------------- small KAN head (fp32, raw weights) ----------------
__global__ void kan_head(const float* __restrict__ u, const float* __restrict__ base_w,
                         const float* __restrict__ spline_w, const float* __restrict__ scaler,
                         float* __restrict__ out, int In, int Out) {
  int o = blockIdx.x * 64 + threadIdx.x;
  int g = blockIdx.y;
  if (o >= Out) return;
  const float* ug = u + (size_t)g * In * 9;
  float acc = 0.f;
  for (int i = 0; i < In; ++i) acc = fmaf(ug[i], base_w[(size_t)o * In + i], acc);
  for (int i = 0; i < In; ++i) {
    const float* sp = spline_w + ((size_t)o * In + i) * 8;
    const float* ub = ug + In + (size_t)i * 8;
    float a2 = 0.f;
#pragma unroll
    for (int gq = 0; gq < 8; ++gq) a2 = fmaf(ub[gq], sp[gq], a2);
    acc = fmaf(scaler[(size_t)o * In + i], a2, acc);
  }
  out[(size_t)g * Out + o] = acc;
}

// ---------------- launch ----------------
extern "C" void kernel_launch(void* const* d_in, const int* in_sizes, int n_in,
                              void* d_out, int out_size, void* d_ws, size_t ws_size,
                              hipStream_t stream) {
  const float* x         = (const float*)d_in[0];
  const float* edge_attr = (const float*)d_in[1];
  const int*   id_token  = (const int*)  d_in[2];
  const int*   edge_index= (const int*)  d_in[3];
  const int*   edge_type = (const int*)  d_in[4];
  const int*   batch     = (const int*)  d_in[5];
  const float* id_emb    = (const float*)d_in[6];
  const float* inW       = (const float*)d_in[7];
  const float* inb       = (const float*)d_in[8];
  const float* Wl        = (const float*)d_in[9];
  const float* bl        = (const float*)d_in[10];
  const float* Wr        = (const float*)d_in[11];
  const float* br        = (const float*)d_in[12];
  const float* We        = (const float*)d_in[13];
  const float* att       = (const float*)d_in[14];
  const float* gat_bias  = (const float*)d_in[15];
  const float* rel_gate  = (const float*)d_in[16];
  const float* rel_emb   = (const float*)d_in[17];
  const float* ln1g      = (const float*)d_in[18];
  const float* ln1b      = (const float*)d_in[19];
  const float* ln2g      = (const float*)d_in[20];
  const float* ln2b      = (const float*)d_in[21];
  const float* ffn1_base = (const float*)d_in[22];
  const float* ffn1_spl  = (const float*)d_in[23];
  const float* ffn1_sc   = (const float*)d_in[24];
  const float* ffn2_base = (const float*)d_in[25];
  const float* ffn2_spl  = (const float*)d_in[26];
  const float* ffn2_sc   = (const float*)d_in[27];
  const float* rog       = (const float*)d_in[28];
  const float* rob       = (const float*)d_in[29];
  const float* h1_base   = (const float*)d_in[30];
  const float* h1_spl    = (const float*)d_in[31];
  const float* h1_sc     = (const float*)d_in[32];
  const float* h2_base   = (const float*)d_in[33];
  const float* h2_spl    = (const float*)d_in[34];
  const float* h2_sc     = (const float*)d_in[35];
  (void)in_sizes; (void)n_in; (void)out_size; (void)ws_size;

  // ---- workspace carve (256B aligned) ----
  char* wsp = (char*)d_ws;
  size_t off = 0;
  auto carve = [&](size_t bytes) { char* p = wsp + off; off = (off + bytes + 255) & ~(size_t)255; return p; };
  float*    h     = (float*)   carve((size_t)NN * HID * 4);
  ushort*   h_hi  = (ushort*)  carve((size_t)NN * HID * 2);
  ushort*   h_lo  = (ushort*)  carve((size_t)NN * HID * 2);
  float*    hmsg  = (float*)   carve((size_t)NN * HID * 4);
  float*    t1    = (float*)   carve((size_t)NN * FFNH * 4);
  float*    gates = (float*)   carve(NR * 4);
  float*    msgb  = (float*)   carve(HID * 4);
  float*    erel  = (float*)   carve(NR * 512 * 4);
  ushort*   WTh   = (ushort*)  carve((size_t)NL * NR * 1024 * HID * 2);
  ushort*   WTl   = (ushort*)  carve((size_t)NL * NR * 1024 * HID * 2);
  float*    blr   = (float*)   carve((size_t)NL * NR * 1024 * 4);
  ushort*   B1h   = (ushort*)  carve((size_t)FFNH * HID * 9 * 2);
  ushort*   B1l   = (ushort*)  carve((size_t)FFNH * HID * 9 * 2);
  ushort*   B2h   = (ushort*)  carve((size_t)HID * FFNH * 9 * 2);
  ushort*   B2l   = (ushort*)  carve((size_t)HID * FFNH * 9 * 2);
  float*    pm    = (float*)   carve((size_t)NG * HID * 4);
  unsigned* pmax  = (unsigned*)carve((size_t)NG * HID * 4);
  float*    cnt   = (float*)   carve(NG * 4);
  float*    gvec  = (float*)   carve((size_t)NG * 256 * 4);
  float*    uhead = (float*)   carve((size_t)NG * 256 * 9 * 4);
  float*    thead = (float*)   carve((size_t)NG * HEADH * 4);
  float*    xlr   = (float*)   carve((size_t)NN * 1024 * 4);
  int*      deg   = (int*)     carve((size_t)NN * 4);
  int*      in_off= (int*)     carve((size_t)(NN + 1) * 4);
  int*      cursor= (int*)     carve((size_t)NN * 4);
  int*      in_edges=(int*)    carve((size_t)NE * 4);

  // ---- CSR build (by target) ----
  fill_zero_i<<<(NN + 255) / 256, 256, 0, stream>>>(deg, NN);
  csr_count<<<(NE + 255) / 256, 256, 0, stream>>>(edge_index, deg);
  csr_scan<<<1, 256, 0, stream>>>(deg, in_off, cursor);
  csr_scatter<<<(NE + 255) / 256, 256, 0, stream>>>(edge_index, cursor, in_edges);

  // ---- weight transpose + split (once per launch) ----
  {
    int total = NL * NR * 1024 * 128;
    conv_wT2<<<(total + 255) / 256, 256, 0, stream>>>(Wl, Wr, bl, br, WTh, WTl, blr, total);
  }

  // ---- input projection ----
  input_proj<<<NN, 128, 0, stream>>>(x, id_emb, id_token, inW, inb, h, h_hi, h_lo);

  const int MB128 = (NN + 127) / 128;  // 79
  const int MB64  = (NN + 63) / 64;    // 157
  for (int l = 0; l < NL; ++l) {
    layer_prep<<<1, 512, 0, stream>>>(rel_gate, gat_bias, rel_emb, We, l, gates, msgb, erel);
    for (int r = 0; r < NR; ++r) {
      const ushort* WThr = WTh + ((size_t)(l * NR + r)) * 1024 * HID;
      const ushort* WTlr = WTl + ((size_t)(l * NR + r)) * 1024 * HID;
      const float* blrr  = blr + (size_t)(l * NR + r) * 1024;
      const float* Wer   = We + ((size_t)(l * NR + r)) * 24 * 512;
      const float* attr  = att + (size_t)(l * NR + r) * 512;
      gemm_bf3<<<dim3(1024 / 64, MB128), 256, 0, stream>>>(h_hi, h_lo, WThr, WTlr, blrr, xlr, NN, HID, 1024);
      gat_node<<<(NN + 3) / 4, 256, 0, stream>>>(in_off, in_edges, edge_type, edge_index,
                                                 edge_attr, xlr, Wer, erel + r * 512, attr,
                                                 gates, r, (r == 0) ? 0.f : 1.f, hmsg);
    }
    ln128<<<NN, 64, 0, stream>>>(h, hmsg, msgb, ln1g + l * HID, ln1b + l * HID, nullptr, nullptr);

    // ---- KAN FFN1: 128 -> 256 (K = 1152), fused expansion, split-K 3 ----
    build_kan_wT<<<((HID * 9 * FFNH) + 255) / 256, 256, 0, stream>>>(
        ffn1_base + (size_t)l * FFNH * HID, ffn1_spl + (size_t)l * FFNH * HID * 8,
        ffn1_sc + (size_t)l * FFNH * HID, B1h, B1l, HID, FFNH);
    fill_zero<<<(NN * FFNH + 255) / 256, 256, 0, stream>>>(t1, NN * FFNH);
    gemm_kan<128, 3><<<dim3(FFNH / 64, MB128, 3), 256, 0, stream>>>(h, B1h, B1l, t1, NN, HID, FFNH);
    // ---- KAN FFN2: 256 -> 128 (K = 2304), fused expansion, split-K 4 ----
    build_kan_wT<<<((FFNH * 9 * HID) + 255) / 256, 256, 0, stream>>>(
        ffn2_base + (size_t)l * HID * FFNH, ffn2_spl + (size_t)l * HID * FFNH * 8,
        ffn2_sc + (size_t)l * HID * FFNH, B2h, B2l, FFNH, HID);
    fill_zero<<<(NN * HID + 255) / 256, 256, 0, stream>>>(hmsg, NN * HID);
    gemm_kan<64, 4><<<dim3(HID / 64, MB64, 4), 256, 0, stream>>>(t1, B2h, B2l, hmsg, NN, FFNH, HID);
    ln128<<<NN, 64, 0, stream>>>(h, hmsg, nullptr, ln2g + l * HID, ln2b + l * HID, h_hi, h_lo);
  }

  // ---- readout ----
  pool_init<<<(NG * HID + 255) / 256, 256, 0, stream>>>(pm, pmax, cnt);
  pool_accum<<<NN, 128, 0, stream>>>(h, batch, pm, pmax, cnt);
  pool_final_ln<<<NG, 256, 0, stream>>>(pm, pmax, cnt, rog, rob, gvec);
  expand_f32<<<((NG * 256) + 255) / 256, 256, 0, stream>>>(gvec, uhead, 256, NG);
  kan_head<<<dim3(2, NG), 64, 0, stream>>>(uhead, h1_base, h1_spl, h1_sc, thead, 256, HEADH);
  expand_f32<<<((NG * HEADH) + 255) / 256, 256, 0, stream>>>(thead, uhead, HEADH, NG);
  kan_head<<<dim3(1, NG), 64, 0, stream>>>(uhead, h2_base, h2_spl, h2_sc, (float*)d_out, HEADH, NCLS);
}

// Round 7
// 2076.354 us; speedup vs baseline: 1.7408x; 1.0813x over previous
//
#include <hip/hip_runtime.h>
#include <cstdint>
#include <cstddef>

// ---------------- static problem config ----------------
#define NN      10000   // nodes
#define NE      120000  // edges
#define NG      32      // graphs
#define FNODE   64
#define FEDGE   16
#define HID     128
#define NHEADS  4
#define NL      3
#define NR      4
#define IDDIM   32
#define RELDIM  8
#define FFNH    256
#define HEADH   128
#define NCLS    10

typedef __attribute__((ext_vector_type(8))) short short8;
typedef __attribute__((ext_vector_type(4))) float floatx4;

// ---------------- helpers ----------------
__device__ __forceinline__ unsigned fenc(float f) {
  unsigned u = __float_as_uint(f);
  return (u & 0x80000000u) ? ~u : (u | 0x80000000u);
}
__device__ __forceinline__ float fdec(unsigned k) {
  return __uint_as_float((k & 0x80000000u) ? (k ^ 0x80000000u) : ~k);
}
__device__ __forceinline__ float silu_f(float x) { return x / (1.f + expf(-x)); }
__device__ __forceinline__ ushort f2bf(float f) {   // round-to-nearest-even bf16
  unsigned u = __float_as_uint(f);
  return (ushort)((u + 0x7FFFu + ((u >> 16) & 1u)) >> 16);
}
__device__ __forceinline__ float bf2f(ushort h) { return __uint_as_float((unsigned)h << 16); }

#define ENC_NEG_INF 0x007FFFFFu

// Cox–de Boor cubic bases on grid t_j = (j-3)*0.4 - 1 (GRID_SIZE=5, ORDER=3) -> 8 bases
__device__ __forceinline__ void kan_bases(float x, float* out8) {
  float bb[11];
#pragma unroll
  for (int j = 0; j < 11; ++j) {
    float t0 = (j - 3) * 0.4f - 1.f;
    float t1 = (j - 2) * 0.4f - 1.f;
    bb[j] = (x >= t0 && x < t1) ? 1.f : 0.f;
  }
  {
    const float inv = 1.f / 0.4f;
#pragma unroll
    for (int j = 0; j < 10; ++j) {
      float tj = (j - 3) * 0.4f - 1.f, tjp1 = (j - 1) * 0.4f - 1.f;
      bb[j] = ((x - tj) * bb[j] + (tjp1 - x) * bb[j + 1]) * inv;
    }
  }
  {
    const float inv = 1.f / 0.8f;
#pragma unroll
    for (int j = 0; j < 9; ++j) {
      float tj = (j - 3) * 0.4f - 1.f, tjp1 = (j) * 0.4f - 1.f;
      bb[j] = ((x - tj) * bb[j] + (tjp1 - x) * bb[j + 1]) * inv;
    }
  }
  {
    const float inv = 1.f / 1.2000001f;
#pragma unroll
    for (int j = 0; j < 8; ++j) {
      float tj = (j - 3) * 0.4f - 1.f, tjp1 = (j + 1) * 0.4f - 1.f;
      bb[j] = ((x - tj) * bb[j] + (tjp1 - x) * bb[j + 1]) * inv;
    }
  }
#pragma unroll
  for (int j = 0; j < 8; ++j) out8[j] = bb[j];
}

// ---------------- 3-term MFMA GEMM, operands pre-split bf16 hi/lo ----------------
// LDA=68: +4 pad breaks pow2 stride (<=2-way conflicts, free); LDS 52.2KB -> 3 blocks/CU.
__global__ __launch_bounds__(256) void gemm_bf3(
    const ushort* __restrict__ Ahg, const ushort* __restrict__ Alg,
    const ushort* __restrict__ Bhg, const ushort* __restrict__ Blg,
    const float* __restrict__ bias, float* __restrict__ C,
    int M, int K, int N) {
  constexpr int LDA = 68;
  __shared__ __align__(16) ushort Ah[128 * LDA];
  __shared__ __align__(16) ushort Al[128 * LDA];
  __shared__ __align__(16) ushort Bh[64 * LDA];
  __shared__ __align__(16) ushort Bl[64 * LDA];
  const int tid = threadIdx.x;
  const int lane = tid & 63, wave = tid >> 6;
  const int lrow = lane & 15, quad = lane >> 4;
  const int bm = blockIdx.y * 128, bn = blockIdx.x * 64;
  floatx4 acc[2][4] = {};
  for (int k0 = 0; k0 < K; k0 += 64) {
#pragma unroll
    for (int i = 0; i < 4; ++i) {
      int c = tid + i * 256;
      int row = c >> 3, col8 = c & 7;
      int gr = bm + row;
      uint4 vh = make_uint4(0, 0, 0, 0), vl = make_uint4(0, 0, 0, 0);
      if (gr < M) {
        vh = *(const uint4*)(Ahg + (size_t)gr * K + k0 + col8 * 8);
        vl = *(const uint4*)(Alg + (size_t)gr * K + k0 + col8 * 8);
      }
      *(uint4*)&Ah[row * LDA + col8 * 8] = vh;
      *(uint4*)&Al[row * LDA + col8 * 8] = vl;
    }
#pragma unroll
    for (int i = 0; i < 2; ++i) {
      int c = tid + i * 256;
      int row = c >> 3, col8 = c & 7;
      *(uint4*)&Bh[row * LDA + col8 * 8] = *(const uint4*)(Bhg + (size_t)(bn + row) * K + k0 + col8 * 8);
      *(uint4*)&Bl[row * LDA + col8 * 8] = *(const uint4*)(Blg + (size_t)(bn + row) * K + k0 + col8 * 8);
    }
    __syncthreads();
#pragma unroll
    for (int kk = 0; kk < 64; kk += 32) {
      int kof = kk + quad * 8;
      const int ra0 = (wave * 32 + lrow) * LDA + kof;
      const int ra1 = (wave * 32 + 16 + lrow) * LDA + kof;
      short8 ah0 = *(const short8*)&Ah[ra0];
      short8 ah1 = *(const short8*)&Ah[ra1];
      short8 al0 = *(const short8*)&Al[ra0];
      short8 al1 = *(const short8*)&Al[ra1];
      short8 bh[4], blo[4];
#pragma unroll
      for (int nt = 0; nt < 4; ++nt) {
        int rb = (nt * 16 + lrow) * LDA + kof;
        bh[nt]  = *(const short8*)&Bh[rb];
        blo[nt] = *(const short8*)&Bl[rb];
      }
#pragma unroll
      for (int nt = 0; nt < 4; ++nt) {
        acc[0][nt] = __builtin_amdgcn_mfma_f32_16x16x32_bf16(ah0, bh[nt],  acc[0][nt], 0, 0, 0);
        acc[1][nt] = __builtin_amdgcn_mfma_f32_16x16x32_bf16(ah1, bh[nt],  acc[1][nt], 0, 0, 0);
        acc[0][nt] = __builtin_amdgcn_mfma_f32_16x16x32_bf16(al0, bh[nt],  acc[0][nt], 0, 0, 0);
        acc[1][nt] = __builtin_amdgcn_mfma_f32_16x16x32_bf16(al1, bh[nt],  acc[1][nt], 0, 0, 0);
        acc[0][nt] = __builtin_amdgcn_mfma_f32_16x16x32_bf16(ah0, blo[nt], acc[0][nt], 0, 0, 0);
        acc[1][nt] = __builtin_amdgcn_mfma_f32_16x16x32_bf16(ah1, blo[nt], acc[1][nt], 0, 0, 0);
      }
    }
    __syncthreads();
  }
#pragma unroll
  for (int mt = 0; mt < 2; ++mt) {
#pragma unroll
    for (int nt = 0; nt < 4; ++nt) {
#pragma unroll
      for (int reg = 0; reg < 4; ++reg) {
        int row = bm + wave * 32 + mt * 16 + quad * 4 + reg;
        int col = bn + nt * 16 + lrow;
        if (row < M) {
          float v = acc[mt][nt][reg];
          if (bias) v += bias[col];
          C[(size_t)row * N + col] = v;
        }
      }
    }
  }
}

// ---------------- fused KAN GEMM w/ split-K: C += expand(A) @ BT^T ----------------
template<int BM, int SPLIT>
__global__ __launch_bounds__(256) void gemm_kan(
    const float* __restrict__ A, const ushort* __restrict__ Bhg, const ushort* __restrict__ Blg,
    float* __restrict__ C, int M, int In, int N) {
  const int K = In * 9;
  const int ntiles = K >> 6;
  const int per = (ntiles + SPLIT - 1) / SPLIT;
  const int kt0 = blockIdx.z * per;
  const int kt1 = (kt0 + per < ntiles) ? (kt0 + per) : ntiles;
  constexpr int LDA = 68;
  __shared__ __align__(16) ushort Ah[BM * LDA];
  __shared__ __align__(16) ushort Al[BM * LDA];
  __shared__ __align__(16) ushort Bh[64 * LDA];
  __shared__ __align__(16) ushort Bl[64 * LDA];
  const int tid = threadIdx.x;
  const int lane = tid & 63, wave = tid >> 6;
  const int lrow = lane & 15, quad = lane >> 4;
  const int bm = blockIdx.y * BM, bn = blockIdx.x * 64;
  constexpr int MT = BM / 64;
  floatx4 acc[MT][4] = {};
  for (int kt = kt0; kt < kt1; ++kt) {
    int k0 = kt << 6;
    if (k0 < In) {
#pragma unroll
      for (int i = 0; i < BM / 16; ++i) {
        int c = tid + i * 256;
        int row = c >> 4, col4 = c & 15;
        int gr = bm + row;
        float4 v = make_float4(0.f, 0.f, 0.f, 0.f);
        if (gr < M) v = *(const float4*)(A + (size_t)gr * In + k0 + col4 * 4);
        float vv[4] = {silu_f(v.x), silu_f(v.y), silu_f(v.z), silu_f(v.w)};
        ushort h0 = f2bf(vv[0]), h1 = f2bf(vv[1]), h2 = f2bf(vv[2]), h3 = f2bf(vv[3]);
        ushort l0 = f2bf(vv[0] - bf2f(h0)), l1 = f2bf(vv[1] - bf2f(h1));
        ushort l2 = f2bf(vv[2] - bf2f(h2)), l3 = f2bf(vv[3] - bf2f(h3));
        *(uint2*)&Ah[row * LDA + col4 * 4] =
          make_uint2((unsigned)h0 | ((unsigned)h1 << 16), (unsigned)h2 | ((unsigned)h3 << 16));
        *(uint2*)&Al[row * LDA + col4 * 4] =
          make_uint2((unsigned)l0 | ((unsigned)l1 << 16), (unsigned)l2 | ((unsigned)l3 << 16));
      }
    } else {
      int i0 = (k0 - In) >> 3;
      if (tid < BM * 2) {
        int row = tid >> 1, half = tid & 1;
        int gr = bm + row;
        float4 v = make_float4(0.f, 0.f, 0.f, 0.f);
        if (gr < M) v = *(const float4*)(A + (size_t)gr * In + i0 + half * 4);
        float vv[4] = {v.x, v.y, v.z, v.w};
#pragma unroll
        for (int jj = 0; jj < 4; ++jj) {
          float b8[8];
          kan_bases(vv[jj], b8);
          unsigned hu[4], lu[4];
#pragma unroll
          for (int q = 0; q < 4; ++q) {
            ushort ha = f2bf(b8[2 * q]), hb = f2bf(b8[2 * q + 1]);
            ushort la = f2bf(b8[2 * q] - bf2f(ha)), lb = f2bf(b8[2 * q + 1] - bf2f(hb));
            hu[q] = (unsigned)ha | ((unsigned)hb << 16);
            lu[q] = (unsigned)la | ((unsigned)lb << 16);
          }
          int cbase = (half * 4 + jj) * 8;
          *(uint4*)&Ah[row * LDA + cbase] = make_uint4(hu[0], hu[1], hu[2], hu[3]);
          *(uint4*)&Al[row * LDA + cbase] = make_uint4(lu[0], lu[1], lu[2], lu[3]);
        }
      }
    }
#pragma unroll
    for (int i = 0; i < 2; ++i) {
      int c = tid + i * 256;
      int row = c >> 3, col8 = c & 7;
      *(uint4*)&Bh[row * LDA + col8 * 8] = *(const uint4*)(Bhg + (size_t)(bn + row) * K + k0 + col8 * 8);
      *(uint4*)&Bl[row * LDA + col8 * 8] = *(const uint4*)(Blg + (size_t)(bn + row) * K + k0 + col8 * 8);
    }
    __syncthreads();
#pragma unroll
    for (int kk = 0; kk < 64; kk += 32) {
      int kof = kk + quad * 8;
      short8 ah[MT], al[MT];
#pragma unroll
      for (int mt = 0; mt < MT; ++mt) {
        int ra = (wave * (BM / 4) + mt * 16 + lrow) * LDA + kof;
        ah[mt] = *(const short8*)&Ah[ra];
        al[mt] = *(const short8*)&Al[ra];
      }
      short8 bh[4], blo[4];
#pragma unroll
      for (int nt = 0; nt < 4; ++nt) {
        int rb = (nt * 16 + lrow) * LDA + kof;
        bh[nt]  = *(const short8*)&Bh[rb];
        blo[nt] = *(const short8*)&Bl[rb];
      }
#pragma unroll
      for (int nt = 0; nt < 4; ++nt) {
#pragma unroll
        for (int mt = 0; mt < MT; ++mt) {
          acc[mt][nt] = __builtin_amdgcn_mfma_f32_16x16x32_bf16(ah[mt], bh[nt],  acc[mt][nt], 0, 0, 0);
          acc[mt][nt] = __builtin_amdgcn_mfma_f32_16x16x32_bf16(al[mt], bh[nt],  acc[mt][nt], 0, 0, 0);
          acc[mt][nt] = __builtin_amdgcn_mfma_f32_16x16x32_bf16(ah[mt], blo[nt], acc[mt][nt], 0, 0, 0);
        }
      }
    }
    __syncthreads();
  }
#pragma unroll
  for (int mt = 0; mt < MT; ++mt) {
#pragma unroll
    for (int nt = 0; nt < 4; ++nt) {
#pragma unroll
      for (int reg = 0; reg < 4; ++reg) {
        int row = bm + wave * (BM / 4) + mt * 16 + quad * 4 + reg;
        int col = bn + nt * 16 + lrow;
        if (row < M) atomicAdd(&C[(size_t)row * N + col], acc[mt][nt][reg]);
      }
    }
  }
}

// ---------------- merged weight transpose+split ----------------
__global__ void conv_wT2(const float* __restrict__ Wl, const float* __restrict__ Wr,
                         const float* __restrict__ bl, const float* __restrict__ br,
                         ushort* __restrict__ WTh, ushort* __restrict__ WTl,
                         float* __restrict__ bout, int total) {
  int i = blockIdx.x * 256 + threadIdx.x;
  if (i >= total) return;
  int g = i / (1024 * 128), rem = i % (1024 * 128);
  int n = rem >> 7, k = rem & 127;
  int nn = n & 511;
  const float* W = (n < 512) ? Wl : Wr;
  float v = W[(size_t)g * 65536 + (size_t)k * 512 + nn];
  ushort hi = f2bf(v);
  WTh[i] = hi;
  WTl[i] = f2bf(v - bf2f(hi));
  if (k == 0) bout[g * 1024 + n] = ((n < 512) ? bl : br)[g * 512 + nn];
}

// ---------------- build expanded KAN weight, transposed + split ----------------
__global__ void build_kan_wT(const float* __restrict__ base_w, const float* __restrict__ spline_w,
                             const float* __restrict__ scaler,
                             ushort* __restrict__ BTh, ushort* __restrict__ BTl,
                             int In, int Out) {
  int i = blockIdx.x * 256 + threadIdx.x;
  if (i >= In * 9 * Out) return;
  int o = i / (In * 9), k = i % (In * 9);
  float v;
  if (k < In) v = base_w[(size_t)o * In + k];
  else {
    int q = k - In, ii = q >> 3, gq = q & 7;
    v = spline_w[((size_t)o * In + ii) * 8 + gq] * scaler[(size_t)o * In + ii];
  }
  ushort hi = f2bf(v);
  BTh[i] = hi;
  BTl[i] = f2bf(v - bf2f(hi));
}

// ---------------- input projection (fp32 h + hi/lo bf16) ----------------
__global__ __launch_bounds__(128) void input_proj(
    const float* __restrict__ x, const float* __restrict__ id_emb,
    const int* __restrict__ id_token, const float* __restrict__ inW,
    const float* __restrict__ inb, float* __restrict__ h,
    ushort* __restrict__ hh, ushort* __restrict__ hl) {
  int n = blockIdx.x, j = threadIdx.x;
  __shared__ float s[FNODE + IDDIM];
  if (j < FNODE) s[j] = x[(size_t)n * FNODE + j];
  else if (j < FNODE + IDDIM) s[j] = id_emb[(size_t)id_token[n] * IDDIM + (j - FNODE)];
  __syncthreads();
  float acc = inb[j];
#pragma unroll
  for (int k = 0; k < FNODE + IDDIM; ++k) acc = fmaf(s[k], inW[k * HID + j], acc);
  float v = silu_f(acc);
  h[(size_t)n * HID + j] = v;
  ushort hi = f2bf(v);
  hh[(size_t)n * HID + j] = hi;
  hl[(size_t)n * HID + j] = f2bf(v - bf2f(hi));
}

// ---------------- per-layer prep ----------------
__global__ __launch_bounds__(512) void layer_prep(
    const float* __restrict__ rel_gate, const float* __restrict__ gat_bias,
    const float* __restrict__ rel_emb, const float* __restrict__ We, int l,
    float* __restrict__ gates, float* __restrict__ msg_bias, float* __restrict__ erel) {
  int j = threadIdx.x;
  float g[NR]; float mx = -1e30f;
  for (int r = 0; r < NR; ++r) { g[r] = rel_gate[l * NR + r]; mx = fmaxf(mx, g[r]); }
  float s = 0.f;
  for (int r = 0; r < NR; ++r) { g[r] = expf(g[r] - mx); s += g[r]; }
  for (int r = 0; r < NR; ++r) g[r] /= s;
  if (j < NR) gates[j] = g[j];
  if (j < HID) {
    float b = 0.f;
    for (int r = 0; r < NR; ++r) b = fmaf(g[r], gat_bias[((size_t)(l * NR + r)) * HID + j], b);
    msg_bias[j] = b;
  }
  for (int r = 0; r < NR; ++r) {
    const float* Wer = We + ((size_t)(l * NR + r)) * 24 * 512;
    const float* re  = rel_emb + (l * NR + r) * RELDIM;
    float acc = 0.f;
#pragma unroll
    for (int q = 0; q < RELDIM; ++q) acc = fmaf(re[q], Wer[(FEDGE + q) * 512 + j], acc);
    erel[r * 512 + j] = acc;
  }
}

// ---------------- fills ----------------
__global__ void fill_zero(float* __restrict__ p, int n) {
  int i = blockIdx.x * 256 + threadIdx.x;
  if (i < n) p[i] = 0.f;
}
__global__ void fill_zero_i(int* __restrict__ p, int n) {
  int i = blockIdx.x * 256 + threadIdx.x;
  if (i < n) p[i] = 0;
}

// ---------------- CSR build (by target) ----------------
__global__ void csr_count(const int* __restrict__ eidx, int* __restrict__ deg) {
  int e = blockIdx.x * 256 + threadIdx.x;
  if (e < NE) atomicAdd(&deg[eidx[NE + e]], 1);
}
__global__ __launch_bounds__(256) void csr_scan(const int* __restrict__ deg,
                                                int* __restrict__ in_off, int* __restrict__ cursor) {
  __shared__ int ps[256];
  int t = threadIdx.x;
  const int CH = (NN + 255) / 256;  // 40
  int base = t * CH;
  int sum = 0;
  for (int i = 0; i < CH; ++i) { int idx = base + i; if (idx < NN) sum += deg[idx]; }
  ps[t] = sum;
  __syncthreads();
  for (int o = 1; o < 256; o <<= 1) {
    int v = (t >= o) ? ps[t - o] : 0;
    __syncthreads();
    ps[t] += v;
    __syncthreads();
  }
  int run = (t == 0) ? 0 : ps[t - 1];
  for (int i = 0; i < CH; ++i) {
    int idx = base + i;
    if (idx < NN) { in_off[idx] = run; cursor[idx] = run; run += deg[idx]; }
  }
  if (t == 255) in_off[NN] = run;
}
__global__ void csr_scatter(const int* __restrict__ eidx, int* __restrict__ cursor,
                            int* __restrict__ in_edges) {
  int e = blockIdx.x * 256 + threadIdx.x;
  if (e < NE) {
    int pos = atomicAdd(&cursor[eidx[NE + e]], 1);
    in_edges[pos] = e;
  }
}

// ---------------- node-centric GAT pass: score+softmax+aggregate, one wave per node ----
__global__ __launch_bounds__(256) void gat_node(
    const int* __restrict__ in_off, const int* __restrict__ in_edges,
    const int* __restrict__ etype, const int* __restrict__ eidx,
    const float* __restrict__ eattr, const float* __restrict__ xlr,
    const float* __restrict__ We_r, const float* __restrict__ erel_r,
    const float* __restrict__ att_r, const float* __restrict__ gates,
    int r, float beta, float* __restrict__ hmsg) {
  __shared__ float WeL[16][512];
  __shared__ float attL[512];
  __shared__ float erelL[512];
  int tid = threadIdx.x;
  for (int i = tid; i < 16 * 512; i += 256) WeL[i >> 9][i & 511] = We_r[i];
  for (int i = tid; i < 512; i += 256) { attL[i] = att_r[i]; erelL[i] = erel_r[i]; }
  __syncthreads();
  float gr = gates[r] * 0.25f;
  int lane = tid & 63, wave = tid >> 6;
  int n = blockIdx.x * 4 + wave;
  if (n >= NN) return;
  float xr[8];
  const float* xrb = xlr + (size_t)n * 1024 + 512;
#pragma unroll
  for (int h = 0; h < 4; ++h) {
    xr[h * 2]     = xrb[h * 128 + lane];
    xr[h * 2 + 1] = xrb[h * 128 + 64 + lane];
  }
  float m[4] = {-1e30f, -1e30f, -1e30f, -1e30f};
  float lsum[4] = {0.f, 0.f, 0.f, 0.f};
  float acc[8] = {0.f, 0.f, 0.f, 0.f, 0.f, 0.f, 0.f, 0.f};
  int e0 = in_off[n], e1 = in_off[n + 1];
  for (int ii = e0; ii < e1; ++ii) {
    int e = in_edges[ii];
    if (etype[e] != r) continue;
    int s = eidx[e];
    const float* xls = xlr + (size_t)s * 1024;
    float ea[16];
#pragma unroll
    for (int k = 0; k < 16; ++k) ea[k] = eattr[(size_t)e * 16 + k];
    float xlv[8], p[4];
#pragma unroll
    for (int h = 0; h < 4; ++h) {
      float ph = 0.f;
#pragma unroll
      for (int half = 0; half < 2; ++half) {
        int idx = h * 128 + half * 64 + lane;
        float xv = xls[idx];
        xlv[h * 2 + half] = xv;
        float et = erelL[idx];
#pragma unroll
        for (int k = 0; k < 16; ++k) et = fmaf(ea[k], WeL[k][idx], et);
        float z = xv + xr[h * 2 + half] + et;
        z = (z > 0.f) ? z : 0.2f * z;  // leaky_relu 0.2
        ph = fmaf(z, attL[idx], ph);
      }
      p[h] = ph;
    }
#pragma unroll
    for (int h = 0; h < 4; ++h) {
#pragma unroll
      for (int o = 32; o > 0; o >>= 1) p[h] += __shfl_xor(p[h], o, 64);
    }
#pragma unroll
    for (int h = 0; h < 4; ++h) {
      float sh = p[h];
      float mn = fmaxf(m[h], sh);
      float sc = expf(m[h] - mn);
      float we = expf(sh - mn);
      m[h] = mn;
      lsum[h] = lsum[h] * sc + we;
      acc[h * 2]     = acc[h * 2] * sc + we * xlv[h * 2];
      acc[h * 2 + 1] = acc[h * 2 + 1] * sc + we * xlv[h * 2 + 1];
    }
  }
  float o0 = 0.f, o1 = 0.f;
#pragma unroll
  for (int h = 0; h < 4; ++h) {
    float inv = 1.f / fmaxf(lsum[h], 1e-16f);
    o0 += acc[h * 2] * inv;
    o1 += acc[h * 2 + 1] * inv;
  }
  size_t base = (size_t)n * HID;
  float old0 = 0.f, old1 = 0.f;
  if (beta != 0.f) { old0 = hmsg[base + lane]; old1 = hmsg[base + 64 + lane]; }
  hmsg[base + lane]      = old0 + gr * o0;
  hmsg[base + 64 + lane] = old1 + gr * o1;
}

// ---------------- LayerNorm over 128 dims (optionally emits hi/lo bf16) ----------------
__global__ __launch_bounds__(64) void ln128(
    float* __restrict__ h, const float* __restrict__ add, const float* __restrict__ bvec,
    const float* __restrict__ g, const float* __restrict__ b,
    ushort* __restrict__ hh, ushort* __restrict__ hl) {
  int n = blockIdx.x, lane = threadIdx.x;
  size_t base = (size_t)n * HID;
  float x0 = h[base + lane] + add[base + lane];
  float x1 = h[base + 64 + lane] + add[base + 64 + lane];
  if (bvec) { x0 += bvec[lane]; x1 += bvec[64 + lane]; }
  float s = x0 + x1;
#pragma unroll
  for (int m = 32; m > 0; m >>= 1) s += __shfl_xor(s, m, 64);
  float mu = s * (1.f / 128.f);
  float d0 = x0 - mu, d1 = x1 - mu;
  float q = d0 * d0 + d1 * d1;
#pragma unroll
  for (int m = 32; m > 0; m >>= 1) q += __shfl_xor(q, m, 64);
  float inv = 1.f / sqrtf(q * (1.f / 128.f) + 1e-5f);
  float o0 = d0 * inv * g[lane] + b[lane];
  float o1 = d1 * inv * g[64 + lane] + b[64 + lane];
  h[base + lane]      = o0;
  h[base + 64 + lane] = o1;
  if (hh) {
    ushort i0 = f2bf(o0), i1 = f2bf(o1);
    hh[base + lane] = i0;        hh[base + 64 + lane] = i1;
    hl[base + lane] = f2bf(o0 - bf2f(i0));
    hl[base + 64 + lane] = f2bf(o1 - bf2f(i1));
  }
}

// ---------------- KAN expansion (fp32) — tiny readout head only ----------------
__global__ void expand_f32(const float* __restrict__ v, float* __restrict__ u, int In, int rows) {
  int i = blockIdx.x * 256 + threadIdx.x;
  if (i >= rows * In) return;
  int n = i / In, c = i % In;
  float x = v[(size_t)n * In + c];
  size_t base = (size_t)n * In * 9;
  u[base + c] = silu_f(x);
  float b8[8];
  kan_bases(x, b8);
  float* ub = u + base + In + (size_t)c * 8;
#pragma unroll
  for (int gq = 0; gq < 8; ++gq) ub[gq] = b8[gq];
}

// ---------------- readout ----------------
__global__ void pool_init(float* __restrict__ mean, unsigned* __restrict__ maxenc, float* __restrict__ cnt) {
  int i = blockIdx.x * 256 + threadIdx.x;
  if (i < NG * HID) { mean[i] = 0.f; maxenc[i] = ENC_NEG_INF; }
  if (i < NG) cnt[i] = 0.f;
}
__global__ __launch_bounds__(128) void pool_accum(
    const float* __restrict__ h, const int* __restrict__ batch,
    float* __restrict__ mean, unsigned* __restrict__ maxenc, float* __restrict__ cnt) {
  int n = blockIdx.x, d = threadIdx.x;
  int g = batch[n];
  float v = h[(size_t)n * HID + d];
  atomicAdd(&mean[g * HID + d], v);
  atomicMax(&maxenc[g * HID + d], fenc(v));
  if (d == 0) atomicAdd(&cnt[g], 1.f);
}
__global__ __launch_bounds__(256) void pool_final_ln(
    const float* __restrict__ mean, const unsigned* __restrict__ maxenc,
    const float* __restrict__ cnt, const float* __restrict__ rog,
    const float* __restrict__ rob, float* __restrict__ gvec) {
  int g = blockIdx.x, j = threadIdx.x;
  __shared__ float rb[256];
  float x;
  if (j < HID) x = mean[g * HID + j] / fmaxf(cnt[g], 1.f);
  else {
    float mv = fdec(maxenc[g * HID + (j - HID)]);
    x = (mv > -1e38f) ? mv : 0.f;
  }
  rb[j] = x; __syncthreads();
  for (int st = 128; st > 0; st >>= 1) { if (j < st) rb[j] += rb[j + st]; __syncthreads(); }
  float mu = rb[0] * (1.f / 256.f); __syncthreads();
  float d = x - mu;
  rb[j] = d * d; __syncthreads();
  for (int st = 128; st > 0; st >>= 1) { if (j < st) rb[j] += rb[j + st]; __syncthreads(); }
  float var = rb[0] * (1.f / 256.f);
  float inv = 1.f / sqrtf(var + 1e-5f);
  gvec[(size_t)g * 256 + j] = d * inv * rog[j] + rob[j];
}

// ---------------- wave-parallel KAN head: one wave per (graph, output) ----------------
__global__ __launch_bounds__(256) void kan_head_w(
    const float* __restrict__ u, const float* __restrict__ base_w,
    const float* __restrict__ spline_w, const float* __restrict__ scaler,
    float* __restrict__ out, int In, int Out, int npairs) {
  int wid = blockIdx.x * 4 + (threadIdx.x >> 6);
  if (wid >= npairs) return;
  int g = wid / Out, o = wid % Out;
  int lane = threadIdx.x & 63;
  const float* ug = u + (size_t)g * In * 9;
  const float* bw = base_w + (size_t)o * In;
  const float* sp = spline_w + (size_t)o * In * 8;
  const float* sc = scaler + (size_t)o * In;
  float acc = 0.f;
  for (int i = lane; i < In; i += 64) acc = fmaf(ug[i], bw[i], acc);
  const float* us = ug + In;
  for (int k = lane; k < In * 8; k += 64) {
    int i = k >> 3;
    acc = fmaf(us[k], sp[k] * sc[i], acc);
  }
#pragma unroll
  for (int off2 = 32; off2 > 0; off2 >>= 1) acc += __shfl_xor(acc, off2, 64);
  if (lane == 0) out[(size_t)g * Out + o] = acc;
}

// ---------------- launch ----------------
extern "C" void kernel_launch(void* const* d_in, const int* in_sizes, int n_in,
                              void* d_out, int out_size, void* d_ws, size_t ws_size,
                              hipStream_t stream) {
  const float* x         = (const float*)d_in[0];
  const float* edge_attr = (const float*)d_in[1];
  const int*   id_token  = (const int*)  d_in[2];
  const int*   edge_index= (const int*)  d_in[3];
  const int*   edge_type = (const int*)  d_in[4];
  const int*   batch     = (const int*)  d_in[5];
  const float* id_emb    = (const float*)d_in[6];
  const float* inW       = (const float*)d_in[7];
  const float* inb       = (const float*)d_in[8];
  const float* Wl        = (const float*)d_in[9];
  const float* bl        = (const float*)d_in[10];
  const float* Wr        = (const float*)d_in[11];
  const float* br        = (const float*)d_in[12];
  const float* We        = (const float*)d_in[13];
  const float* att       = (const float*)d_in[14];
  const float* gat_bias  = (const float*)d_in[15];
  const float* rel_gate  = (const float*)d_in[16];
  const float* rel_emb   = (const float*)d_in[17];
  const float* ln1g      = (const float*)d_in[18];
  const float* ln1b      = (const float*)d_in[19];
  const float* ln2g      = (const float*)d_in[20];
  const float* ln2b      = (const float*)d_in[21];
  const float* ffn1_base = (const float*)d_in[22];
  const float* ffn1_spl  = (const float*)d_in[23];
  const float* ffn1_sc   = (const float*)d_in[24];
  const float* ffn2_base = (const float*)d_in[25];
  const float* ffn2_spl  = (const float*)d_in[26];
  const float* ffn2_sc   = (const float*)d_in[27];
  const float* rog       = (const float*)d_in[28];
  const float* rob       = (const float*)d_in[29];
  const float* h1_base   = (const float*)d_in[30];
  const float* h1_spl    = (const float*)d_in[31];
  const float* h1_sc     = (const float*)d_in[32];
  const float* h2_base   = (const float*)d_in[33];
  const float* h2_spl    = (const float*)d_in[34];
  const float* h2_sc     = (const float*)d_in[35];
  (void)in_sizes; (void)n_in; (void)out_size; (void)ws_size;

  // ---- workspace carve (256B aligned) ----
  char* wsp = (char*)d_ws;
  size_t off = 0;
  auto carve = [&](size_t bytes) { char* p = wsp + off; off = (off + bytes + 255) & ~(size_t)255; return p; };
  float*    h     = (float*)   carve((size_t)NN * HID * 4);
  ushort*   h_hi  = (ushort*)  carve((size_t)NN * HID * 2);
  ushort*   h_lo  = (ushort*)  carve((size_t)NN * HID * 2);
  float*    hmsg  = (float*)   carve((size_t)NN * HID * 4);
  float*    t1    = (float*)   carve((size_t)NN * FFNH * 4);
  float*    gates = (float*)   carve(NR * 4);
  float*    msgb  = (float*)   carve(HID * 4);
  float*    erel  = (float*)   carve(NR * 512 * 4);
  ushort*   WTh   = (ushort*)  carve((size_t)NL * NR * 1024 * HID * 2);
  ushort*   WTl   = (ushort*)  carve((size_t)NL * NR * 1024 * HID * 2);
  float*    blr   = (float*)   carve((size_t)NL * NR * 1024 * 4);
  ushort*   B1h   = (ushort*)  carve((size_t)FFNH * HID * 9 * 2);
  ushort*   B1l   = (ushort*)  carve((size_t)FFNH * HID * 9 * 2);
  ushort*   B2h   = (ushort*)  carve((size_t)HID * FFNH * 9 * 2);
  ushort*   B2l   = (ushort*)  carve((size_t)HID * FFNH * 9 * 2);
  float*    pm    = (float*)   carve((size_t)NG * HID * 4);
  unsigned* pmax  = (unsigned*)carve((size_t)NG * HID * 4);
  float*    cnt   = (float*)   carve(NG * 4);
  float*    gvec  = (float*)   carve((size_t)NG * 256 * 4);
  float*    uhead = (float*)   carve((size_t)NG * 256 * 9 * 4);
  float*    thead = (float*)   carve((size_t)NG * HEADH * 4);
  float*    xlr   = (float*)   carve((size_t)NN * 1024 * 4);
  int*      deg   = (int*)     carve((size_t)NN * 4);
  int*      in_off= (int*)     carve((size_t)(NN + 1) * 4);
  int*      cursor= (int*)     carve((size_t)NN * 4);
  int*      in_edges=(int*)    carve((size_t)NE * 4);

  // ---- CSR build (by target) ----
  fill_zero_i<<<(NN + 255) / 256, 256, 0, stream>>>(deg, NN);
  csr_count<<<(NE + 255) / 256, 256, 0, stream>>>(edge_index, deg);
  csr_scan<<<1, 256, 0, stream>>>(deg, in_off, cursor);
  csr_scatter<<<(NE + 255) / 256, 256, 0, stream>>>(edge_index, cursor, in_edges);

  // ---- weight transpose + split (once per launch) ----
  {
    int total = NL * NR * 1024 * 128;
    conv_wT2<<<(total + 255) / 256, 256, 0, stream>>>(Wl, Wr, bl, br, WTh, WTl, blr, total);
  }

  // ---- input projection ----
  input_proj<<<NN, 128, 0, stream>>>(x, id_emb, id_token, inW, inb, h, h_hi, h_lo);

  const int MB128 = (NN + 127) / 128;  // 79
  const int MB64  = (NN + 63) / 64;    // 157
  for (int l = 0; l < NL; ++l) {
    layer_prep<<<1, 512, 0, stream>>>(rel_gate, gat_bias, rel_emb, We, l, gates, msgb, erel);
    for (int r = 0; r < NR; ++r) {
      const ushort* WThr = WTh + ((size_t)(l * NR + r)) * 1024 * HID;
      const ushort* WTlr = WTl + ((size_t)(l * NR + r)) * 1024 * HID;
      const float* blrr  = blr + (size_t)(l * NR + r) * 1024;
      const float* Wer   = We + ((size_t)(l * NR + r)) * 24 * 512;
      const float* attr  = att + (size_t)(l * NR + r) * 512;
      gemm_bf3<<<dim3(1024 / 64, MB128), 256, 0, stream>>>(h_hi, h_lo, WThr, WTlr, blrr, xlr, NN, HID, 1024);
      gat_node<<<(NN + 3) / 4, 256, 0, stream>>>(in_off, in_edges, edge_type, edge_index,
                                                 edge_attr, xlr, Wer, erel + r * 512, attr,
                                                 gates, r, (r == 0) ? 0.f : 1.f, hmsg);
    }
    ln128<<<NN, 64, 0, stream>>>(h, hmsg, msgb, ln1g + l * HID, ln1b + l * HID, nullptr, nullptr);

    // ---- KAN FFN1: 128 -> 256 (K = 1152), fused expansion, split-K 3 ----
    build_kan_wT<<<((HID * 9 * FFNH) + 255) / 256, 256, 0, stream>>>(
        ffn1_base + (size_t)l * FFNH * HID, ffn1_spl + (size_t)l * FFNH * HID * 8,
        ffn1_sc + (size_t)l * FFNH * HID, B1h, B1l, HID, FFNH);
    fill_zero<<<(NN * FFNH + 255) / 256, 256, 0, stream>>>(t1, NN * FFNH);
    gemm_kan<128, 3><<<dim3(FFNH / 64, MB128, 3), 256, 0, stream>>>(h, B1h, B1l, t1, NN, HID, FFNH);
    // ---- KAN FFN2: 256 -> 128 (K = 2304), fused expansion, split-K 4 ----
    build_kan_wT<<<((FFNH * 9 * HID) + 255) / 256, 256, 0, stream>>>(
        ffn2_base + (size_t)l * HID * FFNH, ffn2_spl + (size_t)l * HID * FFNH * 8,
        ffn2_sc + (size_t)l * HID * FFNH, B2h, B2l, FFNH, HID);
    fill_zero<<<(NN * HID + 255) / 256, 256, 0, stream>>>(hmsg, NN * HID);
    gemm_kan<64, 4><<<dim3(HID / 64, MB64, 4), 256, 0, stream>>>(t1, B2h, B2l, hmsg, NN, FFNH, HID);
    ln128<<<NN, 64, 0, stream>>>(h, hmsg, nullptr, ln2g + l * HID, ln2b + l * HID, h_hi, h_lo);
  }

  // ---- readout ----
  pool_init<<<(NG * HID + 255) / 256, 256, 0, stream>>>(pm, pmax, cnt);
  pool_accum<<<NN, 128, 0, stream>>>(h, batch, pm, pmax, cnt);
  pool_final_ln<<<NG, 256, 0, stream>>>(pm, pmax, cnt, rog, rob, gvec);
  expand_f32<<<((NG * 256) + 255) / 256, 256, 0, stream>>>(gvec, uhead, 256, NG);
  {
    int npairs = NG * HEADH;  // 4096 waves
    kan_head_w<<<(npairs + 3) / 4, 256, 0, stream>>>(uhead, h1_base, h1_spl, h1_sc, thead, 256, HEADH, npairs);
  }
  expand_f32<<<((NG * HEADH) + 255) / 256, 256, 0, stream>>>(thead, uhead, HEADH, NG);
  {
    int npairs = NG * NCLS;   // 320 waves
    kan_head_w<<<(npairs + 3) / 4, 256, 0, stream>>>(uhead, h2_base, h2_spl, h2_sc, (float*)d_out, HEADH, NCLS, npairs);
  }
}

// Round 8
// 1861.714 us; speedup vs baseline: 1.9415x; 1.1153x over previous
//
#include <hip/hip_runtime.h>
#include <cstdint>
#include <cstddef>

// ---------------- static problem config ----------------
#define NN      10000   // nodes
#define NE      120000  // edges
#define NG      32      // graphs
#define FNODE   64
#define FEDGE   16
#define HID     128
#define NHEADS  4
#define NL      3
#define NR      4
#define IDDIM   32
#define RELDIM  8
#define FFNH    256
#define HEADH   128
#define NCLS    10

#define NCHUNK  128     // pooling stage-1 blocks

typedef __attribute__((ext_vector_type(8))) short short8;
typedef __attribute__((ext_vector_type(4))) float floatx4;

// ---------------- helpers ----------------
__device__ __forceinline__ float silu_f(float x) { return x / (1.f + expf(-x)); }
__device__ __forceinline__ ushort f2bf(float f) {   // round-to-nearest-even bf16
  unsigned u = __float_as_uint(f);
  return (ushort)((u + 0x7FFFu + ((u >> 16) & 1u)) >> 16);
}
__device__ __forceinline__ float bf2f(ushort h) { return __uint_as_float((unsigned)h << 16); }

// Cox–de Boor cubic bases on grid t_j = (j-3)*0.4 - 1 (GRID_SIZE=5, ORDER=3) -> 8 bases
__device__ __forceinline__ void kan_bases(float x, float* out8) {
  float bb[11];
#pragma unroll
  for (int j = 0; j < 11; ++j) {
    float t0 = (j - 3) * 0.4f - 1.f;
    float t1 = (j - 2) * 0.4f - 1.f;
    bb[j] = (x >= t0 && x < t1) ? 1.f : 0.f;
  }
  {
    const float inv = 1.f / 0.4f;
#pragma unroll
    for (int j = 0; j < 10; ++j) {
      float tj = (j - 3) * 0.4f - 1.f, tjp1 = (j - 1) * 0.4f - 1.f;
      bb[j] = ((x - tj) * bb[j] + (tjp1 - x) * bb[j + 1]) * inv;
    }
  }
  {
    const float inv = 1.f / 0.8f;
#pragma unroll
    for (int j = 0; j < 9; ++j) {
      float tj = (j - 3) * 0.4f - 1.f, tjp1 = (j) * 0.4f - 1.f;
      bb[j] = ((x - tj) * bb[j] + (tjp1 - x) * bb[j + 1]) * inv;
    }
  }
  {
    const float inv = 1.f / 1.2000001f;
#pragma unroll
    for (int j = 0; j < 8; ++j) {
      float tj = (j - 3) * 0.4f - 1.f, tjp1 = (j + 1) * 0.4f - 1.f;
      bb[j] = ((x - tj) * bb[j] + (tjp1 - x) * bb[j + 1]) * inv;
    }
  }
#pragma unroll
  for (int j = 0; j < 8; ++j) out8[j] = bb[j];
}

// ---------------- 3-term MFMA GEMM, operands pre-split bf16 hi/lo ----------------
// LDA=68: +4 pad breaks pow2 stride (<=2-way conflicts, free); LDS 52.2KB -> 3 blocks/CU.
__global__ __launch_bounds__(256) void gemm_bf3(
    const ushort* __restrict__ Ahg, const ushort* __restrict__ Alg,
    const ushort* __restrict__ Bhg, const ushort* __restrict__ Blg,
    const float* __restrict__ bias, float* __restrict__ C,
    int M, int K, int N) {
  constexpr int LDA = 68;
  __shared__ __align__(16) ushort Ah[128 * LDA];
  __shared__ __align__(16) ushort Al[128 * LDA];
  __shared__ __align__(16) ushort Bh[64 * LDA];
  __shared__ __align__(16) ushort Bl[64 * LDA];
  const int tid = threadIdx.x;
  const int lane = tid & 63, wave = tid >> 6;
  const int lrow = lane & 15, quad = lane >> 4;
  const int bm = blockIdx.y * 128, bn = blockIdx.x * 64;
  floatx4 acc[2][4] = {};
  for (int k0 = 0; k0 < K; k0 += 64) {
#pragma unroll
    for (int i = 0; i < 4; ++i) {
      int c = tid + i * 256;
      int row = c >> 3, col8 = c & 7;
      int gr = bm + row;
      uint4 vh = make_uint4(0, 0, 0, 0), vl = make_uint4(0, 0, 0, 0);
      if (gr < M) {
        vh = *(const uint4*)(Ahg + (size_t)gr * K + k0 + col8 * 8);
        vl = *(const uint4*)(Alg + (size_t)gr * K + k0 + col8 * 8);
      }
      *(uint4*)&Ah[row * LDA + col8 * 8] = vh;
      *(uint4*)&Al[row * LDA + col8 * 8] = vl;
    }
#pragma unroll
    for (int i = 0; i < 2; ++i) {
      int c = tid + i * 256;
      int row = c >> 3, col8 = c & 7;
      *(uint4*)&Bh[row * LDA + col8 * 8] = *(const uint4*)(Bhg + (size_t)(bn + row) * K + k0 + col8 * 8);
      *(uint4*)&Bl[row * LDA + col8 * 8] = *(const uint4*)(Blg + (size_t)(bn + row) * K + k0 + col8 * 8);
    }
    __syncthreads();
#pragma unroll
    for (int kk = 0; kk < 64; kk += 32) {
      int kof = kk + quad * 8;
      const int ra0 = (wave * 32 + lrow) * LDA + kof;
      const int ra1 = (wave * 32 + 16 + lrow) * LDA + kof;
      short8 ah0 = *(const short8*)&Ah[ra0];
      short8 ah1 = *(const short8*)&Ah[ra1];
      short8 al0 = *(const short8*)&Al[ra0];
      short8 al1 = *(const short8*)&Al[ra1];
      short8 bh[4], blo[4];
#pragma unroll
      for (int nt = 0; nt < 4; ++nt) {
        int rb = (nt * 16 + lrow) * LDA + kof;
        bh[nt]  = *(const short8*)&Bh[rb];
        blo[nt] = *(const short8*)&Bl[rb];
      }
#pragma unroll
      for (int nt = 0; nt < 4; ++nt) {
        acc[0][nt] = __builtin_amdgcn_mfma_f32_16x16x32_bf16(ah0, bh[nt],  acc[0][nt], 0, 0, 0);
        acc[1][nt] = __builtin_amdgcn_mfma_f32_16x16x32_bf16(ah1, bh[nt],  acc[1][nt], 0, 0, 0);
        acc[0][nt] = __builtin_amdgcn_mfma_f32_16x16x32_bf16(al0, bh[nt],  acc[0][nt], 0, 0, 0);
        acc[1][nt] = __builtin_amdgcn_mfma_f32_16x16x32_bf16(al1, bh[nt],  acc[1][nt], 0, 0, 0);
        acc[0][nt] = __builtin_amdgcn_mfma_f32_16x16x32_bf16(ah0, blo[nt], acc[0][nt], 0, 0, 0);
        acc[1][nt] = __builtin_amdgcn_mfma_f32_16x16x32_bf16(ah1, blo[nt], acc[1][nt], 0, 0, 0);
      }
    }
    __syncthreads();
  }
#pragma unroll
  for (int mt = 0; mt < 2; ++mt) {
#pragma unroll
    for (int nt = 0; nt < 4; ++nt) {
#pragma unroll
      for (int reg = 0; reg < 4; ++reg) {
        int row = bm + wave * 32 + mt * 16 + quad * 4 + reg;
        int col = bn + nt * 16 + lrow;
        if (row < M) {
          float v = acc[mt][nt][reg];
          if (bias) v += bias[col];
          C[(size_t)row * N + col] = v;
        }
      }
    }
  }
}

// ---------------- fused KAN GEMM w/ split-K: C += expand(A) @ BT^T ----------------
template<int BM, int SPLIT>
__global__ __launch_bounds__(256) void gemm_kan(
    const float* __restrict__ A, const ushort* __restrict__ Bhg, const ushort* __restrict__ Blg,
    float* __restrict__ C, int M, int In, int N) {
  const int K = In * 9;
  const int ntiles = K >> 6;
  const int per = (ntiles + SPLIT - 1) / SPLIT;
  const int kt0 = blockIdx.z * per;
  const int kt1 = (kt0 + per < ntiles) ? (kt0 + per) : ntiles;
  constexpr int LDA = 68;
  __shared__ __align__(16) ushort Ah[BM * LDA];
  __shared__ __align__(16) ushort Al[BM * LDA];
  __shared__ __align__(16) ushort Bh[64 * LDA];
  __shared__ __align__(16) ushort Bl[64 * LDA];
  const int tid = threadIdx.x;
  const int lane = tid & 63, wave = tid >> 6;
  const int lrow = lane & 15, quad = lane >> 4;
  const int bm = blockIdx.y * BM, bn = blockIdx.x * 64;
  constexpr int MT = BM / 64;
  floatx4 acc[MT][4] = {};
  for (int kt = kt0; kt < kt1; ++kt) {
    int k0 = kt << 6;
    if (k0 < In) {
#pragma unroll
      for (int i = 0; i < BM / 16; ++i) {
        int c = tid + i * 256;
        int row = c >> 4, col4 = c & 15;
        int gr = bm + row;
        float4 v = make_float4(0.f, 0.f, 0.f, 0.f);
        if (gr < M) v = *(const float4*)(A + (size_t)gr * In + k0 + col4 * 4);
        float vv[4] = {silu_f(v.x), silu_f(v.y), silu_f(v.z), silu_f(v.w)};
        ushort h0 = f2bf(vv[0]), h1 = f2bf(vv[1]), h2 = f2bf(vv[2]), h3 = f2bf(vv[3]);
        ushort l0 = f2bf(vv[0] - bf2f(h0)), l1 = f2bf(vv[1] - bf2f(h1));
        ushort l2 = f2bf(vv[2] - bf2f(h2)), l3 = f2bf(vv[3] - bf2f(h3));
        *(uint2*)&Ah[row * LDA + col4 * 4] =
          make_uint2((unsigned)h0 | ((unsigned)h1 << 16), (unsigned)h2 | ((unsigned)h3 << 16));
        *(uint2*)&Al[row * LDA + col4 * 4] =
          make_uint2((unsigned)l0 | ((unsigned)l1 << 16), (unsigned)l2 | ((unsigned)l3 << 16));
      }
    } else {
      int i0 = (k0 - In) >> 3;
      if (tid < BM * 2) {
        int row = tid >> 1, half = tid & 1;
        int gr = bm + row;
        float4 v = make_float4(0.f, 0.f, 0.f, 0.f);
        if (gr < M) v = *(const float4*)(A + (size_t)gr * In + i0 + half * 4);
        float vv[4] = {v.x, v.y, v.z, v.w};
#pragma unroll
        for (int jj = 0; jj < 4; ++jj) {
          float b8[8];
          kan_bases(vv[jj], b8);
          unsigned hu[4], lu[4];
#pragma unroll
          for (int q = 0; q < 4; ++q) {
            ushort ha = f2bf(b8[2 * q]), hb = f2bf(b8[2 * q + 1]);
            ushort la = f2bf(b8[2 * q] - bf2f(ha)), lb = f2bf(b8[2 * q + 1] - bf2f(hb));
            hu[q] = (unsigned)ha | ((unsigned)hb << 16);
            lu[q] = (unsigned)la | ((unsigned)lb << 16);
          }
          int cbase = (half * 4 + jj) * 8;
          *(uint4*)&Ah[row * LDA + cbase] = make_uint4(hu[0], hu[1], hu[2], hu[3]);
          *(uint4*)&Al[row * LDA + cbase] = make_uint4(lu[0], lu[1], lu[2], lu[3]);
        }
      }
    }
#pragma unroll
    for (int i = 0; i < 2; ++i) {
      int c = tid + i * 256;
      int row = c >> 3, col8 = c & 7;
      *(uint4*)&Bh[row * LDA + col8 * 8] = *(const uint4*)(Bhg + (size_t)(bn + row) * K + k0 + col8 * 8);
      *(uint4*)&Bl[row * LDA + col8 * 8] = *(const uint4*)(Blg + (size_t)(bn + row) * K + k0 + col8 * 8);
    }
    __syncthreads();
#pragma unroll
    for (int kk = 0; kk < 64; kk += 32) {
      int kof = kk + quad * 8;
      short8 ah[MT], al[MT];
#pragma unroll
      for (int mt = 0; mt < MT; ++mt) {
        int ra = (wave * (BM / 4) + mt * 16 + lrow) * LDA + kof;
        ah[mt] = *(const short8*)&Ah[ra];
        al[mt] = *(const short8*)&Al[ra];
      }
      short8 bh[4], blo[4];
#pragma unroll
      for (int nt = 0; nt < 4; ++nt) {
        int rb = (nt * 16 + lrow) * LDA + kof;
        bh[nt]  = *(const short8*)&Bh[rb];
        blo[nt] = *(const short8*)&Bl[rb];
      }
#pragma unroll
      for (int nt = 0; nt < 4; ++nt) {
#pragma unroll
        for (int mt = 0; mt < MT; ++mt) {
          acc[mt][nt] = __builtin_amdgcn_mfma_f32_16x16x32_bf16(ah[mt], bh[nt],  acc[mt][nt], 0, 0, 0);
          acc[mt][nt] = __builtin_amdgcn_mfma_f32_16x16x32_bf16(al[mt], bh[nt],  acc[mt][nt], 0, 0, 0);
          acc[mt][nt] = __builtin_amdgcn_mfma_f32_16x16x32_bf16(ah[mt], blo[nt], acc[mt][nt], 0, 0, 0);
        }
      }
    }
    __syncthreads();
  }
#pragma unroll
  for (int mt = 0; mt < MT; ++mt) {
#pragma unroll
    for (int nt = 0; nt < 4; ++nt) {
#pragma unroll
      for (int reg = 0; reg < 4; ++reg) {
        int row = bm + wave * (BM / 4) + mt * 16 + quad * 4 + reg;
        int col = bn + nt * 16 + lrow;
        if (row < M) atomicAdd(&C[(size_t)row * N + col], acc[mt][nt][reg]);
      }
    }
  }
}

// ---------------- weight transpose+split: relation pairs -> [L*2][2048][128] ----------------
__global__ void conv_wT2(const float* __restrict__ Wl, const float* __restrict__ Wr,
                         const float* __restrict__ bl, const float* __restrict__ br,
                         ushort* __restrict__ WTh, ushort* __restrict__ WTl,
                         float* __restrict__ bout, int total) {
  int i = blockIdx.x * 256 + threadIdx.x;
  if (i >= total) return;
  int g2 = i / (2048 * 128), rem = i % (2048 * 128);
  int n = rem >> 7, k = rem & 127;
  int l = g2 >> 1, pair = g2 & 1;
  int r = pair * 2 + (n >> 10);          // relation within layer
  int nsub = n & 1023;                   // 0..1023 within [Wl|Wr]
  int nn = nsub & 511;
  int g = l * NR + r;
  const float* W = (nsub < 512) ? Wl : Wr;
  float v = W[(size_t)g * 65536 + (size_t)k * 512 + nn];
  ushort hi = f2bf(v);
  WTh[i] = hi;
  WTl[i] = f2bf(v - bf2f(hi));
  if (k == 0) bout[g2 * 2048 + n] = ((nsub < 512) ? bl : br)[g * 512 + nn];
}

// ---------------- build expanded KAN weight, transposed + split ----------------
__global__ void build_kan_wT(const float* __restrict__ base_w, const float* __restrict__ spline_w,
                             const float* __restrict__ scaler,
                             ushort* __restrict__ BTh, ushort* __restrict__ BTl,
                             int In, int Out) {
  int i = blockIdx.x * 256 + threadIdx.x;
  if (i >= In * 9 * Out) return;
  int o = i / (In * 9), k = i % (In * 9);
  float v;
  if (k < In) v = base_w[(size_t)o * In + k];
  else {
    int q = k - In, ii = q >> 3, gq = q & 7;
    v = spline_w[((size_t)o * In + ii) * 8 + gq] * scaler[(size_t)o * In + ii];
  }
  ushort hi = f2bf(v);
  BTh[i] = hi;
  BTl[i] = f2bf(v - bf2f(hi));
}

// ---------------- input projection (fp32 h + hi/lo bf16) ----------------
__global__ __launch_bounds__(128) void input_proj(
    const float* __restrict__ x, const float* __restrict__ id_emb,
    const int* __restrict__ id_token, const float* __restrict__ inW,
    const float* __restrict__ inb, float* __restrict__ h,
    ushort* __restrict__ hh, ushort* __restrict__ hl) {
  int n = blockIdx.x, j = threadIdx.x;
  __shared__ float s[FNODE + IDDIM];
  if (j < FNODE) s[j] = x[(size_t)n * FNODE + j];
  else if (j < FNODE + IDDIM) s[j] = id_emb[(size_t)id_token[n] * IDDIM + (j - FNODE)];
  __syncthreads();
  float acc = inb[j];
#pragma unroll
  for (int k = 0; k < FNODE + IDDIM; ++k) acc = fmaf(s[k], inW[k * HID + j], acc);
  float v = silu_f(acc);
  h[(size_t)n * HID + j] = v;
  ushort hi = f2bf(v);
  hh[(size_t)n * HID + j] = hi;
  hl[(size_t)n * HID + j] = f2bf(v - bf2f(hi));
}

// ---------------- per-layer prep ----------------
__global__ __launch_bounds__(512) void layer_prep(
    const float* __restrict__ rel_gate, const float* __restrict__ gat_bias,
    const float* __restrict__ rel_emb, const float* __restrict__ We, int l,
    float* __restrict__ gates, float* __restrict__ msg_bias, float* __restrict__ erel) {
  int j = threadIdx.x;
  float g[NR]; float mx = -1e30f;
  for (int r = 0; r < NR; ++r) { g[r] = rel_gate[l * NR + r]; mx = fmaxf(mx, g[r]); }
  float s = 0.f;
  for (int r = 0; r < NR; ++r) { g[r] = expf(g[r] - mx); s += g[r]; }
  for (int r = 0; r < NR; ++r) g[r] /= s;
  if (j < NR) gates[j] = g[j];
  if (j < HID) {
    float b = 0.f;
    for (int r = 0; r < NR; ++r) b = fmaf(g[r], gat_bias[((size_t)(l * NR + r)) * HID + j], b);
    msg_bias[j] = b;
  }
  for (int r = 0; r < NR; ++r) {
    const float* Wer = We + ((size_t)(l * NR + r)) * 24 * 512;
    const float* re  = rel_emb + (l * NR + r) * RELDIM;
    float acc = 0.f;
#pragma unroll
    for (int q = 0; q < RELDIM; ++q) acc = fmaf(re[q], Wer[(FEDGE + q) * 512 + j], acc);
    erel[r * 512 + j] = acc;
  }
}

// ---------------- fills ----------------
__global__ void fill_zero(float* __restrict__ p, int n) {
  int i = blockIdx.x * 256 + threadIdx.x;
  if (i < n) p[i] = 0.f;
}
__global__ void fill_zero_i(int* __restrict__ p, int n) {
  int i = blockIdx.x * 256 + threadIdx.x;
  if (i < n) p[i] = 0;
}

// ---------------- CSR build (by target) ----------------
__global__ void csr_count(const int* __restrict__ eidx, int* __restrict__ deg) {
  int e = blockIdx.x * 256 + threadIdx.x;
  if (e < NE) atomicAdd(&deg[eidx[NE + e]], 1);
}
__global__ __launch_bounds__(256) void csr_scan(const int* __restrict__ deg,
                                                int* __restrict__ in_off, int* __restrict__ cursor) {
  __shared__ int ps[256];
  int t = threadIdx.x;
  const int CH = (NN + 255) / 256;  // 40
  int base = t * CH;
  int sum = 0;
  for (int i = 0; i < CH; ++i) { int idx = base + i; if (idx < NN) sum += deg[idx]; }
  ps[t] = sum;
  __syncthreads();
  for (int o = 1; o < 256; o <<= 1) {
    int v = (t >= o) ? ps[t - o] : 0;
    __syncthreads();
    ps[t] += v;
    __syncthreads();
  }
  int run = (t == 0) ? 0 : ps[t - 1];
  for (int i = 0; i < CH; ++i) {
    int idx = base + i;
    if (idx < NN) { in_off[idx] = run; cursor[idx] = run; run += deg[idx]; }
  }
  if (t == 255) in_off[NN] = run;
}
__global__ void csr_scatter(const int* __restrict__ eidx, int* __restrict__ cursor,
                            int* __restrict__ in_edges) {
  int e = blockIdx.x * 256 + threadIdx.x;
  if (e < NE) {
    int pos = atomicAdd(&cursor[eidx[NE + e]], 1);
    in_edges[pos] = e;
  }
}

// ---------------- node-centric GAT, relation pair via blockIdx.y ----------------
// xlr [NN,2048]: for r_sub: xl at [rs*1024, +512), xr at [rs*1024+512, +512).
// hmsg += gates[r]*0.25*agg via atomicAdd (hmsg pre-zeroed).
__global__ __launch_bounds__(256) void gat_node2(
    const int* __restrict__ in_off, const int* __restrict__ in_edges,
    const int* __restrict__ etype, const int* __restrict__ eidx,
    const float* __restrict__ eattr, const float* __restrict__ xlr,
    const float* __restrict__ We_base, const float* __restrict__ erel_base,
    const float* __restrict__ att_base, const float* __restrict__ gates,
    int rbase, float* __restrict__ hmsg) {
  __shared__ float WeL[16][512];
  __shared__ float attL[512];
  __shared__ float erelL[512];
  int tid = threadIdx.x;
  int rs = blockIdx.y;
  int r = rbase + rs;
  const float* We_r = We_base + (size_t)rs * 24 * 512;
  for (int i = tid; i < 16 * 512; i += 256) WeL[i >> 9][i & 511] = We_r[i];
  for (int i = tid; i < 512; i += 256) {
    attL[i] = att_base[rs * 512 + i];
    erelL[i] = erel_base[rs * 512 + i];
  }
  __syncthreads();
  float gr = gates[r] * 0.25f;
  int lane = tid & 63, wave = tid >> 6;
  int n = blockIdx.x * 4 + wave;
  if (n >= NN) return;
  int roff = rs * 1024;
  float xr[8];
  const float* xrb = xlr + (size_t)n * 2048 + roff + 512;
#pragma unroll
  for (int h = 0; h < 4; ++h) {
    xr[h * 2]     = xrb[h * 128 + lane];
    xr[h * 2 + 1] = xrb[h * 128 + 64 + lane];
  }
  float m[4] = {-1e30f, -1e30f, -1e30f, -1e30f};
  float lsum[4] = {0.f, 0.f, 0.f, 0.f};
  float acc[8] = {0.f, 0.f, 0.f, 0.f, 0.f, 0.f, 0.f, 0.f};
  int e0 = in_off[n], e1 = in_off[n + 1];
  for (int ii = e0; ii < e1; ++ii) {
    int e = in_edges[ii];
    if (etype[e] != r) continue;
    int s = eidx[e];
    const float* xls = xlr + (size_t)s * 2048 + roff;
    float ea[16];
#pragma unroll
    for (int k = 0; k < 16; ++k) ea[k] = eattr[(size_t)e * 16 + k];
    float xlv[8], p[4];
#pragma unroll
    for (int h = 0; h < 4; ++h) {
      float ph = 0.f;
#pragma unroll
      for (int half = 0; half < 2; ++half) {
        int idx = h * 128 + half * 64 + lane;
        float xv = xls[idx];
        xlv[h * 2 + half] = xv;
        float et = erelL[idx];
#pragma unroll
        for (int k = 0; k < 16; ++k) et = fmaf(ea[k], WeL[k][idx], et);
        float z = xv + xr[h * 2 + half] + et;
        z = (z > 0.f) ? z : 0.2f * z;  // leaky_relu 0.2
        ph = fmaf(z, attL[idx], ph);
      }
      p[h] = ph;
    }
#pragma unroll
    for (int h = 0; h < 4; ++h) {
#pragma unroll
      for (int o = 32; o > 0; o >>= 1) p[h] += __shfl_xor(p[h], o, 64);
    }
#pragma unroll
    for (int h = 0; h < 4; ++h) {
      float sh = p[h];
      float mn = fmaxf(m[h], sh);
      float sc = expf(m[h] - mn);
      float we = expf(sh - mn);
      m[h] = mn;
      lsum[h] = lsum[h] * sc + we;
      acc[h * 2]     = acc[h * 2] * sc + we * xlv[h * 2];
      acc[h * 2 + 1] = acc[h * 2 + 1] * sc + we * xlv[h * 2 + 1];
    }
  }
  float o0 = 0.f, o1 = 0.f;
#pragma unroll
  for (int h = 0; h < 4; ++h) {
    float inv = 1.f / fmaxf(lsum[h], 1e-16f);
    o0 += acc[h * 2] * inv;
    o1 += acc[h * 2 + 1] * inv;
  }
  size_t base = (size_t)n * HID;
  atomicAdd(&hmsg[base + lane],      gr * o0);
  atomicAdd(&hmsg[base + 64 + lane], gr * o1);
}

// ---------------- LayerNorm over 128 dims (optionally emits hi/lo bf16) ----------------
__global__ __launch_bounds__(64) void ln128(
    float* __restrict__ h, const float* __restrict__ add, const float* __restrict__ bvec,
    const float* __restrict__ g, const float* __restrict__ b,
    ushort* __restrict__ hh, ushort* __restrict__ hl) {
  int n = blockIdx.x, lane = threadIdx.x;
  size_t base = (size_t)n * HID;
  float x0 = h[base + lane] + add[base + lane];
  float x1 = h[base + 64 + lane] + add[base + 64 + lane];
  if (bvec) { x0 += bvec[lane]; x1 += bvec[64 + lane]; }
  float s = x0 + x1;
#pragma unroll
  for (int m = 32; m > 0; m >>= 1) s += __shfl_xor(s, m, 64);
  float mu = s * (1.f / 128.f);
  float d0 = x0 - mu, d1 = x1 - mu;
  float q = d0 * d0 + d1 * d1;
#pragma unroll
  for (int m = 32; m > 0; m >>= 1) q += __shfl_xor(q, m, 64);
  float inv = 1.f / sqrtf(q * (1.f / 128.f) + 1e-5f);
  float o0 = d0 * inv * g[lane] + b[lane];
  float o1 = d1 * inv * g[64 + lane] + b[64 + lane];
  h[base + lane]      = o0;
  h[base + 64 + lane] = o1;
  if (hh) {
    ushort i0 = f2bf(o0), i1 = f2bf(o1);
    hh[base + lane] = i0;        hh[base + 64 + lane] = i1;
    hl[base + lane] = f2bf(o0 - bf2f(i0));
    hl[base + 64 + lane] = f2bf(o1 - bf2f(i1));
  }
}

// ---------------- KAN expansion (fp32) — tiny readout head only ----------------
__global__ void expand_f32(const float* __restrict__ v, float* __restrict__ u, int In, int rows) {
  int i = blockIdx.x * 256 + threadIdx.x;
  if (i >= rows * In) return;
  int n = i / In, c = i % In;
  float x = v[(size_t)n * In + c];
  size_t base = (size_t)n * In * 9;
  u[base + c] = silu_f(x);
  float b8[8];
  kan_bases(x, b8);
  float* ub = u + base + In + (size_t)c * 8;
#pragma unroll
  for (int gq = 0; gq < 8; ++gq) ub[gq] = b8[gq];
}

// ---------------- atomic-free pooling, stage 1: per-chunk partials ----------------
// Thread d exclusively owns dim d in the LDS [NG][HID] tables -> race-free.
__global__ __launch_bounds__(128) void pool_part(
    const float* __restrict__ h, const int* __restrict__ batch,
    float* __restrict__ psum, float* __restrict__ pmax, float* __restrict__ pcnt) {
  __shared__ float sS[NG][HID];
  __shared__ float sM[NG][HID];
  __shared__ int sC[NG];
  int d = threadIdx.x, blk = blockIdx.x;
  const float NEGINF = __uint_as_float(0xff800000u);  // -inf
  for (int i = d; i < NG * HID; i += 128) {
    ((float*)sS)[i] = 0.f;
    ((float*)sM)[i] = NEGINF;
  }
  if (d < NG) sC[d] = 0;
  __syncthreads();
  const int CH = (NN + NCHUNK - 1) / NCHUNK;  // 79
  int n0 = blk * CH, n1 = (n0 + CH < NN) ? n0 + CH : NN;
  for (int n = n0; n < n1; ++n) {
    int g = batch[n];
    float v = h[(size_t)n * HID + d];
    sS[g][d] += v;
    sM[g][d] = fmaxf(sM[g][d], v);
    if (d == 0) sC[g]++;
  }
  __syncthreads();
  for (int i = d; i < NG * HID; i += 128) {
    psum[(size_t)blk * NG * HID + i] = ((float*)sS)[i];
    pmax[(size_t)blk * NG * HID + i] = ((float*)sM)[i];
  }
  if (d < NG) pcnt[blk * NG + d] = (float)sC[d];
}

// ---------------- pooling stage 2 + readout LN ----------------
__global__ __launch_bounds__(256) void pool_final2(
    const float* __restrict__ psum, const float* __restrict__ pmax,
    const float* __restrict__ pcnt, const float* __restrict__ rog,
    const float* __restrict__ rob, float* __restrict__ gvec) {
  int g = blockIdx.x, j = threadIdx.x;
  __shared__ float rb[256];
  float x;
  if (j < HID) {
    float s = 0.f, cn = 0.f;
    for (int c = 0; c < NCHUNK; ++c) {
      s += psum[(size_t)c * NG * HID + g * HID + j];
      cn += pcnt[c * NG + g];
    }
    x = s / fmaxf(cn, 1.f);
  } else {
    float mx = __uint_as_float(0xff800000u);
    for (int c = 0; c < NCHUNK; ++c)
      mx = fmaxf(mx, pmax[(size_t)c * NG * HID + g * HID + (j - HID)]);
    x = (mx > -1e38f) ? mx : 0.f;  // where(isfinite, ., 0)
  }
  rb[j] = x; __syncthreads();
  for (int st = 128; st > 0; st >>= 1) { if (j < st) rb[j] += rb[j + st]; __syncthreads(); }
  float mu = rb[0] * (1.f / 256.f); __syncthreads();
  float d = x - mu;
  rb[j] = d * d; __syncthreads();
  for (int st = 128; st > 0; st >>= 1) { if (j < st) rb[j] += rb[j + st]; __syncthreads(); }
  float var = rb[0] * (1.f / 256.f);
  float inv = 1.f / sqrtf(var + 1e-5f);
  gvec[(size_t)g * 256 + j] = d * inv * rog[j] + rob[j];
}

// ---------------- wave-parallel KAN head: one wave per (graph, output) ----------------
__global__ __launch_bounds__(256) void kan_head_w(
    const float* __restrict__ u, const float* __restrict__ base_w,
    const float* __restrict__ spline_w, const float* __restrict__ scaler,
    float* __restrict__ out, int In, int Out, int npairs) {
  int wid = blockIdx.x * 4 + (threadIdx.x >> 6);
  if (wid >= npairs) return;
  int g = wid / Out, o = wid % Out;
  int lane = threadIdx.x & 63;
  const float* ug = u + (size_t)g * In * 9;
  const float* bw = base_w + (size_t)o * In;
  const float* sp = spline_w + (size_t)o * In * 8;
  const float* sc = scaler + (size_t)o * In;
  float acc = 0.f;
  for (int i = lane; i < In; i += 64) acc = fmaf(ug[i], bw[i], acc);
  const float* us = ug + In;
  for (int k = lane; k < In * 8; k += 64) {
    int i = k >> 3;
    acc = fmaf(us[k], sp[k] * sc[i], acc);
  }
#pragma unroll
  for (int off2 = 32; off2 > 0; off2 >>= 1) acc += __shfl_xor(acc, off2, 64);
  if (lane == 0) out[(size_t)g * Out + o] = acc;
}

// ---------------- launch ----------------
extern "C" void kernel_launch(void* const* d_in, const int* in_sizes, int n_in,
                              void* d_out, int out_size, void* d_ws, size_t ws_size,
                              hipStream_t stream) {
  const float* x         = (const float*)d_in[0];
  const float* edge_attr = (const float*)d_in[1];
  const int*   id_token  = (const int*)  d_in[2];
  const int*   edge_index= (const int*)  d_in[3];
  const int*   edge_type = (const int*)  d_in[4];
  const int*   batch     = (const int*)  d_in[5];
  const float* id_emb    = (const float*)d_in[6];
  const float* inW       = (const float*)d_in[7];
  const float* inb       = (const float*)d_in[8];
  const float* Wl        = (const float*)d_in[9];
  const float* bl        = (const float*)d_in[10];
  const float* Wr        = (const float*)d_in[11];
  const float* br        = (const float*)d_in[12];
  const float* We        = (const float*)d_in[13];
  const float* att       = (const float*)d_in[14];
  const float* gat_bias  = (const float*)d_in[15];
  const float* rel_gate  = (const float*)d_in[16];
  const float* rel_emb   = (const float*)d_in[17];
  const float* ln1g      = (const float*)d_in[18];
  const float* ln1b      = (const float*)d_in[19];
  const float* ln2g      = (const float*)d_in[20];
  const float* ln2b      = (const float*)d_in[21];
  const float* ffn1_base = (const float*)d_in[22];
  const float* ffn1_spl  = (const float*)d_in[23];
  const float* ffn1_sc   = (const float*)d_in[24];
  const float* ffn2_base = (const float*)d_in[25];
  const float* ffn2_spl  = (const float*)d_in[26];
  const float* ffn2_sc   = (const float*)d_in[27];
  const float* rog       = (const float*)d_in[28];
  const float* rob       = (const float*)d_in[29];
  const float* h1_base   = (const float*)d_in[30];
  const float* h1_spl    = (const float*)d_in[31];
  const float* h1_sc     = (const float*)d_in[32];
  const float* h2_base   = (const float*)d_in[33];
  const float* h2_spl    = (const float*)d_in[34];
  const float* h2_sc     = (const float*)d_in[35];
  (void)in_sizes; (void)n_in; (void)out_size; (void)ws_size;

  // ---- workspace carve (256B aligned) ----
  char* wsp = (char*)d_ws;
  size_t off = 0;
  auto carve = [&](size_t bytes) { char* p = wsp + off; off = (off + bytes + 255) & ~(size_t)255; return p; };
  float*    h     = (float*)   carve((size_t)NN * HID * 4);
  ushort*   h_hi  = (ushort*)  carve((size_t)NN * HID * 2);
  ushort*   h_lo  = (ushort*)  carve((size_t)NN * HID * 2);
  float*    hmsg  = (float*)   carve((size_t)NN * HID * 4);
  float*    t1    = (float*)   carve((size_t)NN * FFNH * 4);
  float*    gates = (float*)   carve(NR * 4);
  float*    msgb  = (float*)   carve(HID * 4);
  float*    erel  = (float*)   carve(NR * 512 * 4);
  ushort*   WTh   = (ushort*)  carve((size_t)NL * 2 * 2048 * HID * 2);
  ushort*   WTl   = (ushort*)  carve((size_t)NL * 2 * 2048 * HID * 2);
  float*    blr   = (float*)   carve((size_t)NL * 2 * 2048 * 4);
  ushort*   B1h   = (ushort*)  carve((size_t)FFNH * HID * 9 * 2);
  ushort*   B1l   = (ushort*)  carve((size_t)FFNH * HID * 9 * 2);
  ushort*   B2h   = (ushort*)  carve((size_t)HID * FFNH * 9 * 2);
  ushort*   B2l   = (ushort*)  carve((size_t)HID * FFNH * 9 * 2);
  float*    psum  = (float*)   carve((size_t)NCHUNK * NG * HID * 4);
  float*    pmax  = (float*)   carve((size_t)NCHUNK * NG * HID * 4);
  float*    pcnt  = (float*)   carve((size_t)NCHUNK * NG * 4);
  float*    gvec  = (float*)   carve((size_t)NG * 256 * 4);
  float*    uhead = (float*)   carve((size_t)NG * 256 * 9 * 4);
  float*    thead = (float*)   carve((size_t)NG * HEADH * 4);
  float*    xlr   = (float*)   carve((size_t)NN * 2048 * 4);        // 82 MB
  int*      deg   = (int*)     carve((size_t)NN * 4);
  int*      in_off= (int*)     carve((size_t)(NN + 1) * 4);
  int*      cursor= (int*)     carve((size_t)NN * 4);
  int*      in_edges=(int*)    carve((size_t)NE * 4);

  // ---- CSR build (by target) ----
  fill_zero_i<<<(NN + 255) / 256, 256, 0, stream>>>(deg, NN);
  csr_count<<<(NE + 255) / 256, 256, 0, stream>>>(edge_index, deg);
  csr_scan<<<1, 256, 0, stream>>>(deg, in_off, cursor);
  csr_scatter<<<(NE + 255) / 256, 256, 0, stream>>>(edge_index, cursor, in_edges);

  // ---- weight transpose + split (once per launch) ----
  {
    int total = NL * 2 * 2048 * 128;
    conv_wT2<<<(total + 255) / 256, 256, 0, stream>>>(Wl, Wr, bl, br, WTh, WTl, blr, total);
  }

  // ---- input projection ----
  input_proj<<<NN, 128, 0, stream>>>(x, id_emb, id_token, inW, inb, h, h_hi, h_lo);

  const int MB128 = (NN + 127) / 128;  // 79
  const int MB64  = (NN + 63) / 64;    // 157
  for (int l = 0; l < NL; ++l) {
    layer_prep<<<1, 512, 0, stream>>>(rel_gate, gat_bias, rel_emb, We, l, gates, msgb, erel);
    fill_zero<<<(NN * HID + 255) / 256, 256, 0, stream>>>(hmsg, NN * HID);
    for (int pair = 0; pair < 2; ++pair) {
      int g2 = l * 2 + pair;
      const ushort* WThp = WTh + (size_t)g2 * 2048 * HID;
      const ushort* WTlp = WTl + (size_t)g2 * 2048 * HID;
      const float* blp   = blr + (size_t)g2 * 2048;
      int rbase = pair * 2;
      gemm_bf3<<<dim3(2048 / 64, MB128), 256, 0, stream>>>(h_hi, h_lo, WThp, WTlp, blp, xlr, NN, HID, 2048);
      gat_node2<<<dim3((NN + 3) / 4, 2), 256, 0, stream>>>(
          in_off, in_edges, edge_type, edge_index, edge_attr, xlr,
          We + ((size_t)(l * NR + rbase)) * 24 * 512, erel + rbase * 512,
          att + (size_t)(l * NR + rbase) * 512, gates, rbase, hmsg);
    }
    ln128<<<NN, 64, 0, stream>>>(h, hmsg, msgb, ln1g + l * HID, ln1b + l * HID, nullptr, nullptr);

    // ---- KAN FFN1: 128 -> 256 (K = 1152), fused expansion, split-K 3 ----
    build_kan_wT<<<((HID * 9 * FFNH) + 255) / 256, 256, 0, stream>>>(
        ffn1_base + (size_t)l * FFNH * HID, ffn1_spl + (size_t)l * FFNH * HID * 8,
        ffn1_sc + (size_t)l * FFNH * HID, B1h, B1l, HID, FFNH);
    fill_zero<<<(NN * FFNH + 255) / 256, 256, 0, stream>>>(t1, NN * FFNH);
    gemm_kan<128, 3><<<dim3(FFNH / 64, MB128, 3), 256, 0, stream>>>(h, B1h, B1l, t1, NN, HID, FFNH);
    // ---- KAN FFN2: 256 -> 128 (K = 2304), fused expansion, split-K 4 ----
    build_kan_wT<<<((FFNH * 9 * HID) + 255) / 256, 256, 0, stream>>>(
        ffn2_base + (size_t)l * HID * FFNH, ffn2_spl + (size_t)l * HID * FFNH * 8,
        ffn2_sc + (size_t)l * HID * FFNH, B2h, B2l, FFNH, HID);
    fill_zero<<<(NN * HID + 255) / 256, 256, 0, stream>>>(hmsg, NN * HID);
    gemm_kan<64, 4><<<dim3(HID / 64, MB64, 4), 256, 0, stream>>>(t1, B2h, B2l, hmsg, NN, FFNH, HID);
    ln128<<<NN, 64, 0, stream>>>(h, hmsg, nullptr, ln2g + l * HID, ln2b + l * HID, h_hi, h_lo);
  }

  // ---- readout (atomic-free pooling) ----
  pool_part<<<NCHUNK, 128, 0, stream>>>(h, batch, psum, pmax, pcnt);
  pool_final2<<<NG, 256, 0, stream>>>(psum, pmax, pcnt, rog, rob, gvec);
  expand_f32<<<((NG * 256) + 255) / 256, 256, 0, stream>>>(gvec, uhead, 256, NG);
  {
    int npairs = NG * HEADH;  // 4096 waves
    kan_head_w<<<(npairs + 3) / 4, 256, 0, stream>>>(uhead, h1_base, h1_spl, h1_sc, thead, 256, HEADH, npairs);
  }
  expand_f32<<<((NG * HEADH) + 255) / 256, 256, 0, stream>>>(thead, uhead, HEADH, NG);
  {
    int npairs = NG * NCLS;   // 320 waves
    kan_head_w<<<(npairs + 3) / 4, 256, 0, stream>>>(uhead, h2_base, h2_spl, h2_sc, (float*)d_out, HEADH, NCLS, npairs);
  }
}